// Round 5
// baseline (598.306 us; speedup 1.0000x reference)
//
#include <hip/hip_runtime.h>
#include <math.h>

#define NB 2
#define NN 2048
#define NC 512
#define NH 8
#define DK 64
#define DFF 2048
#define NTOP 512
#define NPOOL 1024
#define KSPLIT 4

typedef unsigned short u16;
typedef __attribute__((ext_vector_type(8))) short frag8;
typedef __attribute__((ext_vector_type(8))) _Float16 h8;
typedef __attribute__((ext_vector_type(4))) float f32x4;

static __device__ __forceinline__ u16 f2b(float f) {
    union { float f; unsigned int u; } v; v.f = f;
    unsigned int r = (v.u + 0x7fffu + ((v.u >> 16) & 1u)) >> 16;
    return (u16)r;
}
static __device__ __forceinline__ float b2f(u16 v) {
    union { unsigned u; float f; } x; x.u = ((unsigned)v) << 16; return x.f;
}
static __device__ __forceinline__ u16 f2h_bits(float f) {
    union { _Float16 h; u16 u; } v; v.h = (_Float16)f; return v.u;
}
static __device__ __forceinline__ float h2f_bits(u16 u) {
    union { u16 u; _Float16 h; } v; v.u = u; return (float)v.h;
}

// =============== bf16 MFMA GEMM: C = A @ Bt^T (+bias)(+gelu), 128x128 tile ========
// m0 from blockIdx.x (gridDim.x = 32 == 0 mod 8): blocks sharing an A-panel land on
// the SAME XCD -> panel lives in that XCD's L2 (round-4: cross-XCD re-fetch 35 MB).
// Register-staged prefetch: LOAD(k+1)->regs before MFMA(k); write LDS after barrier.
template<int MODE>
__global__ __launch_bounds__(256) void mfma_gemm(const u16* __restrict__ A, int lda,
    const u16* __restrict__ Bt, const float* __restrict__ bias,
    float* __restrict__ C, u16* __restrict__ Cb, int ldc, int K, int act)
{
    __shared__ u16 As[128][72];
    __shared__ u16 Bs[128][72];
    int tid = threadIdx.x;
    int m0 = blockIdx.x * 128, n0 = blockIdx.y * 128;
    int wave = tid >> 6, lane = tid & 63;
    int ln = lane & 15, quad = lane >> 4;
    int wm = (wave >> 1) * 64, wn = (wave & 1) * 64;
    f32x4 acc[4][4] = {};
    uint4 ra[4], rb[4];
    auto LOAD = [&](int k0) {
        #pragma unroll
        for (int i = 0; i < 4; i++) {
            int t = tid + i * 256;
            int m = t >> 3, kq = t & 7;
            size_t aoff;
            if (MODE == 1) {
                int grow = m0 + m;
                int shift = (k0 >> 9) - 1;
                int arow = (grow & ~(NN - 1)) | ((grow + shift) & (NN - 1));
                aoff = (size_t)arow * NC + ((k0 & 511) + kq * 8);
            } else {
                aoff = (size_t)(m0 + m) * lda + k0 + kq * 8;
            }
            ra[i] = *(const uint4*)&A[aoff];
            rb[i] = *(const uint4*)&Bt[(size_t)(n0 + m) * K + k0 + kq * 8];
        }
    };
    auto STORE = [&]() {
        #pragma unroll
        for (int i = 0; i < 4; i++) {
            int t = tid + i * 256;
            int m = t >> 3, kq = t & 7;
            *(uint4*)&As[m][kq * 8] = ra[i];
            *(uint4*)&Bs[m][kq * 8] = rb[i];
        }
    };
    LOAD(0); STORE();
    __syncthreads();
    for (int k0 = 0; k0 < K; k0 += 64) {
        bool more = (k0 + 64) < K;
        if (more) LOAD(k0 + 64);          // issue early: latency hides under MFMA
        #pragma unroll
        for (int kk = 0; kk < 2; kk++) {
            frag8 af[4], bf[4];
            #pragma unroll
            for (int i = 0; i < 4; i++) {
                af[i] = *(const frag8*)&As[wm + i * 16 + ln][kk * 32 + quad * 8];
                bf[i] = *(const frag8*)&Bs[wn + i * 16 + ln][kk * 32 + quad * 8];
            }
            #pragma unroll
            for (int i = 0; i < 4; i++)
                #pragma unroll
                for (int j = 0; j < 4; j++)
                    acc[i][j] = __builtin_amdgcn_mfma_f32_16x16x32_bf16(
                        af[i], bf[j], acc[i][j], 0, 0, 0);
        }
        if (more) {
            __syncthreads();              // all waves done reading LDS
            STORE();                      // write late
            __syncthreads();
        }
    }
    #pragma unroll
    for (int i = 0; i < 4; i++) {
        #pragma unroll
        for (int j = 0; j < 4; j++) {
            int col = n0 + wn + j * 16 + ln;
            float bv = bias ? bias[col] : 0.f;
            #pragma unroll
            for (int r = 0; r < 4; r++) {
                int row = m0 + wm + i * 16 + quad * 4 + r;
                float v = acc[i][j][r] + bv;
                if (act == 1) v = 0.5f * v * (1.0f + erff(v * 0.70710678118654752f));
                if (Cb) Cb[(size_t)row * ldc + col] = f2b(v);
                else    C[(size_t)row * ldc + col] = v;
            }
        }
    }
}

// =============== Q/K projection: f16 concat-hi/lo MFMA GEMM (fp32-grade) =========
__global__ __launch_bounds__(256) void mfma_qk(const u16* __restrict__ A,
    const u16* __restrict__ Bt, const float* __restrict__ bias,
    float* __restrict__ Qh, float* __restrict__ Kh,
    u16* __restrict__ Qcat, u16* __restrict__ Kcat)
{
    __shared__ u16 As[128][72];
    __shared__ u16 Bs[128][72];
    int tid = threadIdx.x;
    int m0 = blockIdx.x * 128, n0 = blockIdx.y * 128;
    int wave = tid >> 6, lane = tid & 63;
    int ln = lane & 15, quad = lane >> 4;
    int wm = (wave >> 1) * 64, wn = (wave & 1) * 64;
    f32x4 acc[4][4] = {};
    uint4 ra[4], rb[4];
    auto LOAD = [&](int k0) {
        #pragma unroll
        for (int i = 0; i < 4; i++) {
            int t = tid + i * 256;
            int m = t >> 3, kq = t & 7;
            ra[i] = *(const uint4*)&A[(size_t)(m0 + m) * 1024 + k0 + kq * 8];
            rb[i] = *(const uint4*)&Bt[(size_t)(n0 + m) * 1024 + k0 + kq * 8];
        }
    };
    auto STORE = [&]() {
        #pragma unroll
        for (int i = 0; i < 4; i++) {
            int t = tid + i * 256;
            int m = t >> 3, kq = t & 7;
            *(uint4*)&As[m][kq * 8] = ra[i];
            *(uint4*)&Bs[m][kq * 8] = rb[i];
        }
    };
    LOAD(0); STORE();
    __syncthreads();
    for (int k0 = 0; k0 < 1024; k0 += 64) {
        bool more = (k0 + 64) < 1024;
        if (more) LOAD(k0 + 64);
        #pragma unroll
        for (int kk = 0; kk < 2; kk++) {
            h8 af[4], bf[4];
            #pragma unroll
            for (int i = 0; i < 4; i++) {
                af[i] = *(const h8*)&As[wm + i * 16 + ln][kk * 32 + quad * 8];
                bf[i] = *(const h8*)&Bs[wn + i * 16 + ln][kk * 32 + quad * 8];
            }
            #pragma unroll
            for (int i = 0; i < 4; i++)
                #pragma unroll
                for (int j = 0; j < 4; j++)
                    acc[i][j] = __builtin_amdgcn_mfma_f32_16x16x32_f16(
                        af[i], bf[j], acc[i][j], 0, 0, 0);
        }
        if (more) {
            __syncthreads();
            STORE();
            __syncthreads();
        }
    }
    #pragma unroll
    for (int i = 0; i < 4; i++) {
        #pragma unroll
        for (int j = 0; j < 4; j++) {
            int col = n0 + wn + j * 16 + ln;   // 0..1023 : [Q | K]
            float bv = bias[col];
            int which = col >> 9;
            int h = (col >> 6) & 7, d = col & 63;
            #pragma unroll
            for (int r = 0; r < 4; r++) {
                int row = m0 + wm + i * 16 + quad * 4 + r;
                int b = row >> 11, n = row & (NN - 1);
                float v = acc[i][j][r] + bv;
                size_t off32 = ((size_t)((b << 3) + h) * NN + n) * DK + d;
                size_t offc  = ((size_t)((b << 3) + h) * NN + n) * 128 + d;
                u16 hb_ = f2h_bits(v);
                u16 lb_ = f2h_bits(v - h2f_bits(hb_));
                if (which == 0) {
                    Qh[off32] = v;
                    Qcat[offc] = hb_; Qcat[offc + 64] = lb_;
                } else {
                    Kh[off32] = v;
                    Kcat[offc] = hb_; Kcat[offc + 64] = lb_;
                }
            }
        }
    }
}

// =============== V-projection MFMA with head-major scatter ===============
__global__ __launch_bounds__(256) void mfma_v(const u16* __restrict__ A,
    const u16* __restrict__ Bt, const float* __restrict__ bias, float* __restrict__ Vh)
{
    __shared__ u16 As[128][72];
    __shared__ u16 Bs[128][72];
    int tid = threadIdx.x;
    int m0 = blockIdx.x * 128, n0 = blockIdx.y * 128;
    int wave = tid >> 6, lane = tid & 63;
    int ln = lane & 15, quad = lane >> 4;
    int wm = (wave >> 1) * 64, wn = (wave & 1) * 64;
    f32x4 acc[4][4] = {};
    uint4 ra[4], rb[4];
    auto LOAD = [&](int k0) {
        #pragma unroll
        for (int i = 0; i < 4; i++) {
            int t = tid + i * 256;
            int m = t >> 3, kq = t & 7;
            ra[i] = *(const uint4*)&A[(size_t)(m0 + m) * NC + k0 + kq * 8];
            rb[i] = *(const uint4*)&Bt[(size_t)(n0 + m) * NC + k0 + kq * 8];
        }
    };
    auto STORE = [&]() {
        #pragma unroll
        for (int i = 0; i < 4; i++) {
            int t = tid + i * 256;
            int m = t >> 3, kq = t & 7;
            *(uint4*)&As[m][kq * 8] = ra[i];
            *(uint4*)&Bs[m][kq * 8] = rb[i];
        }
    };
    LOAD(0); STORE();
    __syncthreads();
    for (int k0 = 0; k0 < NC; k0 += 64) {
        bool more = (k0 + 64) < NC;
        if (more) LOAD(k0 + 64);
        #pragma unroll
        for (int kk = 0; kk < 2; kk++) {
            frag8 af[4], bf[4];
            #pragma unroll
            for (int i = 0; i < 4; i++) {
                af[i] = *(const frag8*)&As[wm + i * 16 + ln][kk * 32 + quad * 8];
                bf[i] = *(const frag8*)&Bs[wn + i * 16 + ln][kk * 32 + quad * 8];
            }
            #pragma unroll
            for (int i = 0; i < 4; i++)
                #pragma unroll
                for (int j = 0; j < 4; j++)
                    acc[i][j] = __builtin_amdgcn_mfma_f32_16x16x32_bf16(
                        af[i], bf[j], acc[i][j], 0, 0, 0);
        }
        if (more) {
            __syncthreads();
            STORE();
            __syncthreads();
        }
    }
    #pragma unroll
    for (int i = 0; i < 4; i++) {
        #pragma unroll
        for (int j = 0; j < 4; j++) {
            int col = n0 + wn + j * 16 + ln;
            int h = col >> 6, d = col & 63;
            float bv = bias[col];
            #pragma unroll
            for (int r = 0; r < 4; r++) {
                int row = m0 + wm + i * 16 + quad * 4 + r;
                int b = row >> 11, n = row & (NN - 1);
                Vh[((size_t)((b << 3) + h) * NN + n) * DK + d] = acc[i][j][r] + bv;
            }
        }
    }
}

// =============== weight cast+transpose (bf16) ===============
__global__ __launch_bounds__(256) void castw_t(const float* __restrict__ in,
    u16* __restrict__ out, int R, int C, int ldi, int coff)
{
    __shared__ float t[32][33];
    int c0 = blockIdx.x * 32, r0 = blockIdx.y * 32;
    int lx = threadIdx.x & 31, ly = threadIdx.x >> 5;
    #pragma unroll
    for (int i = 0; i < 4; i++)
        t[ly + i * 8][lx] = in[(size_t)(r0 + ly + i * 8) * ldi + coff + c0 + lx];
    __syncthreads();
    #pragma unroll
    for (int i = 0; i < 4; i++)
        out[(size_t)(c0 + ly + i * 8) * R + r0 + lx] = f2b(t[lx][ly + i * 8]);
}

// =============== qkv_w cols[0,1024): transpose + fp16 hi/lo concat ===============
__global__ __launch_bounds__(256) void castw_hl(const float* __restrict__ in,
    u16* __restrict__ out)
{
    __shared__ float t[32][33];
    int c0 = blockIdx.x * 32, r0 = blockIdx.y * 32;
    int lx = threadIdx.x & 31, ly = threadIdx.x >> 5;
    #pragma unroll
    for (int i = 0; i < 4; i++)
        t[ly + i * 8][lx] = in[(size_t)(r0 + ly + i * 8) * 1536 + c0 + lx];
    __syncthreads();
    #pragma unroll
    for (int i = 0; i < 4; i++) {
        float v = t[lx][ly + i * 8];
        u16 hb_ = f2h_bits(v);
        u16 lb_ = f2h_bits(v - h2f_bits(hb_));
        size_t ob = (size_t)(c0 + ly + i * 8) * 1024 + r0 + lx;
        out[ob] = hb_;
        out[ob + 512] = lb_;
    }
}

// =============== conv weight cast: [co][ci][t] -> [co][t*512+ci] bf16 ===============
__global__ void castconvw_k(const float* __restrict__ cw, u16* __restrict__ out)
{
    int i = blockIdx.x * 256 + threadIdx.x;
    if (i >= 3 * NC * NC) return;
    int t = i % 3, ci = (i / 3) & (NC - 1), co = i / (3 * NC);
    out[(size_t)co * 1536 + t * NC + ci] = f2b(cw[i]);
}

// =============== x: one read -> bf16 (xb) + concat hi/lo fp16 (xcat) ===============
__global__ void castx_k(const float* __restrict__ in, u16* __restrict__ xb,
                        u16* __restrict__ xcat)
{
    int i = blockIdx.x * 256 + threadIdx.x;
    if (i >= (NB * NN * NC) / 4) return;
    int m = i >> 7, kq = i & 127;
    float4 v = ((const float4*)in)[i];
    ushort4 b, h, l;
    b.x = f2b(v.x); b.y = f2b(v.y); b.z = f2b(v.z); b.w = f2b(v.w);
    h.x = f2h_bits(v.x); h.y = f2h_bits(v.y);
    h.z = f2h_bits(v.z); h.w = f2h_bits(v.w);
    l.x = f2h_bits(v.x - h2f_bits(h.x));
    l.y = f2h_bits(v.y - h2f_bits(h.y));
    l.z = f2h_bits(v.z - h2f_bits(h.z));
    l.w = f2h_bits(v.w - h2f_bits(h.w));
    ((ushort4*)xb)[i] = b;
    *(ushort4*)&xcat[(size_t)m * 1024 + kq * 4] = h;
    *(ushort4*)&xcat[(size_t)m * 1024 + 512 + kq * 4] = l;
}

// =============== K,V -> bf16 (V transposed per bh) ===============
__global__ __launch_bounds__(256) void castkv_k(const float* __restrict__ Kh,
    const float* __restrict__ Vh, u16* __restrict__ Kb, u16* __restrict__ Vtb)
{
    int bh = blockIdx.y;
    int n0 = blockIdx.x * 64;
    __shared__ float vt[64][68];
    int tid = threadIdx.x;
    const float* kin = Kh + ((size_t)bh * NN + n0) * DK;
    u16* kout = Kb + ((size_t)bh * NN + n0) * DK;
    const float* vin = Vh + ((size_t)bh * NN + n0) * DK;
    #pragma unroll
    for (int i = 0; i < 4; i++) {
        int t = tid + i * 256;
        int n = t >> 4, dq = t & 15;
        float4 v = *(const float4*)&kin[(size_t)n * DK + dq * 4];
        ushort4 o;
        o.x = f2b(v.x); o.y = f2b(v.y); o.z = f2b(v.z); o.w = f2b(v.w);
        *(ushort4*)&kout[(size_t)n * DK + dq * 4] = o;
        float4 w = *(const float4*)&vin[(size_t)n * DK + dq * 4];
        vt[dq * 4 + 0][n] = w.x; vt[dq * 4 + 1][n] = w.y;
        vt[dq * 4 + 2][n] = w.z; vt[dq * 4 + 3][n] = w.w;
    }
    __syncthreads();
    #pragma unroll
    for (int i = 0; i < 4; i++) {
        int t = tid + i * 256;
        int d = t >> 4, nq = t & 15;
        float4 v = *(const float4*)&vt[d][nq * 4];
        ushort4 o;
        o.x = f2b(v.x); o.y = f2b(v.y); o.z = f2b(v.z); o.w = f2b(v.w);
        *(ushort4*)&Vtb[((size_t)bh * DK + d) * NN + n0 + nq * 4] = o;
    }
}

// =============== mean of V: stage 1, 512 blocks, coalesced partials ===============
__global__ __launch_bounds__(256) void meanv_part_k(const float* __restrict__ Vh,
    float* __restrict__ pmean)
{
    int bh = blockIdx.y, chunk = blockIdx.x;   // 32 chunks of 64 rows
    int tid = threadIdx.x;
    int d = tid & 63, sub = tid >> 6;
    const float* vb = Vh + ((size_t)bh * NN + chunk * 64 + sub * 16) * DK;
    float s = 0.f;
    #pragma unroll
    for (int r = 0; r < 16; r++) s += vb[(size_t)r * DK + d];
    __shared__ float red[256];
    red[tid] = s;
    __syncthreads();
    if (sub == 0)
        pmean[((size_t)bh * 32 + chunk) * 64 + d] =
            red[d] + red[64 + d] + red[128 + d] + red[192 + d];
}

// =============== mean of V: stage 2 combine ===============
__global__ void meanv_comb_k(const float* __restrict__ pmean, float* __restrict__ meanv)
{
    int bh = blockIdx.x;
    int d = threadIdx.x;   // 64 threads
    float s = 0.f;
    #pragma unroll
    for (int c = 0; c < 32; c++) s += pmean[((size_t)bh * 32 + c) * 64 + d];
    meanv[bh * DK + d] = s * (1.0f / (float)NN);
}

// =============== rowstat via concat-fp16 MFMA; emits Marr and scaled rowmax ========
// bh = blockIdx.x (16 == 0 mod 8): all blocks of one head co-XCD -> K-panel in L2.
__global__ __launch_bounds__(256) void rowstat_mfma_k(const u16* __restrict__ Qcat,
    const u16* __restrict__ Kcat, float* __restrict__ Marr, float* __restrict__ rowmax)
{
    int bh = blockIdx.x;
    int m0 = blockIdx.y * 64;
    int tid = threadIdx.x;
    int wave = tid >> 6, lane = tid & 63;
    int ln = lane & 15, quad = lane >> 4;
    __shared__ u16 Ks[128][136];
    h8 qf[4];
    {
        const u16* qp = &Qcat[((size_t)bh * NN + m0 + wave * 16 + ln) * 128];
        #pragma unroll
        for (int ks = 0; ks < 4; ks++)
            qf[ks] = *(const h8*)&qp[ks * 32 + quad * 8];
    }
    f32x4 vmax, vsum;
    #pragma unroll
    for (int r = 0; r < 4; r++) { vmax[r] = -INFINITY; vsum[r] = 0.f; }
    const u16* kB = Kcat + (size_t)bh * NN * 128;
    uint4 rk[8];
    auto LOADK = [&](int nc) {
        #pragma unroll
        for (int i = 0; i < 8; i++) {
            int e = tid + i * 256;
            int n = e >> 4, kq = e & 15;
            rk[i] = *(const uint4*)&kB[(size_t)(nc + n) * 128 + kq * 8];
        }
    };
    auto STOREK = [&]() {
        #pragma unroll
        for (int i = 0; i < 8; i++) {
            int e = tid + i * 256;
            int n = e >> 4, kq = e & 15;
            *(uint4*)&Ks[n][kq * 8] = rk[i];
        }
    };
    LOADK(0); STOREK();
    __syncthreads();
    for (int nc = 0; nc < NN; nc += 128) {
        bool more = (nc + 128) < NN;
        if (more) LOADK(nc + 128);
        f32x4 accS[8] = {};
        #pragma unroll
        for (int nt = 0; nt < 8; nt++) {
            #pragma unroll
            for (int ks = 0; ks < 4; ks++) {
                h8 kf = *(const h8*)&Ks[nt * 16 + ln][ks * 32 + quad * 8];
                accS[nt] = __builtin_amdgcn_mfma_f32_16x16x32_f16(
                    qf[ks], kf, accS[nt], 0, 0, 0);
            }
        }
        #pragma unroll
        for (int nt = 0; nt < 8; nt++)
            #pragma unroll
            for (int r = 0; r < 4; r++) {
                vmax[r] = fmaxf(vmax[r], accS[nt][r]);
                vsum[r] += accS[nt][r];
            }
        if (more) {
            __syncthreads();
            STOREK();
            __syncthreads();
        }
    }
    #pragma unroll
    for (int r = 0; r < 4; r++) {
        float mx = vmax[r], sm = vsum[r];
        #pragma unroll
        for (int off = 1; off < 16; off <<= 1) {
            mx = fmaxf(mx, __shfl_xor(mx, off));
            sm += __shfl_xor(sm, off);
        }
        if (ln == 0) {
            int m = m0 + wave * 16 + quad * 4 + r;
            Marr[(size_t)bh * NN + m] = (mx - sm * (1.0f / (float)NN)) * 0.125f;
            rowmax[(size_t)bh * NN + m] = mx * 0.125f;
        }
    }
}

// =============== top-512 per (b,h): radix-select, wave-shfl scans ===============
__global__ __launch_bounds__(256) void topk_k(const float* __restrict__ Marr,
                                              int* __restrict__ idx)
{
    int bh = blockIdx.x;
    const float* Mr = Marr + (size_t)bh * NN;
    int* idxr = idx + (size_t)bh * NTOP;
    __shared__ int hist[256];
    __shared__ int suf[256];
    __shared__ int wred[4], wred2[4];
    __shared__ int bin_sh, rank_sh;
    int tid = threadIdx.x;
    int lane = tid & 63, w = tid >> 6;
    unsigned prefix = 0;
    int rank = NTOP;
    for (int pass = 0; pass < 4; pass++) {
        int shift = 24 - pass * 8;
        unsigned mask_hi = (pass == 0) ? 0u : (0xFFFFFFFFu << (shift + 8));
        hist[tid] = 0;
        __syncthreads();
        for (int i = tid; i < NN; i += 256) {
            union { float f; unsigned u; } v; v.f = Mr[i];
            unsigned k = (v.u & 0x80000000u) ? ~v.u : (v.u | 0x80000000u);
            if ((k & mask_hi) == prefix)
                atomicAdd(&hist[(k >> shift) & 255], 1);
        }
        __syncthreads();
        // inclusive suffix scan: wave-level shfl + cross-wave combine
        int v = hist[tid];
        #pragma unroll
        for (int off = 1; off < 64; off <<= 1) {
            int t = __shfl_down(v, off);
            if (lane + off < 64) v += t;
        }
        if (lane == 0) wred[w] = v;
        __syncthreads();
        int add = 0;
        #pragma unroll
        for (int w2 = 0; w2 < 4; w2++) if (w2 > w) add += wred[w2];
        suf[tid] = v + add;
        __syncthreads();
        int sv = suf[tid];
        int nxt = (tid < 255) ? suf[tid + 1] : 0;
        if (sv >= rank && nxt < rank) { bin_sh = tid; rank_sh = rank - nxt; }
        __syncthreads();
        prefix |= ((unsigned)bin_sh << shift);
        rank = rank_sh;
        __syncthreads();
    }
    union { unsigned u; float f; } tv;
    tv.u = (prefix & 0x80000000u) ? (prefix & 0x7FFFFFFFu) : ~prefix;
    float thr = tv.f;
    int lg = 0, le = 0;
    #pragma unroll
    for (int k = 0; k < 8; k++) {
        float v = Mr[tid * 8 + k];
        lg += (v > thr) ? 1 : 0;
        le += (v == thr) ? 1 : 0;
    }
    // inclusive prefix scans of lg, le via wave shfl
    int vg = lg, ve = le;
    #pragma unroll
    for (int off = 1; off < 64; off <<= 1) {
        int tg = __shfl_up(vg, off);
        int te = __shfl_up(ve, off);
        if (lane >= off) { vg += tg; ve += te; }
    }
    if (lane == 63) { wred[w] = vg; wred2[w] = ve; }
    __syncthreads();
    int addg = 0, adde = 0, totg = 0;
    #pragma unroll
    for (int w2 = 0; w2 < 4; w2++) {
        totg += wred[w2];
        if (w2 < w) { addg += wred[w2]; adde += wred2[w2]; }
    }
    int cnt_gt = totg;
    int needed = NTOP - cnt_gt;
    int gpre = (vg + addg) - lg, epre = (ve + adde) - le;
    #pragma unroll
    for (int k = 0; k < 8; k++) {
        int p = tid * 8 + k;
        float v = Mr[p];
        bool isgt = v > thr, iseq = v == thr;
        bool selv = isgt || (iseq && epre < needed);
        if (selv) idxr[gpre + (epre < needed ? epre : needed)] = p;
        gpre += isgt ? 1 : 0;
        epre += iseq ? 1 : 0;
    }
}

// =============== fill ctx (bf16) with uniform-attention result ===============
__global__ void fill_k(const float* __restrict__ meanv, u16* __restrict__ ctxb)
{
    int i = blockIdx.x * 256 + threadIdx.x;
    if (i >= NB * NN * NC) return;
    int c = i & (NC - 1);
    int m = i >> 9;
    int b = m >> 11;
    int h = c >> 6, d = c & 63;
    ctxb[i] = f2b(meanv[(((b << 3) + h) << 6) + d]);
}

// =============== MFMA flash attention, precomputed rowmax, split-K ===============
// yy = blockIdx.x (64 == 0 mod 8): blocks sharing a (bh,split) K/V range co-XCD.
__global__ __launch_bounds__(256) void attn_mfma_k(const float* __restrict__ Qh,
    const u16* __restrict__ Kb, const u16* __restrict__ Vtb,
    const int* __restrict__ idx, const float* __restrict__ rowmax,
    float* __restrict__ Opart, float* __restrict__ ml)
{
    int yy = blockIdx.x;
    int bh = yy >> 2, split = yy & (KSPLIT - 1);
    int t0 = blockIdx.y * 64;
    int tid = threadIdx.x;
    int wave = tid >> 6, lane = tid & 63;
    int ln = lane & 15, quad = lane >> 4;
    __shared__ u16 Ks[128][72];
    __shared__ u16 Vt[64][136];
    __shared__ u16 Ps[4][16][136];
    __shared__ int rows[64];
    if (tid < 64) rows[tid] = idx[bh * NTOP + t0 + tid];
    __syncthreads();
    frag8 qf[2];
    {
        const float* qp = &Qh[((size_t)bh * NN + rows[wave * 16 + ln]) * DK];
        #pragma unroll
        for (int ks = 0; ks < 2; ks++) {
            float4 a = *(const float4*)&qp[ks * 32 + quad * 8];
            float4 b = *(const float4*)&qp[ks * 32 + quad * 8 + 4];
            union { frag8 f; u16 s[8]; } u;
            u.s[0] = f2b(a.x * 0.125f); u.s[1] = f2b(a.y * 0.125f);
            u.s[2] = f2b(a.z * 0.125f); u.s[3] = f2b(a.w * 0.125f);
            u.s[4] = f2b(b.x * 0.125f); u.s[5] = f2b(b.y * 0.125f);
            u.s[6] = f2b(b.z * 0.125f); u.s[7] = f2b(b.w * 0.125f);
            qf[ks] = u.f;
        }
    }
    float rm[4];
    #pragma unroll
    for (int r = 0; r < 4; r++)
        rm[r] = rowmax[(size_t)bh * NN + rows[wave * 16 + quad * 4 + r]];
    f32x4 accO[4] = {};
    float lrun[4] = {};
    const u16* kbB = Kb + (size_t)bh * NN * DK;
    const u16* vtB = Vtb + (size_t)bh * DK * NN;
    int nc0 = split * (NN / KSPLIT);
    for (int nc = nc0; nc < nc0 + NN / KSPLIT; nc += 128) {
        __syncthreads();
        #pragma unroll
        for (int i = 0; i < 4; i++) {
            int e = tid + i * 256;
            int n = e >> 3, kq = e & 7;
            *(uint4*)&Ks[n][kq * 8] = *(const uint4*)&kbB[(size_t)(nc + n) * DK + kq * 8];
        }
        #pragma unroll
        for (int i = 0; i < 4; i++) {
            int e = tid + i * 256;
            int d = e >> 4, nq = e & 15;
            *(uint4*)&Vt[d][nq * 8] = *(const uint4*)&vtB[(size_t)d * NN + nc + nq * 8];
        }
        __syncthreads();
        f32x4 accS[8] = {};
        #pragma unroll
        for (int nt = 0; nt < 8; nt++) {
            frag8 b0 = *(const frag8*)&Ks[nt * 16 + ln][quad * 8];
            frag8 b1 = *(const frag8*)&Ks[nt * 16 + ln][32 + quad * 8];
            accS[nt] = __builtin_amdgcn_mfma_f32_16x16x32_bf16(qf[0], b0, accS[nt], 0, 0, 0);
            accS[nt] = __builtin_amdgcn_mfma_f32_16x16x32_bf16(qf[1], b1, accS[nt], 0, 0, 0);
        }
        #pragma unroll
        for (int nt = 0; nt < 8; nt++)
            #pragma unroll
            for (int r = 0; r < 4; r++) {
                float p = expf(accS[nt][r] - rm[r]);
                accS[nt][r] = p;
                lrun[r] += p;
            }
        #pragma unroll
        for (int nt = 0; nt < 8; nt++)
            #pragma unroll
            for (int r = 0; r < 4; r++)
                Ps[wave][quad * 4 + r][nt * 16 + ln] = f2b(accS[nt][r]);
        #pragma unroll
        for (int ks = 0; ks < 4; ks++) {
            frag8 pf = *(const frag8*)&Ps[wave][ln][ks * 32 + quad * 8];
            #pragma unroll
            for (int nt2 = 0; nt2 < 4; nt2++) {
                frag8 vf = *(const frag8*)&Vt[nt2 * 16 + ln][ks * 32 + quad * 8];
                accO[nt2] = __builtin_amdgcn_mfma_f32_16x16x32_bf16(pf, vf, accO[nt2], 0, 0, 0);
            }
        }
    }
    #pragma unroll
    for (int r = 0; r < 4; r++) {
        float ls = lrun[r];
        #pragma unroll
        for (int off = 1; off < 16; off <<= 1) ls += __shfl_xor(ls, off);
        int p = t0 + wave * 16 + quad * 4 + r;
        size_t pb = ((size_t)bh * NTOP + p) * KSPLIT + split;
        #pragma unroll
        for (int nt2 = 0; nt2 < 4; nt2++)
            Opart[pb * 64 + nt2 * 16 + ln] = accO[nt2][r];
        if (ln == 0) ml[pb * 2 + 1] = ls;
    }
}

// =============== combine split-K partials -> ctxb (bf16) ===============
// all splits share the same (exact) rowmax -> plain sums
__global__ __launch_bounds__(256) void attn_comb_k(const float* __restrict__ Opart,
    const float* __restrict__ ml, const int* __restrict__ idx,
    u16* __restrict__ ctxb)
{
    int gid = blockIdx.x * 4 + (threadIdx.x >> 6);
    int lane = threadIdx.x & 63;
    int bh = gid >> 9;
    int h = bh & 7, b = bh >> 3;
    size_t base = (size_t)gid * KSPLIT;
    float L = 0.f, O = 0.f;
    #pragma unroll
    for (int s = 0; s < KSPLIT; s++) {
        L += ml[(base + s) * 2 + 1];
        O += Opart[(base + s) * 64 + lane];
    }
    int n = idx[gid];
    ctxb[((size_t)(b * NN + n)) * NC + h * DK + lane] = f2b(O / L);
}

// =============== layernorm; B operand fp32 or bf16; fp32 and/or bf16 out ===========
__global__ __launch_bounds__(256) void ln_k(const float* __restrict__ A,
    const float* __restrict__ Bv, const u16* __restrict__ Bvb,
    const float* __restrict__ g, const float* __restrict__ bb,
    float* __restrict__ out, u16* __restrict__ outb)
{
    int row = blockIdx.x;
    int tid = threadIdx.x;
    __shared__ float v[NC];
    __shared__ float red[256];
    size_t base = (size_t)row * NC;
    for (int i = tid; i < NC; i += 256)
        v[i] = A[base + i] + (Bvb ? b2f(Bvb[base + i]) : Bv[base + i]);
    __syncthreads();
    float ls = 0.f;
    for (int i = tid; i < NC; i += 256) ls += v[i];
    red[tid] = ls; __syncthreads();
    for (int off = 128; off > 0; off >>= 1) {
        if (tid < off) red[tid] += red[tid + off];
        __syncthreads();
    }
    float mu = red[0] / (float)NC;
    __syncthreads();
    float lv = 0.f;
    for (int i = tid; i < NC; i += 256) { float d = v[i] - mu; lv += d * d; }
    red[tid] = lv; __syncthreads();
    for (int off = 128; off > 0; off >>= 1) {
        if (tid < off) red[tid] += red[tid + off];
        __syncthreads();
    }
    float rstd = rsqrtf(red[0] / (float)NC + 1e-5f);
    for (int i = tid; i < NC; i += 256) {
        float r = (v[i] - mu) * rstd * g[i] + bb[i];
        if (out) out[base + i] = r;
        if (outb) outb[base + i] = f2b(r);
    }
}

// =============== maxpool(3,2,1) + ELU + LN over bf16 conv output ===============
__global__ __launch_bounds__(256) void pool_ln_k(const u16* __restrict__ y,
    const float* __restrict__ g, const float* __restrict__ bb,
    float* __restrict__ outp)
{
    int row = blockIdx.x;
    int j = row & (NPOOL - 1), b = row / NPOOL;
    int tid = threadIdx.x;
    __shared__ float v[NC];
    __shared__ float red[256];
    const u16* ybase = y + (size_t)b * NN * NC;
    for (int i = tid; i < NC; i += 256) {
        float m = -INFINITY;
        int p0 = 2 * j - 1;
        #pragma unroll
        for (int t = 0; t < 3; t++) {
            int p = p0 + t;
            if (p >= 0 && p < NN) m = fmaxf(m, b2f(ybase[(size_t)p * NC + i]));
        }
        v[i] = m > 0.f ? m : expm1f(m);
    }
    __syncthreads();
    float ls = 0.f;
    for (int i = tid; i < NC; i += 256) ls += v[i];
    red[tid] = ls; __syncthreads();
    for (int off = 128; off > 0; off >>= 1) {
        if (tid < off) red[tid] += red[tid + off];
        __syncthreads();
    }
    float mu = red[0] / (float)NC;
    __syncthreads();
    float lv = 0.f;
    for (int i = tid; i < NC; i += 256) { float d = v[i] - mu; lv += d * d; }
    red[tid] = lv; __syncthreads();
    for (int off = 128; off > 0; off >>= 1) {
        if (tid < off) red[tid] += red[tid + off];
        __syncthreads();
    }
    float rstd = rsqrtf(red[0] / (float)NC + 1e-5f);
    for (int i = tid; i < NC; i += 256)
        outp[(size_t)row * NC + i] = (v[i] - mu) * rstd * g[i] + bb[i];
}

extern "C" void kernel_launch(void* const* d_in, const int* in_sizes, int n_in,
                              void* d_out, int out_size, void* d_ws, size_t ws_size,
                              hipStream_t stream)
{
    (void)in_sizes; (void)n_in; (void)out_size; (void)ws_size;
    const float* x      = (const float*)d_in[0];
    const float* qkv_w  = (const float*)d_in[1];
    const float* qkv_b  = (const float*)d_in[2];
    const float* out_w  = (const float*)d_in[3];
    const float* out_b  = (const float*)d_in[4];
    const float* ffn_w1 = (const float*)d_in[5];
    const float* ffn_b1 = (const float*)d_in[6];
    const float* ffn_w2 = (const float*)d_in[7];
    const float* ffn_b2 = (const float*)d_in[8];
    const float* n1_g   = (const float*)d_in[9];
    const float* n1_b   = (const float*)d_in[10];
    const float* n2_g   = (const float*)d_in[11];
    const float* n2_b   = (const float*)d_in[12];
    const float* conv_w = (const float*)d_in[13];
    const float* conv_b = (const float*)d_in[14];
    const float* cn_g   = (const float*)d_in[15];
    const float* cn_b   = (const float*)d_in[16];

    const size_t R = (size_t)NB * NN * NC;     // 2097152
    float* ws = (float*)d_ws;
    float* x1   = ws;                 // R : Kcat during rowstat; Opart; LN1 fp32 out
    float* reg2 = ws + R;             // R : xb+vwT -> Kb+Vtb
    float* Qh   = ws + 2 * R;         // R : Q; later attn_out
    float* Kh   = ws + 3 * R;         // R : K; later hb
    float* Vh   = ws + 4 * R;         // R : xcat during proj; V after mfma_v
    size_t o = 5 * R;
    float* pmax  = ws + o;  o += 65536;   // rowmax (scaled) lives here
    float* psum  = ws + o;  o += 65536;   // (kept for layout stability; unused)
    float* Marr  = ws + o;  o += 32768;
    float* pmean = ws + o;  o += 32768;
    float* meanv = ws + o;  o += 1024;
    int*   idx   = (int*)(ws + o);  o += 8192;
    float* ml    = ws + o;  o += 65536;
    u16*   ctxb  = (u16*)(ws + o);  o += R / 2;   // later ffn_outb
    u16*   x1b   = (u16*)(ws + o);  o += R / 2;   // Qcat lower half; later convyb
    u16*   x2b   = (u16*)(ws + o);  o += R / 2;   // Qcat upper half; later LN2 out
    u16*   owT   = (u16*)(ws + o);  o += 131072;
    u16*   w1T   = (u16*)(ws + o);  o += 524288;  // wcatT early, ffn_w1^T after mfma_qk
    u16*   w2T   = (u16*)(ws + o);  o += 524288;
    u16*   cwT   = (u16*)(ws + o);  o += 393216;
    u16*   xb    = (u16*)reg2;                      // R u16 (dead after mfma_v)
    u16*   vwT   = (u16*)(ws + R + R / 2);          // dead after mfma_v
    u16*   Kb    = (u16*)reg2;                      // [16][2048][64] u16
    u16*   Vtb   = (u16*)(ws + R + R / 2);          // [16][64][2048] u16
    float* Opart    = x1;
    float* attn_out = Qh;
    u16*   hb       = (u16*)(ws + 3 * R);
    u16*   ffn_outb = ctxb;           // ctxb dead after proj
    u16*   convyb   = x1b;            // x1b dead after FFN1
    float* rowmax   = pmax;
    // concat-fp16 buffers for the MFMA Q/K projection + rowstat:
    u16*   xcat  = (u16*)Vh;          // [4096][1024] fp16 (2R u16) — dead before mfma_v
    u16*   wcatT = w1T;               // [1024][1024] fp16 — dead before castw_t(ffn_w1)
    u16*   Qcat  = x1b;               // [16][2048][128] fp16 (2R u16 = x1b+x2b)
    u16*   Kcat  = (u16*)x1;          // [16][2048][128] fp16 (2R u16 = x1 region)
    (void)psum;

    // weight / activation casts (w1T region is wcatT until after mfma_qk)
    castw_t<<<dim3(16, 16), 256, 0, stream>>>(out_w, owT, 512, 512, 512, 0);
    castw_t<<<dim3(16, 64), 256, 0, stream>>>(ffn_w2, w2T, 2048, 512, 512, 0);
    castw_t<<<dim3(16, 16), 256, 0, stream>>>(qkv_w, vwT, 512, 512, 1536, 1024);
    castconvw_k<<<3072, 256, 0, stream>>>(conv_w, cwT);
    castx_k<<<2048, 256, 0, stream>>>(x, xb, xcat);
    castw_hl<<<dim3(32, 16), 256, 0, stream>>>(qkv_w, wcatT);

    // Q,K projection via concat-fp16 MFMA (fp32-grade, selection-safe)
    // grid (m-tiles=32, n-tiles=8): A-panel sharers co-XCD
    mfma_qk<<<dim3(32, 8), 256, 0, stream>>>(xcat, wcatT, qkv_b, Qh, Kh, Qcat, Kcat);

    // now wcatT dead -> build real w1T; xcat dead -> V projection may write Vh
    castw_t<<<dim3(64, 16), 256, 0, stream>>>(ffn_w1, w1T, 512, 2048, 2048, 0);
    mfma_v<<<dim3(32, 4), 256, 0, stream>>>(xb, vwT, qkv_b + 1024, Vh);

    // pre-cast K/V for MFMA attention (overwrites xb/vwT region)
    castkv_k<<<dim3(NN / 64, NB * NH), 256, 0, stream>>>(Kh, Vh, Kb, Vtb);

    // mean of V: two-stage parallel reduction
    meanv_part_k<<<dim3(32, NB * NH), 256, 0, stream>>>(Vh, pmean);
    meanv_comb_k<<<NB * NH, 64, 0, stream>>>(pmean, meanv);

    // row max/mean of scores via concat-fp16 MFMA; emits Marr + rowmax
    // grid (bh=16, m-tiles=32): per-head K-panel stays in one XCD's L2
    rowstat_mfma_k<<<dim3(NB * NH, NN / 64), 256, 0, stream>>>(Qcat, Kcat, Marr, rowmax);
    topk_k<<<NB * NH, 256, 0, stream>>>(Marr, idx);
    fill_k<<<((int)R + 255) / 256, 256, 0, stream>>>(meanv, ctxb);
    attn_mfma_k<<<dim3(NB * NH * KSPLIT, NTOP / 64), 256, 0, stream>>>(
        Qh, Kb, Vtb, idx, rowmax, Opart, ml);
    attn_comb_k<<<NB * NH * NTOP / 4, 256, 0, stream>>>(Opart, ml, idx, ctxb);

    // proj (MFMA, 128x128, m-major grid)
    mfma_gemm<0><<<dim3(32, 4), 256, 0, stream>>>(
        ctxb, NC, owT, out_b, attn_out, (u16*)nullptr, NC, NC, 0);

    // x1 = LN(x + attn_out)
    ln_k<<<NB * NN, 256, 0, stream>>>(x, attn_out, (const u16*)nullptr,
                                      n1_g, n1_b, x1, x1b);

    // FFN (MFMA); FFN2 emits bf16 into the dead ctxb region
    mfma_gemm<0><<<dim3(32, 16), 256, 0, stream>>>(
        x1b, NC, w1T, ffn_b1, (float*)nullptr, hb, DFF, NC, 1);
    mfma_gemm<0><<<dim3(32, 4), 256, 0, stream>>>(
        hb, DFF, w2T, ffn_b2, (float*)nullptr, ffn_outb, NC, DFF, 0);

    // x2 = LN(x1 + ffn_out[bf16]) -> bf16
    ln_k<<<NB * NN, 256, 0, stream>>>(x1, (const float*)nullptr, ffn_outb,
                                      n2_g, n2_b, (float*)nullptr, x2b);

    // fused circular conv1d(k=3): one MFMA GEMM, K=1536, bf16 out
    mfma_gemm<1><<<dim3(32, 4), 256, 0, stream>>>(
        x2b, NC, cwT, conv_b, (float*)nullptr, convyb, NC, 1536, 0);

    pool_ln_k<<<NB * NPOOL, 256, 0, stream>>>(convyb, cn_g, cn_b, (float*)d_out);
}

// Round 6
// 375.413 us; speedup vs baseline: 1.5937x; 1.5937x over previous
//
#include <hip/hip_runtime.h>
#include <math.h>

#define NB 2
#define NN 2048
#define NC 512
#define NH 8
#define DK 64
#define DFF 2048
#define NTOP 512
#define NPOOL 1024
#define KSPLIT 4

typedef unsigned short u16;
typedef __attribute__((ext_vector_type(8))) short frag8;
typedef __attribute__((ext_vector_type(8))) _Float16 h8;
typedef __attribute__((ext_vector_type(4))) float f32x4;

static __device__ __forceinline__ u16 f2b(float f) {
    union { float f; unsigned int u; } v; v.f = f;
    unsigned int r = (v.u + 0x7fffu + ((v.u >> 16) & 1u)) >> 16;
    return (u16)r;
}
static __device__ __forceinline__ float b2f(u16 v) {
    union { unsigned u; float f; } x; x.u = ((unsigned)v) << 16; return x.f;
}
static __device__ __forceinline__ u16 f2h_bits(float f) {
    union { _Float16 h; u16 u; } v; v.h = (_Float16)f; return v.u;
}
static __device__ __forceinline__ float h2f_bits(u16 u) {
    union { u16 u; _Float16 h; } v; v.u = u; return (float)v.h;
}

// =============== bf16 MFMA GEMM: C = A @ Bt^T (+bias)(+gelu), 128x128 tile ========
// Round-4 K-loop body (proven): stage->LDS at loop head, two barriers, VGPR 88.
// Round-5's register prefetch REGRESSED 42->95us (scheduler serialization) — removed.
// m-major grid (m0 = blockIdx.x, gridDim.x = 32 == 0 mod 8): A-panel sharers co-XCD;
// round-5 measured FETCH 34.9 -> 18.1 MB from this mapping — kept.
template<int MODE>
__global__ __launch_bounds__(256) void mfma_gemm(const u16* __restrict__ A, int lda,
    const u16* __restrict__ Bt, const float* __restrict__ bias,
    float* __restrict__ C, u16* __restrict__ Cb, int ldc, int K, int act)
{
    __shared__ u16 As[128][72];
    __shared__ u16 Bs[128][72];
    int tid = threadIdx.x;
    int m0 = blockIdx.x * 128, n0 = blockIdx.y * 128;
    int wave = tid >> 6, lane = tid & 63;
    int ln = lane & 15, quad = lane >> 4;
    int wm = (wave >> 1) * 64, wn = (wave & 1) * 64;
    f32x4 acc[4][4] = {};
    for (int k0 = 0; k0 < K; k0 += 64) {
        #pragma unroll
        for (int i = 0; i < 4; i++) {
            int t = tid + i * 256;
            int m = t >> 3, kq = t & 7;
            size_t aoff;
            if (MODE == 1) {
                int grow = m0 + m;
                int shift = (k0 >> 9) - 1;
                int arow = (grow & ~(NN - 1)) | ((grow + shift) & (NN - 1));
                aoff = (size_t)arow * NC + ((k0 & 511) + kq * 8);
            } else {
                aoff = (size_t)(m0 + m) * lda + k0 + kq * 8;
            }
            *(uint4*)&As[m][kq * 8] = *(const uint4*)&A[aoff];
            *(uint4*)&Bs[m][kq * 8] = *(const uint4*)&Bt[(size_t)(n0 + m) * K + k0 + kq * 8];
        }
        __syncthreads();
        #pragma unroll
        for (int kk = 0; kk < 2; kk++) {
            frag8 af[4], bf[4];
            #pragma unroll
            for (int i = 0; i < 4; i++) {
                af[i] = *(const frag8*)&As[wm + i * 16 + ln][kk * 32 + quad * 8];
                bf[i] = *(const frag8*)&Bs[wn + i * 16 + ln][kk * 32 + quad * 8];
            }
            #pragma unroll
            for (int i = 0; i < 4; i++)
                #pragma unroll
                for (int j = 0; j < 4; j++)
                    acc[i][j] = __builtin_amdgcn_mfma_f32_16x16x32_bf16(
                        af[i], bf[j], acc[i][j], 0, 0, 0);
        }
        __syncthreads();
    }
    #pragma unroll
    for (int i = 0; i < 4; i++) {
        #pragma unroll
        for (int j = 0; j < 4; j++) {
            int col = n0 + wn + j * 16 + ln;
            float bv = bias ? bias[col] : 0.f;
            #pragma unroll
            for (int r = 0; r < 4; r++) {
                int row = m0 + wm + i * 16 + quad * 4 + r;
                float v = acc[i][j][r] + bv;
                if (act == 1) v = 0.5f * v * (1.0f + erff(v * 0.70710678118654752f));
                if (Cb) Cb[(size_t)row * ldc + col] = f2b(v);
                else    C[(size_t)row * ldc + col] = v;
            }
        }
    }
}

// =============== Q/K projection: f16 concat-hi/lo MFMA GEMM (fp32-grade) =========
__global__ __launch_bounds__(256) void mfma_qk(const u16* __restrict__ A,
    const u16* __restrict__ Bt, const float* __restrict__ bias,
    float* __restrict__ Qh, float* __restrict__ Kh,
    u16* __restrict__ Qcat, u16* __restrict__ Kcat)
{
    __shared__ u16 As[128][72];
    __shared__ u16 Bs[128][72];
    int tid = threadIdx.x;
    int m0 = blockIdx.x * 128, n0 = blockIdx.y * 128;
    int wave = tid >> 6, lane = tid & 63;
    int ln = lane & 15, quad = lane >> 4;
    int wm = (wave >> 1) * 64, wn = (wave & 1) * 64;
    f32x4 acc[4][4] = {};
    for (int k0 = 0; k0 < 1024; k0 += 64) {
        #pragma unroll
        for (int i = 0; i < 4; i++) {
            int t = tid + i * 256;
            int m = t >> 3, kq = t & 7;
            *(uint4*)&As[m][kq * 8] = *(const uint4*)&A[(size_t)(m0 + m) * 1024 + k0 + kq * 8];
            *(uint4*)&Bs[m][kq * 8] = *(const uint4*)&Bt[(size_t)(n0 + m) * 1024 + k0 + kq * 8];
        }
        __syncthreads();
        #pragma unroll
        for (int kk = 0; kk < 2; kk++) {
            h8 af[4], bf[4];
            #pragma unroll
            for (int i = 0; i < 4; i++) {
                af[i] = *(const h8*)&As[wm + i * 16 + ln][kk * 32 + quad * 8];
                bf[i] = *(const h8*)&Bs[wn + i * 16 + ln][kk * 32 + quad * 8];
            }
            #pragma unroll
            for (int i = 0; i < 4; i++)
                #pragma unroll
                for (int j = 0; j < 4; j++)
                    acc[i][j] = __builtin_amdgcn_mfma_f32_16x16x32_f16(
                        af[i], bf[j], acc[i][j], 0, 0, 0);
        }
        __syncthreads();
    }
    #pragma unroll
    for (int i = 0; i < 4; i++) {
        #pragma unroll
        for (int j = 0; j < 4; j++) {
            int col = n0 + wn + j * 16 + ln;   // 0..1023 : [Q | K]
            float bv = bias[col];
            int which = col >> 9;
            int h = (col >> 6) & 7, d = col & 63;
            #pragma unroll
            for (int r = 0; r < 4; r++) {
                int row = m0 + wm + i * 16 + quad * 4 + r;
                int b = row >> 11, n = row & (NN - 1);
                float v = acc[i][j][r] + bv;
                size_t off32 = ((size_t)((b << 3) + h) * NN + n) * DK + d;
                size_t offc  = ((size_t)((b << 3) + h) * NN + n) * 128 + d;
                u16 hb_ = f2h_bits(v);
                u16 lb_ = f2h_bits(v - h2f_bits(hb_));
                if (which == 0) {
                    Qh[off32] = v;
                    Qcat[offc] = hb_; Qcat[offc + 64] = lb_;
                } else {
                    Kh[off32] = v;
                    Kcat[offc] = hb_; Kcat[offc + 64] = lb_;
                }
            }
        }
    }
}

// =============== V-projection MFMA with head-major scatter ===============
__global__ __launch_bounds__(256) void mfma_v(const u16* __restrict__ A,
    const u16* __restrict__ Bt, const float* __restrict__ bias, float* __restrict__ Vh)
{
    __shared__ u16 As[128][72];
    __shared__ u16 Bs[128][72];
    int tid = threadIdx.x;
    int m0 = blockIdx.x * 128, n0 = blockIdx.y * 128;
    int wave = tid >> 6, lane = tid & 63;
    int ln = lane & 15, quad = lane >> 4;
    int wm = (wave >> 1) * 64, wn = (wave & 1) * 64;
    f32x4 acc[4][4] = {};
    for (int k0 = 0; k0 < NC; k0 += 64) {
        #pragma unroll
        for (int i = 0; i < 4; i++) {
            int t = tid + i * 256;
            int m = t >> 3, kq = t & 7;
            *(uint4*)&As[m][kq * 8] = *(const uint4*)&A[(size_t)(m0 + m) * NC + k0 + kq * 8];
            *(uint4*)&Bs[m][kq * 8] = *(const uint4*)&Bt[(size_t)(n0 + m) * NC + k0 + kq * 8];
        }
        __syncthreads();
        #pragma unroll
        for (int kk = 0; kk < 2; kk++) {
            frag8 af[4], bf[4];
            #pragma unroll
            for (int i = 0; i < 4; i++) {
                af[i] = *(const frag8*)&As[wm + i * 16 + ln][kk * 32 + quad * 8];
                bf[i] = *(const frag8*)&Bs[wn + i * 16 + ln][kk * 32 + quad * 8];
            }
            #pragma unroll
            for (int i = 0; i < 4; i++)
                #pragma unroll
                for (int j = 0; j < 4; j++)
                    acc[i][j] = __builtin_amdgcn_mfma_f32_16x16x32_bf16(
                        af[i], bf[j], acc[i][j], 0, 0, 0);
        }
        __syncthreads();
    }
    #pragma unroll
    for (int i = 0; i < 4; i++) {
        #pragma unroll
        for (int j = 0; j < 4; j++) {
            int col = n0 + wn + j * 16 + ln;
            int h = col >> 6, d = col & 63;
            float bv = bias[col];
            #pragma unroll
            for (int r = 0; r < 4; r++) {
                int row = m0 + wm + i * 16 + quad * 4 + r;
                int b = row >> 11, n = row & (NN - 1);
                Vh[((size_t)((b << 3) + h) * NN + n) * DK + d] = acc[i][j][r] + bv;
            }
        }
    }
}

// =============== weight cast+transpose (bf16) ===============
__global__ __launch_bounds__(256) void castw_t(const float* __restrict__ in,
    u16* __restrict__ out, int R, int C, int ldi, int coff)
{
    __shared__ float t[32][33];
    int c0 = blockIdx.x * 32, r0 = blockIdx.y * 32;
    int lx = threadIdx.x & 31, ly = threadIdx.x >> 5;
    #pragma unroll
    for (int i = 0; i < 4; i++)
        t[ly + i * 8][lx] = in[(size_t)(r0 + ly + i * 8) * ldi + coff + c0 + lx];
    __syncthreads();
    #pragma unroll
    for (int i = 0; i < 4; i++)
        out[(size_t)(c0 + ly + i * 8) * R + r0 + lx] = f2b(t[lx][ly + i * 8]);
}

// =============== qkv_w cols[0,1024): transpose + fp16 hi/lo concat ===============
__global__ __launch_bounds__(256) void castw_hl(const float* __restrict__ in,
    u16* __restrict__ out)
{
    __shared__ float t[32][33];
    int c0 = blockIdx.x * 32, r0 = blockIdx.y * 32;
    int lx = threadIdx.x & 31, ly = threadIdx.x >> 5;
    #pragma unroll
    for (int i = 0; i < 4; i++)
        t[ly + i * 8][lx] = in[(size_t)(r0 + ly + i * 8) * 1536 + c0 + lx];
    __syncthreads();
    #pragma unroll
    for (int i = 0; i < 4; i++) {
        float v = t[lx][ly + i * 8];
        u16 hb_ = f2h_bits(v);
        u16 lb_ = f2h_bits(v - h2f_bits(hb_));
        size_t ob = (size_t)(c0 + ly + i * 8) * 1024 + r0 + lx;
        out[ob] = hb_;
        out[ob + 512] = lb_;
    }
}

// =============== conv weight cast: [co][ci][t] -> [co][t*512+ci] bf16 ===============
__global__ void castconvw_k(const float* __restrict__ cw, u16* __restrict__ out)
{
    int i = blockIdx.x * 256 + threadIdx.x;
    if (i >= 3 * NC * NC) return;
    int t = i % 3, ci = (i / 3) & (NC - 1), co = i / (3 * NC);
    out[(size_t)co * 1536 + t * NC + ci] = f2b(cw[i]);
}

// =============== x: one read -> bf16 (xb) + concat hi/lo fp16 (xcat) ===============
__global__ void castx_k(const float* __restrict__ in, u16* __restrict__ xb,
                        u16* __restrict__ xcat)
{
    int i = blockIdx.x * 256 + threadIdx.x;
    if (i >= (NB * NN * NC) / 4) return;
    int m = i >> 7, kq = i & 127;
    float4 v = ((const float4*)in)[i];
    ushort4 b, h, l;
    b.x = f2b(v.x); b.y = f2b(v.y); b.z = f2b(v.z); b.w = f2b(v.w);
    h.x = f2h_bits(v.x); h.y = f2h_bits(v.y);
    h.z = f2h_bits(v.z); h.w = f2h_bits(v.w);
    l.x = f2h_bits(v.x - h2f_bits(h.x));
    l.y = f2h_bits(v.y - h2f_bits(h.y));
    l.z = f2h_bits(v.z - h2f_bits(h.z));
    l.w = f2h_bits(v.w - h2f_bits(h.w));
    ((ushort4*)xb)[i] = b;
    *(ushort4*)&xcat[(size_t)m * 1024 + kq * 4] = h;
    *(ushort4*)&xcat[(size_t)m * 1024 + 512 + kq * 4] = l;
}

// =============== K,V -> bf16 (V transposed per bh) ===============
__global__ __launch_bounds__(256) void castkv_k(const float* __restrict__ Kh,
    const float* __restrict__ Vh, u16* __restrict__ Kb, u16* __restrict__ Vtb)
{
    int bh = blockIdx.y;
    int n0 = blockIdx.x * 64;
    __shared__ float vt[64][68];
    int tid = threadIdx.x;
    const float* kin = Kh + ((size_t)bh * NN + n0) * DK;
    u16* kout = Kb + ((size_t)bh * NN + n0) * DK;
    const float* vin = Vh + ((size_t)bh * NN + n0) * DK;
    #pragma unroll
    for (int i = 0; i < 4; i++) {
        int t = tid + i * 256;
        int n = t >> 4, dq = t & 15;
        float4 v = *(const float4*)&kin[(size_t)n * DK + dq * 4];
        ushort4 o;
        o.x = f2b(v.x); o.y = f2b(v.y); o.z = f2b(v.z); o.w = f2b(v.w);
        *(ushort4*)&kout[(size_t)n * DK + dq * 4] = o;
        float4 w = *(const float4*)&vin[(size_t)n * DK + dq * 4];
        vt[dq * 4 + 0][n] = w.x; vt[dq * 4 + 1][n] = w.y;
        vt[dq * 4 + 2][n] = w.z; vt[dq * 4 + 3][n] = w.w;
    }
    __syncthreads();
    #pragma unroll
    for (int i = 0; i < 4; i++) {
        int t = tid + i * 256;
        int d = t >> 4, nq = t & 15;
        float4 v = *(const float4*)&vt[d][nq * 4];
        ushort4 o;
        o.x = f2b(v.x); o.y = f2b(v.y); o.z = f2b(v.z); o.w = f2b(v.w);
        *(ushort4*)&Vtb[((size_t)bh * DK + d) * NN + n0 + nq * 4] = o;
    }
}

// =============== mean of V: stage 1, 512 blocks, coalesced partials ===============
__global__ __launch_bounds__(256) void meanv_part_k(const float* __restrict__ Vh,
    float* __restrict__ pmean)
{
    int bh = blockIdx.y, chunk = blockIdx.x;   // 32 chunks of 64 rows
    int tid = threadIdx.x;
    int d = tid & 63, sub = tid >> 6;
    const float* vb = Vh + ((size_t)bh * NN + chunk * 64 + sub * 16) * DK;
    float s = 0.f;
    #pragma unroll
    for (int r = 0; r < 16; r++) s += vb[(size_t)r * DK + d];
    __shared__ float red[256];
    red[tid] = s;
    __syncthreads();
    if (sub == 0)
        pmean[((size_t)bh * 32 + chunk) * 64 + d] =
            red[d] + red[64 + d] + red[128 + d] + red[192 + d];
}

// =============== mean of V: stage 2 combine ===============
__global__ void meanv_comb_k(const float* __restrict__ pmean, float* __restrict__ meanv)
{
    int bh = blockIdx.x;
    int d = threadIdx.x;   // 64 threads
    float s = 0.f;
    #pragma unroll
    for (int c = 0; c < 32; c++) s += pmean[((size_t)bh * 32 + c) * 64 + d];
    meanv[bh * DK + d] = s * (1.0f / (float)NN);
}

// =============== rowstat via concat-fp16 MFMA; emits Marr and scaled rowmax ========
// bh = blockIdx.x (16 == 0 mod 8): all blocks of one head co-XCD -> K-panel in L2.
// Round-4 staging body (no reg prefetch).
__global__ __launch_bounds__(256) void rowstat_mfma_k(const u16* __restrict__ Qcat,
    const u16* __restrict__ Kcat, float* __restrict__ Marr, float* __restrict__ rowmax)
{
    int bh = blockIdx.x;
    int m0 = blockIdx.y * 64;
    int tid = threadIdx.x;
    int wave = tid >> 6, lane = tid & 63;
    int ln = lane & 15, quad = lane >> 4;
    __shared__ u16 Ks[128][136];
    h8 qf[4];
    {
        const u16* qp = &Qcat[((size_t)bh * NN + m0 + wave * 16 + ln) * 128];
        #pragma unroll
        for (int ks = 0; ks < 4; ks++)
            qf[ks] = *(const h8*)&qp[ks * 32 + quad * 8];
    }
    f32x4 vmax, vsum;
    #pragma unroll
    for (int r = 0; r < 4; r++) { vmax[r] = -INFINITY; vsum[r] = 0.f; }
    const u16* kB = Kcat + (size_t)bh * NN * 128;
    for (int nc = 0; nc < NN; nc += 128) {
        __syncthreads();
        #pragma unroll
        for (int i = 0; i < 8; i++) {
            int e = tid + i * 256;
            int n = e >> 4, kq = e & 15;
            *(uint4*)&Ks[n][kq * 8] = *(const uint4*)&kB[(size_t)(nc + n) * 128 + kq * 8];
        }
        __syncthreads();
        f32x4 accS[8] = {};
        #pragma unroll
        for (int nt = 0; nt < 8; nt++) {
            #pragma unroll
            for (int ks = 0; ks < 4; ks++) {
                h8 kf = *(const h8*)&Ks[nt * 16 + ln][ks * 32 + quad * 8];
                accS[nt] = __builtin_amdgcn_mfma_f32_16x16x32_f16(
                    qf[ks], kf, accS[nt], 0, 0, 0);
            }
        }
        #pragma unroll
        for (int nt = 0; nt < 8; nt++)
            #pragma unroll
            for (int r = 0; r < 4; r++) {
                vmax[r] = fmaxf(vmax[r], accS[nt][r]);
                vsum[r] += accS[nt][r];
            }
    }
    #pragma unroll
    for (int r = 0; r < 4; r++) {
        float mx = vmax[r], sm = vsum[r];
        #pragma unroll
        for (int off = 1; off < 16; off <<= 1) {
            mx = fmaxf(mx, __shfl_xor(mx, off));
            sm += __shfl_xor(sm, off);
        }
        if (ln == 0) {
            int m = m0 + wave * 16 + quad * 4 + r;
            Marr[(size_t)bh * NN + m] = (mx - sm * (1.0f / (float)NN)) * 0.125f;
            rowmax[(size_t)bh * NN + m] = mx * 0.125f;
        }
    }
}

// =============== top-512 per (b,h): radix-select, wave-shfl scans ===============
__global__ __launch_bounds__(256) void topk_k(const float* __restrict__ Marr,
                                              int* __restrict__ idx)
{
    int bh = blockIdx.x;
    const float* Mr = Marr + (size_t)bh * NN;
    int* idxr = idx + (size_t)bh * NTOP;
    __shared__ int hist[256];
    __shared__ int suf[256];
    __shared__ int wred[4], wred2[4];
    __shared__ int bin_sh, rank_sh;
    int tid = threadIdx.x;
    int lane = tid & 63, w = tid >> 6;
    unsigned prefix = 0;
    int rank = NTOP;
    for (int pass = 0; pass < 4; pass++) {
        int shift = 24 - pass * 8;
        unsigned mask_hi = (pass == 0) ? 0u : (0xFFFFFFFFu << (shift + 8));
        hist[tid] = 0;
        __syncthreads();
        for (int i = tid; i < NN; i += 256) {
            union { float f; unsigned u; } v; v.f = Mr[i];
            unsigned k = (v.u & 0x80000000u) ? ~v.u : (v.u | 0x80000000u);
            if ((k & mask_hi) == prefix)
                atomicAdd(&hist[(k >> shift) & 255], 1);
        }
        __syncthreads();
        // inclusive suffix scan: wave-level shfl + cross-wave combine
        int v = hist[tid];
        #pragma unroll
        for (int off = 1; off < 64; off <<= 1) {
            int t = __shfl_down(v, off);
            if (lane + off < 64) v += t;
        }
        if (lane == 0) wred[w] = v;
        __syncthreads();
        int add = 0;
        #pragma unroll
        for (int w2 = 0; w2 < 4; w2++) if (w2 > w) add += wred[w2];
        suf[tid] = v + add;
        __syncthreads();
        int sv = suf[tid];
        int nxt = (tid < 255) ? suf[tid + 1] : 0;
        if (sv >= rank && nxt < rank) { bin_sh = tid; rank_sh = rank - nxt; }
        __syncthreads();
        prefix |= ((unsigned)bin_sh << shift);
        rank = rank_sh;
        __syncthreads();
    }
    union { unsigned u; float f; } tv;
    tv.u = (prefix & 0x80000000u) ? (prefix & 0x7FFFFFFFu) : ~prefix;
    float thr = tv.f;
    int lg = 0, le = 0;
    #pragma unroll
    for (int k = 0; k < 8; k++) {
        float v = Mr[tid * 8 + k];
        lg += (v > thr) ? 1 : 0;
        le += (v == thr) ? 1 : 0;
    }
    // inclusive prefix scans of lg, le via wave shfl
    int vg = lg, ve = le;
    #pragma unroll
    for (int off = 1; off < 64; off <<= 1) {
        int tg = __shfl_up(vg, off);
        int te = __shfl_up(ve, off);
        if (lane >= off) { vg += tg; ve += te; }
    }
    if (lane == 63) { wred[w] = vg; wred2[w] = ve; }
    __syncthreads();
    int addg = 0, adde = 0, totg = 0;
    #pragma unroll
    for (int w2 = 0; w2 < 4; w2++) {
        totg += wred[w2];
        if (w2 < w) { addg += wred[w2]; adde += wred2[w2]; }
    }
    int cnt_gt = totg;
    int needed = NTOP - cnt_gt;
    int gpre = (vg + addg) - lg, epre = (ve + adde) - le;
    #pragma unroll
    for (int k = 0; k < 8; k++) {
        int p = tid * 8 + k;
        float v = Mr[p];
        bool isgt = v > thr, iseq = v == thr;
        bool selv = isgt || (iseq && epre < needed);
        if (selv) idxr[gpre + (epre < needed ? epre : needed)] = p;
        gpre += isgt ? 1 : 0;
        epre += iseq ? 1 : 0;
    }
}

// =============== fill ctx (bf16) with uniform-attention result ===============
__global__ void fill_k(const float* __restrict__ meanv, u16* __restrict__ ctxb)
{
    int i = blockIdx.x * 256 + threadIdx.x;
    if (i >= NB * NN * NC) return;
    int c = i & (NC - 1);
    int m = i >> 9;
    int b = m >> 11;
    int h = c >> 6, d = c & 63;
    ctxb[i] = f2b(meanv[(((b << 3) + h) << 6) + d]);
}

// =============== MFMA flash attention, precomputed rowmax, split-K ===============
// yy = blockIdx.x (64 == 0 mod 8): blocks sharing a (bh,split) K/V range co-XCD.
__global__ __launch_bounds__(256) void attn_mfma_k(const float* __restrict__ Qh,
    const u16* __restrict__ Kb, const u16* __restrict__ Vtb,
    const int* __restrict__ idx, const float* __restrict__ rowmax,
    float* __restrict__ Opart, float* __restrict__ ml)
{
    int yy = blockIdx.x;
    int bh = yy >> 2, split = yy & (KSPLIT - 1);
    int t0 = blockIdx.y * 64;
    int tid = threadIdx.x;
    int wave = tid >> 6, lane = tid & 63;
    int ln = lane & 15, quad = lane >> 4;
    __shared__ u16 Ks[128][72];
    __shared__ u16 Vt[64][136];
    __shared__ u16 Ps[4][16][136];
    __shared__ int rows[64];
    if (tid < 64) rows[tid] = idx[bh * NTOP + t0 + tid];
    __syncthreads();
    frag8 qf[2];
    {
        const float* qp = &Qh[((size_t)bh * NN + rows[wave * 16 + ln]) * DK];
        #pragma unroll
        for (int ks = 0; ks < 2; ks++) {
            float4 a = *(const float4*)&qp[ks * 32 + quad * 8];
            float4 b = *(const float4*)&qp[ks * 32 + quad * 8 + 4];
            union { frag8 f; u16 s[8]; } u;
            u.s[0] = f2b(a.x * 0.125f); u.s[1] = f2b(a.y * 0.125f);
            u.s[2] = f2b(a.z * 0.125f); u.s[3] = f2b(a.w * 0.125f);
            u.s[4] = f2b(b.x * 0.125f); u.s[5] = f2b(b.y * 0.125f);
            u.s[6] = f2b(b.z * 0.125f); u.s[7] = f2b(b.w * 0.125f);
            qf[ks] = u.f;
        }
    }
    float rm[4];
    #pragma unroll
    for (int r = 0; r < 4; r++)
        rm[r] = rowmax[(size_t)bh * NN + rows[wave * 16 + quad * 4 + r]];
    f32x4 accO[4] = {};
    float lrun[4] = {};
    const u16* kbB = Kb + (size_t)bh * NN * DK;
    const u16* vtB = Vtb + (size_t)bh * DK * NN;
    int nc0 = split * (NN / KSPLIT);
    for (int nc = nc0; nc < nc0 + NN / KSPLIT; nc += 128) {
        __syncthreads();
        #pragma unroll
        for (int i = 0; i < 4; i++) {
            int e = tid + i * 256;
            int n = e >> 3, kq = e & 7;
            *(uint4*)&Ks[n][kq * 8] = *(const uint4*)&kbB[(size_t)(nc + n) * DK + kq * 8];
        }
        #pragma unroll
        for (int i = 0; i < 4; i++) {
            int e = tid + i * 256;
            int d = e >> 4, nq = e & 15;
            *(uint4*)&Vt[d][nq * 8] = *(const uint4*)&vtB[(size_t)d * NN + nc + nq * 8];
        }
        __syncthreads();
        f32x4 accS[8] = {};
        #pragma unroll
        for (int nt = 0; nt < 8; nt++) {
            frag8 b0 = *(const frag8*)&Ks[nt * 16 + ln][quad * 8];
            frag8 b1 = *(const frag8*)&Ks[nt * 16 + ln][32 + quad * 8];
            accS[nt] = __builtin_amdgcn_mfma_f32_16x16x32_bf16(qf[0], b0, accS[nt], 0, 0, 0);
            accS[nt] = __builtin_amdgcn_mfma_f32_16x16x32_bf16(qf[1], b1, accS[nt], 0, 0, 0);
        }
        #pragma unroll
        for (int nt = 0; nt < 8; nt++)
            #pragma unroll
            for (int r = 0; r < 4; r++) {
                float p = expf(accS[nt][r] - rm[r]);
                accS[nt][r] = p;
                lrun[r] += p;
            }
        #pragma unroll
        for (int nt = 0; nt < 8; nt++)
            #pragma unroll
            for (int r = 0; r < 4; r++)
                Ps[wave][quad * 4 + r][nt * 16 + ln] = f2b(accS[nt][r]);
        #pragma unroll
        for (int ks = 0; ks < 4; ks++) {
            frag8 pf = *(const frag8*)&Ps[wave][ln][ks * 32 + quad * 8];
            #pragma unroll
            for (int nt2 = 0; nt2 < 4; nt2++) {
                frag8 vf = *(const frag8*)&Vt[nt2 * 16 + ln][ks * 32 + quad * 8];
                accO[nt2] = __builtin_amdgcn_mfma_f32_16x16x32_bf16(pf, vf, accO[nt2], 0, 0, 0);
            }
        }
    }
    #pragma unroll
    for (int r = 0; r < 4; r++) {
        float ls = lrun[r];
        #pragma unroll
        for (int off = 1; off < 16; off <<= 1) ls += __shfl_xor(ls, off);
        int p = t0 + wave * 16 + quad * 4 + r;
        size_t pb = ((size_t)bh * NTOP + p) * KSPLIT + split;
        #pragma unroll
        for (int nt2 = 0; nt2 < 4; nt2++)
            Opart[pb * 64 + nt2 * 16 + ln] = accO[nt2][r];
        if (ln == 0) ml[pb * 2 + 1] = ls;
    }
}

// =============== combine split-K partials -> ctxb (bf16) ===============
// all splits share the same (exact) rowmax -> plain sums
__global__ __launch_bounds__(256) void attn_comb_k(const float* __restrict__ Opart,
    const float* __restrict__ ml, const int* __restrict__ idx,
    u16* __restrict__ ctxb)
{
    int gid = blockIdx.x * 4 + (threadIdx.x >> 6);
    int lane = threadIdx.x & 63;
    int bh = gid >> 9;
    int h = bh & 7, b = bh >> 3;
    size_t base = (size_t)gid * KSPLIT;
    float L = 0.f, O = 0.f;
    #pragma unroll
    for (int s = 0; s < KSPLIT; s++) {
        L += ml[(base + s) * 2 + 1];
        O += Opart[(base + s) * 64 + lane];
    }
    int n = idx[gid];
    ctxb[((size_t)(b * NN + n)) * NC + h * DK + lane] = f2b(O / L);
}

// =============== layernorm; B operand fp32 or bf16; fp32 and/or bf16 out ===========
__global__ __launch_bounds__(256) void ln_k(const float* __restrict__ A,
    const float* __restrict__ Bv, const u16* __restrict__ Bvb,
    const float* __restrict__ g, const float* __restrict__ bb,
    float* __restrict__ out, u16* __restrict__ outb)
{
    int row = blockIdx.x;
    int tid = threadIdx.x;
    __shared__ float v[NC];
    __shared__ float red[256];
    size_t base = (size_t)row * NC;
    for (int i = tid; i < NC; i += 256)
        v[i] = A[base + i] + (Bvb ? b2f(Bvb[base + i]) : Bv[base + i]);
    __syncthreads();
    float ls = 0.f;
    for (int i = tid; i < NC; i += 256) ls += v[i];
    red[tid] = ls; __syncthreads();
    for (int off = 128; off > 0; off >>= 1) {
        if (tid < off) red[tid] += red[tid + off];
        __syncthreads();
    }
    float mu = red[0] / (float)NC;
    __syncthreads();
    float lv = 0.f;
    for (int i = tid; i < NC; i += 256) { float d = v[i] - mu; lv += d * d; }
    red[tid] = lv; __syncthreads();
    for (int off = 128; off > 0; off >>= 1) {
        if (tid < off) red[tid] += red[tid + off];
        __syncthreads();
    }
    float rstd = rsqrtf(red[0] / (float)NC + 1e-5f);
    for (int i = tid; i < NC; i += 256) {
        float r = (v[i] - mu) * rstd * g[i] + bb[i];
        if (out) out[base + i] = r;
        if (outb) outb[base + i] = f2b(r);
    }
}

// =============== maxpool(3,2,1) + ELU + LN over bf16 conv output ===============
__global__ __launch_bounds__(256) void pool_ln_k(const u16* __restrict__ y,
    const float* __restrict__ g, const float* __restrict__ bb,
    float* __restrict__ outp)
{
    int row = blockIdx.x;
    int j = row & (NPOOL - 1), b = row / NPOOL;
    int tid = threadIdx.x;
    __shared__ float v[NC];
    __shared__ float red[256];
    const u16* ybase = y + (size_t)b * NN * NC;
    for (int i = tid; i < NC; i += 256) {
        float m = -INFINITY;
        int p0 = 2 * j - 1;
        #pragma unroll
        for (int t = 0; t < 3; t++) {
            int p = p0 + t;
            if (p >= 0 && p < NN) m = fmaxf(m, b2f(ybase[(size_t)p * NC + i]));
        }
        v[i] = m > 0.f ? m : expm1f(m);
    }
    __syncthreads();
    float ls = 0.f;
    for (int i = tid; i < NC; i += 256) ls += v[i];
    red[tid] = ls; __syncthreads();
    for (int off = 128; off > 0; off >>= 1) {
        if (tid < off) red[tid] += red[tid + off];
        __syncthreads();
    }
    float mu = red[0] / (float)NC;
    __syncthreads();
    float lv = 0.f;
    for (int i = tid; i < NC; i += 256) { float d = v[i] - mu; lv += d * d; }
    red[tid] = lv; __syncthreads();
    for (int off = 128; off > 0; off >>= 1) {
        if (tid < off) red[tid] += red[tid + off];
        __syncthreads();
    }
    float rstd = rsqrtf(red[0] / (float)NC + 1e-5f);
    for (int i = tid; i < NC; i += 256)
        outp[(size_t)row * NC + i] = (v[i] - mu) * rstd * g[i] + bb[i];
}

extern "C" void kernel_launch(void* const* d_in, const int* in_sizes, int n_in,
                              void* d_out, int out_size, void* d_ws, size_t ws_size,
                              hipStream_t stream)
{
    (void)in_sizes; (void)n_in; (void)out_size; (void)ws_size;
    const float* x      = (const float*)d_in[0];
    const float* qkv_w  = (const float*)d_in[1];
    const float* qkv_b  = (const float*)d_in[2];
    const float* out_w  = (const float*)d_in[3];
    const float* out_b  = (const float*)d_in[4];
    const float* ffn_w1 = (const float*)d_in[5];
    const float* ffn_b1 = (const float*)d_in[6];
    const float* ffn_w2 = (const float*)d_in[7];
    const float* ffn_b2 = (const float*)d_in[8];
    const float* n1_g   = (const float*)d_in[9];
    const float* n1_b   = (const float*)d_in[10];
    const float* n2_g   = (const float*)d_in[11];
    const float* n2_b   = (const float*)d_in[12];
    const float* conv_w = (const float*)d_in[13];
    const float* conv_b = (const float*)d_in[14];
    const float* cn_g   = (const float*)d_in[15];
    const float* cn_b   = (const float*)d_in[16];

    const size_t R = (size_t)NB * NN * NC;     // 2097152
    float* ws = (float*)d_ws;
    float* x1   = ws;                 // R : Kcat during rowstat; Opart; LN1 fp32 out
    float* reg2 = ws + R;             // R : xb+vwT -> Kb+Vtb
    float* Qh   = ws + 2 * R;         // R : Q; later attn_out
    float* Kh   = ws + 3 * R;         // R : K; later hb
    float* Vh   = ws + 4 * R;         // R : xcat during proj; V after mfma_v
    size_t o = 5 * R;
    float* pmax  = ws + o;  o += 65536;   // rowmax (scaled) lives here
    float* psum  = ws + o;  o += 65536;   // (kept for layout stability; unused)
    float* Marr  = ws + o;  o += 32768;
    float* pmean = ws + o;  o += 32768;
    float* meanv = ws + o;  o += 1024;
    int*   idx   = (int*)(ws + o);  o += 8192;
    float* ml    = ws + o;  o += 65536;
    u16*   ctxb  = (u16*)(ws + o);  o += R / 2;   // later ffn_outb
    u16*   x1b   = (u16*)(ws + o);  o += R / 2;   // Qcat lower half; later convyb
    u16*   x2b   = (u16*)(ws + o);  o += R / 2;   // Qcat upper half; later LN2 out
    u16*   owT   = (u16*)(ws + o);  o += 131072;
    u16*   w1T   = (u16*)(ws + o);  o += 524288;  // wcatT early, ffn_w1^T after mfma_qk
    u16*   w2T   = (u16*)(ws + o);  o += 524288;
    u16*   cwT   = (u16*)(ws + o);  o += 393216;
    u16*   xb    = (u16*)reg2;                      // R u16 (dead after mfma_v)
    u16*   vwT   = (u16*)(ws + R + R / 2);          // dead after mfma_v
    u16*   Kb    = (u16*)reg2;                      // [16][2048][64] u16
    u16*   Vtb   = (u16*)(ws + R + R / 2);          // [16][64][2048] u16
    float* Opart    = x1;
    float* attn_out = Qh;
    u16*   hb       = (u16*)(ws + 3 * R);
    u16*   ffn_outb = ctxb;           // ctxb dead after proj
    u16*   convyb   = x1b;            // x1b dead after FFN1
    float* rowmax   = pmax;
    // concat-fp16 buffers for the MFMA Q/K projection + rowstat:
    u16*   xcat  = (u16*)Vh;          // [4096][1024] fp16 (2R u16) — dead before mfma_v
    u16*   wcatT = w1T;               // [1024][1024] fp16 — dead before castw_t(ffn_w1)
    u16*   Qcat  = x1b;               // [16][2048][128] fp16 (2R u16 = x1b+x2b)
    u16*   Kcat  = (u16*)x1;          // [16][2048][128] fp16 (2R u16 = x1 region)
    (void)psum;

    // weight / activation casts (w1T region is wcatT until after mfma_qk)
    castw_t<<<dim3(16, 16), 256, 0, stream>>>(out_w, owT, 512, 512, 512, 0);
    castw_t<<<dim3(16, 64), 256, 0, stream>>>(ffn_w2, w2T, 2048, 512, 512, 0);
    castw_t<<<dim3(16, 16), 256, 0, stream>>>(qkv_w, vwT, 512, 512, 1536, 1024);
    castconvw_k<<<3072, 256, 0, stream>>>(conv_w, cwT);
    castx_k<<<2048, 256, 0, stream>>>(x, xb, xcat);
    castw_hl<<<dim3(32, 16), 256, 0, stream>>>(qkv_w, wcatT);

    // Q,K projection via concat-fp16 MFMA (fp32-grade, selection-safe)
    // m-major grid (32 m-tiles on x): A-panel sharers co-XCD
    mfma_qk<<<dim3(32, 8), 256, 0, stream>>>(xcat, wcatT, qkv_b, Qh, Kh, Qcat, Kcat);

    // now wcatT dead -> build real w1T; xcat dead -> V projection may write Vh
    castw_t<<<dim3(64, 16), 256, 0, stream>>>(ffn_w1, w1T, 512, 2048, 2048, 0);
    mfma_v<<<dim3(32, 4), 256, 0, stream>>>(xb, vwT, qkv_b + 1024, Vh);

    // pre-cast K/V for MFMA attention (overwrites xb/vwT region)
    castkv_k<<<dim3(NN / 64, NB * NH), 256, 0, stream>>>(Kh, Vh, Kb, Vtb);

    // mean of V: two-stage parallel reduction
    meanv_part_k<<<dim3(32, NB * NH), 256, 0, stream>>>(Vh, pmean);
    meanv_comb_k<<<NB * NH, 64, 0, stream>>>(pmean, meanv);

    // row max/mean of scores via concat-fp16 MFMA; emits Marr + rowmax
    // grid (bh=16 on x, 32 m-tiles on y): per-head K-panel stays in one XCD's L2
    rowstat_mfma_k<<<dim3(NB * NH, NN / 64), 256, 0, stream>>>(Qcat, Kcat, Marr, rowmax);
    topk_k<<<NB * NH, 256, 0, stream>>>(Marr, idx);
    fill_k<<<((int)R + 255) / 256, 256, 0, stream>>>(meanv, ctxb);
    attn_mfma_k<<<dim3(NB * NH * KSPLIT, NTOP / 64), 256, 0, stream>>>(
        Qh, Kb, Vtb, idx, rowmax, Opart, ml);
    attn_comb_k<<<NB * NH * NTOP / 4, 256, 0, stream>>>(Opart, ml, idx, ctxb);

    // proj (MFMA, 128x128, m-major grid)
    mfma_gemm<0><<<dim3(32, 4), 256, 0, stream>>>(
        ctxb, NC, owT, out_b, attn_out, (u16*)nullptr, NC, NC, 0);

    // x1 = LN(x + attn_out)
    ln_k<<<NB * NN, 256, 0, stream>>>(x, attn_out, (const u16*)nullptr,
                                      n1_g, n1_b, x1, x1b);

    // FFN (MFMA); FFN2 emits bf16 into the dead ctxb region
    mfma_gemm<0><<<dim3(32, 16), 256, 0, stream>>>(
        x1b, NC, w1T, ffn_b1, (float*)nullptr, hb, DFF, NC, 1);
    mfma_gemm<0><<<dim3(32, 4), 256, 0, stream>>>(
        hb, DFF, w2T, ffn_b2, (float*)nullptr, ffn_outb, NC, DFF, 0);

    // x2 = LN(x1 + ffn_out[bf16]) -> bf16
    ln_k<<<NB * NN, 256, 0, stream>>>(x1, (const float*)nullptr, ffn_outb,
                                      n2_g, n2_b, (float*)nullptr, x2b);

    // fused circular conv1d(k=3): one MFMA GEMM, K=1536, bf16 out
    mfma_gemm<1><<<dim3(32, 4), 256, 0, stream>>>(
        x2b, NC, cwT, conv_b, (float*)nullptr, convyb, NC, 1536, 0);

    pool_ln_k<<<NB * NPOOL, 256, 0, stream>>>(convyb, cn_g, cn_b, (float*)d_out);
}

// Round 7
// 343.468 us; speedup vs baseline: 1.7420x; 1.0930x over previous
//
#include <hip/hip_runtime.h>
#include <math.h>

#define NB 2
#define NN 2048
#define NC 512
#define NH 8
#define DK 64
#define DFF 2048
#define NTOP 512
#define NPOOL 1024
#define KSPLIT 4

typedef unsigned short u16;
typedef __attribute__((ext_vector_type(8))) short frag8;
typedef __attribute__((ext_vector_type(8))) _Float16 h8;
typedef __attribute__((ext_vector_type(4))) float f32x4;

static __device__ __forceinline__ u16 f2b(float f) {
    union { float f; unsigned int u; } v; v.f = f;
    unsigned int r = (v.u + 0x7fffu + ((v.u >> 16) & 1u)) >> 16;
    return (u16)r;
}
static __device__ __forceinline__ float b2f(u16 v) {
    union { unsigned u; float f; } x; x.u = ((unsigned)v) << 16; return x.f;
}
static __device__ __forceinline__ u16 f2h_bits(float f) {
    union { _Float16 h; u16 u; } v; v.h = (_Float16)f; return v.u;
}
static __device__ __forceinline__ float h2f_bits(u16 u) {
    union { u16 u; _Float16 h; } v; v.u = u; return (float)v.h;
}

// =============== bf16 MFMA GEMM (full-K): used for FFN1 (+gelu) ===============
// Round-4 proven body. m-major grid: A-panel sharers co-XCD.
template<int MODE>
__global__ __launch_bounds__(256) void mfma_gemm(const u16* __restrict__ A, int lda,
    const u16* __restrict__ Bt, const float* __restrict__ bias,
    float* __restrict__ C, u16* __restrict__ Cb, int ldc, int K, int act)
{
    __shared__ u16 As[128][72];
    __shared__ u16 Bs[128][72];
    int tid = threadIdx.x;
    int m0 = blockIdx.x * 128, n0 = blockIdx.y * 128;
    int wave = tid >> 6, lane = tid & 63;
    int ln = lane & 15, quad = lane >> 4;
    int wm = (wave >> 1) * 64, wn = (wave & 1) * 64;
    f32x4 acc[4][4] = {};
    for (int k0 = 0; k0 < K; k0 += 64) {
        #pragma unroll
        for (int i = 0; i < 4; i++) {
            int t = tid + i * 256;
            int m = t >> 3, kq = t & 7;
            size_t aoff;
            if (MODE == 1) {
                int grow = m0 + m;
                int shift = (k0 >> 9) - 1;
                int arow = (grow & ~(NN - 1)) | ((grow + shift) & (NN - 1));
                aoff = (size_t)arow * NC + ((k0 & 511) + kq * 8);
            } else {
                aoff = (size_t)(m0 + m) * lda + k0 + kq * 8;
            }
            *(uint4*)&As[m][kq * 8] = *(const uint4*)&A[aoff];
            *(uint4*)&Bs[m][kq * 8] = *(const uint4*)&Bt[(size_t)(n0 + m) * K + k0 + kq * 8];
        }
        __syncthreads();
        #pragma unroll
        for (int kk = 0; kk < 2; kk++) {
            frag8 af[4], bf[4];
            #pragma unroll
            for (int i = 0; i < 4; i++) {
                af[i] = *(const frag8*)&As[wm + i * 16 + ln][kk * 32 + quad * 8];
                bf[i] = *(const frag8*)&Bs[wn + i * 16 + ln][kk * 32 + quad * 8];
            }
            #pragma unroll
            for (int i = 0; i < 4; i++)
                #pragma unroll
                for (int j = 0; j < 4; j++)
                    acc[i][j] = __builtin_amdgcn_mfma_f32_16x16x32_bf16(
                        af[i], bf[j], acc[i][j], 0, 0, 0);
        }
        __syncthreads();
    }
    #pragma unroll
    for (int i = 0; i < 4; i++) {
        #pragma unroll
        for (int j = 0; j < 4; j++) {
            int col = n0 + wn + j * 16 + ln;
            float bv = bias ? bias[col] : 0.f;
            #pragma unroll
            for (int r = 0; r < 4; r++) {
                int row = m0 + wm + i * 16 + quad * 4 + r;
                float v = acc[i][j][r] + bv;
                if (act == 1) v = 0.5f * v * (1.0f + erff(v * 0.70710678118654752f));
                if (Cb) Cb[(size_t)row * ldc + col] = f2b(v);
                else    C[(size_t)row * ldc + col] = v;
            }
        }
    }
}

// =============== split-K x2 MFMA GEMM: fp32 partials, no bias/act ===============
// proj/FFN2/conv have only 128 wg (half the CUs idle). Split-K doubles the grid
// WITHOUT duplicating A-fetch (round-3 lesson: BN-split doubles it). Partials are
// combined for free in the consumer (ln_k / pool_ln_k already do an add).
template<int MODE>
__global__ __launch_bounds__(256) void mfma_gemm_sk(const u16* __restrict__ A, int lda,
    const u16* __restrict__ Bt, float* __restrict__ P0, float* __restrict__ P1,
    int ldc, int K)
{
    __shared__ u16 As[128][72];
    __shared__ u16 Bs[128][72];
    int tid = threadIdx.x;
    int m0 = blockIdx.x * 128, n0 = blockIdx.y * 128;
    int split = blockIdx.z;
    int K2 = K >> 1, kbeg = split * K2;
    int wave = tid >> 6, lane = tid & 63;
    int ln = lane & 15, quad = lane >> 4;
    int wm = (wave >> 1) * 64, wn = (wave & 1) * 64;
    f32x4 acc[4][4] = {};
    for (int k0 = kbeg; k0 < kbeg + K2; k0 += 64) {
        #pragma unroll
        for (int i = 0; i < 4; i++) {
            int t = tid + i * 256;
            int m = t >> 3, kq = t & 7;
            size_t aoff;
            if (MODE == 1) {
                int grow = m0 + m;
                int shift = (k0 >> 9) - 1;
                int arow = (grow & ~(NN - 1)) | ((grow + shift) & (NN - 1));
                aoff = (size_t)arow * NC + ((k0 & 511) + kq * 8);
            } else {
                aoff = (size_t)(m0 + m) * lda + k0 + kq * 8;
            }
            *(uint4*)&As[m][kq * 8] = *(const uint4*)&A[aoff];
            *(uint4*)&Bs[m][kq * 8] = *(const uint4*)&Bt[(size_t)(n0 + m) * K + k0 + kq * 8];
        }
        __syncthreads();
        #pragma unroll
        for (int kk = 0; kk < 2; kk++) {
            frag8 af[4], bf[4];
            #pragma unroll
            for (int i = 0; i < 4; i++) {
                af[i] = *(const frag8*)&As[wm + i * 16 + ln][kk * 32 + quad * 8];
                bf[i] = *(const frag8*)&Bs[wn + i * 16 + ln][kk * 32 + quad * 8];
            }
            #pragma unroll
            for (int i = 0; i < 4; i++)
                #pragma unroll
                for (int j = 0; j < 4; j++)
                    acc[i][j] = __builtin_amdgcn_mfma_f32_16x16x32_bf16(
                        af[i], bf[j], acc[i][j], 0, 0, 0);
        }
        __syncthreads();
    }
    float* P = split ? P1 : P0;
    #pragma unroll
    for (int i = 0; i < 4; i++) {
        #pragma unroll
        for (int j = 0; j < 4; j++) {
            int col = n0 + wn + j * 16 + ln;
            #pragma unroll
            for (int r = 0; r < 4; r++) {
                int row = m0 + wm + i * 16 + quad * 4 + r;
                P[(size_t)row * ldc + col] = acc[i][j][r];
            }
        }
    }
}

// =============== Q/K projection: f16 concat-hi/lo MFMA GEMM (fp32-grade) =========
__global__ __launch_bounds__(256) void mfma_qk(const u16* __restrict__ A,
    const u16* __restrict__ Bt, const float* __restrict__ bias,
    float* __restrict__ Qh, float* __restrict__ Kh,
    u16* __restrict__ Qcat, u16* __restrict__ Kcat)
{
    __shared__ u16 As[128][72];
    __shared__ u16 Bs[128][72];
    int tid = threadIdx.x;
    int m0 = blockIdx.x * 128, n0 = blockIdx.y * 128;
    int wave = tid >> 6, lane = tid & 63;
    int ln = lane & 15, quad = lane >> 4;
    int wm = (wave >> 1) * 64, wn = (wave & 1) * 64;
    f32x4 acc[4][4] = {};
    for (int k0 = 0; k0 < 1024; k0 += 64) {
        #pragma unroll
        for (int i = 0; i < 4; i++) {
            int t = tid + i * 256;
            int m = t >> 3, kq = t & 7;
            *(uint4*)&As[m][kq * 8] = *(const uint4*)&A[(size_t)(m0 + m) * 1024 + k0 + kq * 8];
            *(uint4*)&Bs[m][kq * 8] = *(const uint4*)&Bt[(size_t)(n0 + m) * 1024 + k0 + kq * 8];
        }
        __syncthreads();
        #pragma unroll
        for (int kk = 0; kk < 2; kk++) {
            h8 af[4], bf[4];
            #pragma unroll
            for (int i = 0; i < 4; i++) {
                af[i] = *(const h8*)&As[wm + i * 16 + ln][kk * 32 + quad * 8];
                bf[i] = *(const h8*)&Bs[wn + i * 16 + ln][kk * 32 + quad * 8];
            }
            #pragma unroll
            for (int i = 0; i < 4; i++)
                #pragma unroll
                for (int j = 0; j < 4; j++)
                    acc[i][j] = __builtin_amdgcn_mfma_f32_16x16x32_f16(
                        af[i], bf[j], acc[i][j], 0, 0, 0);
        }
        __syncthreads();
    }
    #pragma unroll
    for (int i = 0; i < 4; i++) {
        #pragma unroll
        for (int j = 0; j < 4; j++) {
            int col = n0 + wn + j * 16 + ln;   // 0..1023 : [Q | K]
            float bv = bias[col];
            int which = col >> 9;
            int h = (col >> 6) & 7, d = col & 63;
            #pragma unroll
            for (int r = 0; r < 4; r++) {
                int row = m0 + wm + i * 16 + quad * 4 + r;
                int b = row >> 11, n = row & (NN - 1);
                float v = acc[i][j][r] + bv;
                size_t off32 = ((size_t)((b << 3) + h) * NN + n) * DK + d;
                size_t offc  = ((size_t)((b << 3) + h) * NN + n) * 128 + d;
                u16 hb_ = f2h_bits(v);
                u16 lb_ = f2h_bits(v - h2f_bits(hb_));
                if (which == 0) {
                    Qh[off32] = v;
                    Qcat[offc] = hb_; Qcat[offc + 64] = lb_;
                } else {
                    Kh[off32] = v;
                    Kcat[offc] = hb_; Kcat[offc + 64] = lb_;
                }
            }
        }
    }
}

// =============== V-projection MFMA with head-major scatter ===============
__global__ __launch_bounds__(256) void mfma_v(const u16* __restrict__ A,
    const u16* __restrict__ Bt, const float* __restrict__ bias, float* __restrict__ Vh)
{
    __shared__ u16 As[128][72];
    __shared__ u16 Bs[128][72];
    int tid = threadIdx.x;
    int m0 = blockIdx.x * 128, n0 = blockIdx.y * 128;
    int wave = tid >> 6, lane = tid & 63;
    int ln = lane & 15, quad = lane >> 4;
    int wm = (wave >> 1) * 64, wn = (wave & 1) * 64;
    f32x4 acc[4][4] = {};
    for (int k0 = 0; k0 < NC; k0 += 64) {
        #pragma unroll
        for (int i = 0; i < 4; i++) {
            int t = tid + i * 256;
            int m = t >> 3, kq = t & 7;
            *(uint4*)&As[m][kq * 8] = *(const uint4*)&A[(size_t)(m0 + m) * NC + k0 + kq * 8];
            *(uint4*)&Bs[m][kq * 8] = *(const uint4*)&Bt[(size_t)(n0 + m) * NC + k0 + kq * 8];
        }
        __syncthreads();
        #pragma unroll
        for (int kk = 0; kk < 2; kk++) {
            frag8 af[4], bf[4];
            #pragma unroll
            for (int i = 0; i < 4; i++) {
                af[i] = *(const frag8*)&As[wm + i * 16 + ln][kk * 32 + quad * 8];
                bf[i] = *(const frag8*)&Bs[wn + i * 16 + ln][kk * 32 + quad * 8];
            }
            #pragma unroll
            for (int i = 0; i < 4; i++)
                #pragma unroll
                for (int j = 0; j < 4; j++)
                    acc[i][j] = __builtin_amdgcn_mfma_f32_16x16x32_bf16(
                        af[i], bf[j], acc[i][j], 0, 0, 0);
        }
        __syncthreads();
    }
    #pragma unroll
    for (int i = 0; i < 4; i++) {
        #pragma unroll
        for (int j = 0; j < 4; j++) {
            int col = n0 + wn + j * 16 + ln;
            int h = col >> 6, d = col & 63;
            float bv = bias[col];
            #pragma unroll
            for (int r = 0; r < 4; r++) {
                int row = m0 + wm + i * 16 + quad * 4 + r;
                int b = row >> 11, n = row & (NN - 1);
                Vh[((size_t)((b << 3) + h) * NN + n) * DK + d] = acc[i][j][r] + bv;
            }
        }
    }
}

// =============== weight cast+transpose (bf16) ===============
__global__ __launch_bounds__(256) void castw_t(const float* __restrict__ in,
    u16* __restrict__ out, int R, int C, int ldi, int coff)
{
    __shared__ float t[32][33];
    int c0 = blockIdx.x * 32, r0 = blockIdx.y * 32;
    int lx = threadIdx.x & 31, ly = threadIdx.x >> 5;
    #pragma unroll
    for (int i = 0; i < 4; i++)
        t[ly + i * 8][lx] = in[(size_t)(r0 + ly + i * 8) * ldi + coff + c0 + lx];
    __syncthreads();
    #pragma unroll
    for (int i = 0; i < 4; i++)
        out[(size_t)(c0 + ly + i * 8) * R + r0 + lx] = f2b(t[lx][ly + i * 8]);
}

// =============== qkv_w cols[0,1024): transpose + fp16 hi/lo concat ===============
__global__ __launch_bounds__(256) void castw_hl(const float* __restrict__ in,
    u16* __restrict__ out)
{
    __shared__ float t[32][33];
    int c0 = blockIdx.x * 32, r0 = blockIdx.y * 32;
    int lx = threadIdx.x & 31, ly = threadIdx.x >> 5;
    #pragma unroll
    for (int i = 0; i < 4; i++)
        t[ly + i * 8][lx] = in[(size_t)(r0 + ly + i * 8) * 1536 + c0 + lx];
    __syncthreads();
    #pragma unroll
    for (int i = 0; i < 4; i++) {
        float v = t[lx][ly + i * 8];
        u16 hb_ = f2h_bits(v);
        u16 lb_ = f2h_bits(v - h2f_bits(hb_));
        size_t ob = (size_t)(c0 + ly + i * 8) * 1024 + r0 + lx;
        out[ob] = hb_;
        out[ob + 512] = lb_;
    }
}

// =============== conv weight cast: [co][ci][t] -> [co][t*512+ci] bf16 ===============
__global__ void castconvw_k(const float* __restrict__ cw, u16* __restrict__ out)
{
    int i = blockIdx.x * 256 + threadIdx.x;
    if (i >= 3 * NC * NC) return;
    int t = i % 3, ci = (i / 3) & (NC - 1), co = i / (3 * NC);
    out[(size_t)co * 1536 + t * NC + ci] = f2b(cw[i]);
}

// =============== x: one read -> bf16 (xb) + concat hi/lo fp16 (xcat) ===============
__global__ void castx_k(const float* __restrict__ in, u16* __restrict__ xb,
                        u16* __restrict__ xcat)
{
    int i = blockIdx.x * 256 + threadIdx.x;
    if (i >= (NB * NN * NC) / 4) return;
    int m = i >> 7, kq = i & 127;
    float4 v = ((const float4*)in)[i];
    ushort4 b, h, l;
    b.x = f2b(v.x); b.y = f2b(v.y); b.z = f2b(v.z); b.w = f2b(v.w);
    h.x = f2h_bits(v.x); h.y = f2h_bits(v.y);
    h.z = f2h_bits(v.z); h.w = f2h_bits(v.w);
    l.x = f2h_bits(v.x - h2f_bits(h.x));
    l.y = f2h_bits(v.y - h2f_bits(h.y));
    l.z = f2h_bits(v.z - h2f_bits(h.z));
    l.w = f2h_bits(v.w - h2f_bits(h.w));
    ((ushort4*)xb)[i] = b;
    *(ushort4*)&xcat[(size_t)m * 1024 + kq * 4] = h;
    *(ushort4*)&xcat[(size_t)m * 1024 + 512 + kq * 4] = l;
}

// =============== K,V -> bf16 (V transposed per bh) ===============
__global__ __launch_bounds__(256) void castkv_k(const float* __restrict__ Kh,
    const float* __restrict__ Vh, u16* __restrict__ Kb, u16* __restrict__ Vtb)
{
    int bh = blockIdx.y;
    int n0 = blockIdx.x * 64;
    __shared__ float vt[64][68];
    int tid = threadIdx.x;
    const float* kin = Kh + ((size_t)bh * NN + n0) * DK;
    u16* kout = Kb + ((size_t)bh * NN + n0) * DK;
    const float* vin = Vh + ((size_t)bh * NN + n0) * DK;
    #pragma unroll
    for (int i = 0; i < 4; i++) {
        int t = tid + i * 256;
        int n = t >> 4, dq = t & 15;
        float4 v = *(const float4*)&kin[(size_t)n * DK + dq * 4];
        ushort4 o;
        o.x = f2b(v.x); o.y = f2b(v.y); o.z = f2b(v.z); o.w = f2b(v.w);
        *(ushort4*)&kout[(size_t)n * DK + dq * 4] = o;
        float4 w = *(const float4*)&vin[(size_t)n * DK + dq * 4];
        vt[dq * 4 + 0][n] = w.x; vt[dq * 4 + 1][n] = w.y;
        vt[dq * 4 + 2][n] = w.z; vt[dq * 4 + 3][n] = w.w;
    }
    __syncthreads();
    #pragma unroll
    for (int i = 0; i < 4; i++) {
        int t = tid + i * 256;
        int d = t >> 4, nq = t & 15;
        float4 v = *(const float4*)&vt[d][nq * 4];
        ushort4 o;
        o.x = f2b(v.x); o.y = f2b(v.y); o.z = f2b(v.z); o.w = f2b(v.w);
        *(ushort4*)&Vtb[((size_t)bh * DK + d) * NN + n0 + nq * 4] = o;
    }
}

// =============== mean of V: stage 1, 512 blocks, coalesced partials ===============
__global__ __launch_bounds__(256) void meanv_part_k(const float* __restrict__ Vh,
    float* __restrict__ pmean)
{
    int bh = blockIdx.y, chunk = blockIdx.x;   // 32 chunks of 64 rows
    int tid = threadIdx.x;
    int d = tid & 63, sub = tid >> 6;
    const float* vb = Vh + ((size_t)bh * NN + chunk * 64 + sub * 16) * DK;
    float s = 0.f;
    #pragma unroll
    for (int r = 0; r < 16; r++) s += vb[(size_t)r * DK + d];
    __shared__ float red[256];
    red[tid] = s;
    __syncthreads();
    if (sub == 0)
        pmean[((size_t)bh * 32 + chunk) * 64 + d] =
            red[d] + red[64 + d] + red[128 + d] + red[192 + d];
}

// =============== mean of V: stage 2 combine ===============
__global__ void meanv_comb_k(const float* __restrict__ pmean, float* __restrict__ meanv)
{
    int bh = blockIdx.x;
    int d = threadIdx.x;   // 64 threads
    float s = 0.f;
    #pragma unroll
    for (int c = 0; c < 32; c++) s += pmean[((size_t)bh * 32 + c) * 64 + d];
    meanv[bh * DK + d] = s * (1.0f / (float)NN);
}

// =============== rowstat via concat-fp16 MFMA; emits Marr and scaled rowmax ========
__global__ __launch_bounds__(256) void rowstat_mfma_k(const u16* __restrict__ Qcat,
    const u16* __restrict__ Kcat, float* __restrict__ Marr, float* __restrict__ rowmax)
{
    int bh = blockIdx.x;
    int m0 = blockIdx.y * 64;
    int tid = threadIdx.x;
    int wave = tid >> 6, lane = tid & 63;
    int ln = lane & 15, quad = lane >> 4;
    __shared__ u16 Ks[128][136];
    h8 qf[4];
    {
        const u16* qp = &Qcat[((size_t)bh * NN + m0 + wave * 16 + ln) * 128];
        #pragma unroll
        for (int ks = 0; ks < 4; ks++)
            qf[ks] = *(const h8*)&qp[ks * 32 + quad * 8];
    }
    f32x4 vmax, vsum;
    #pragma unroll
    for (int r = 0; r < 4; r++) { vmax[r] = -INFINITY; vsum[r] = 0.f; }
    const u16* kB = Kcat + (size_t)bh * NN * 128;
    for (int nc = 0; nc < NN; nc += 128) {
        __syncthreads();
        #pragma unroll
        for (int i = 0; i < 8; i++) {
            int e = tid + i * 256;
            int n = e >> 4, kq = e & 15;
            *(uint4*)&Ks[n][kq * 8] = *(const uint4*)&kB[(size_t)(nc + n) * 128 + kq * 8];
        }
        __syncthreads();
        f32x4 accS[8] = {};
        #pragma unroll
        for (int nt = 0; nt < 8; nt++) {
            #pragma unroll
            for (int ks = 0; ks < 4; ks++) {
                h8 kf = *(const h8*)&Ks[nt * 16 + ln][ks * 32 + quad * 8];
                accS[nt] = __builtin_amdgcn_mfma_f32_16x16x32_f16(
                    qf[ks], kf, accS[nt], 0, 0, 0);
            }
        }
        #pragma unroll
        for (int nt = 0; nt < 8; nt++)
            #pragma unroll
            for (int r = 0; r < 4; r++) {
                vmax[r] = fmaxf(vmax[r], accS[nt][r]);
                vsum[r] += accS[nt][r];
            }
    }
    #pragma unroll
    for (int r = 0; r < 4; r++) {
        float mx = vmax[r], sm = vsum[r];
        #pragma unroll
        for (int off = 1; off < 16; off <<= 1) {
            mx = fmaxf(mx, __shfl_xor(mx, off));
            sm += __shfl_xor(sm, off);
        }
        if (ln == 0) {
            int m = m0 + wave * 16 + quad * 4 + r;
            Marr[(size_t)bh * NN + m] = (mx - sm * (1.0f / (float)NN)) * 0.125f;
            rowmax[(size_t)bh * NN + m] = mx * 0.125f;
        }
    }
}

// =============== top-512 per (b,h): radix-select, wave-shfl scans ===============
__global__ __launch_bounds__(256) void topk_k(const float* __restrict__ Marr,
                                              int* __restrict__ idx)
{
    int bh = blockIdx.x;
    const float* Mr = Marr + (size_t)bh * NN;
    int* idxr = idx + (size_t)bh * NTOP;
    __shared__ int hist[256];
    __shared__ int suf[256];
    __shared__ int wred[4], wred2[4];
    __shared__ int bin_sh, rank_sh;
    int tid = threadIdx.x;
    int lane = tid & 63, w = tid >> 6;
    unsigned prefix = 0;
    int rank = NTOP;
    for (int pass = 0; pass < 4; pass++) {
        int shift = 24 - pass * 8;
        unsigned mask_hi = (pass == 0) ? 0u : (0xFFFFFFFFu << (shift + 8));
        hist[tid] = 0;
        __syncthreads();
        for (int i = tid; i < NN; i += 256) {
            union { float f; unsigned u; } v; v.f = Mr[i];
            unsigned k = (v.u & 0x80000000u) ? ~v.u : (v.u | 0x80000000u);
            if ((k & mask_hi) == prefix)
                atomicAdd(&hist[(k >> shift) & 255], 1);
        }
        __syncthreads();
        int v = hist[tid];
        #pragma unroll
        for (int off = 1; off < 64; off <<= 1) {
            int t = __shfl_down(v, off);
            if (lane + off < 64) v += t;
        }
        if (lane == 0) wred[w] = v;
        __syncthreads();
        int add = 0;
        #pragma unroll
        for (int w2 = 0; w2 < 4; w2++) if (w2 > w) add += wred[w2];
        suf[tid] = v + add;
        __syncthreads();
        int sv = suf[tid];
        int nxt = (tid < 255) ? suf[tid + 1] : 0;
        if (sv >= rank && nxt < rank) { bin_sh = tid; rank_sh = rank - nxt; }
        __syncthreads();
        prefix |= ((unsigned)bin_sh << shift);
        rank = rank_sh;
        __syncthreads();
    }
    union { unsigned u; float f; } tv;
    tv.u = (prefix & 0x80000000u) ? (prefix & 0x7FFFFFFFu) : ~prefix;
    float thr = tv.f;
    int lg = 0, le = 0;
    #pragma unroll
    for (int k = 0; k < 8; k++) {
        float v = Mr[tid * 8 + k];
        lg += (v > thr) ? 1 : 0;
        le += (v == thr) ? 1 : 0;
    }
    int vg = lg, ve = le;
    #pragma unroll
    for (int off = 1; off < 64; off <<= 1) {
        int tg = __shfl_up(vg, off);
        int te = __shfl_up(ve, off);
        if (lane >= off) { vg += tg; ve += te; }
    }
    if (lane == 63) { wred[w] = vg; wred2[w] = ve; }
    __syncthreads();
    int addg = 0, adde = 0, totg = 0;
    #pragma unroll
    for (int w2 = 0; w2 < 4; w2++) {
        totg += wred[w2];
        if (w2 < w) { addg += wred[w2]; adde += wred2[w2]; }
    }
    int cnt_gt = totg;
    int needed = NTOP - cnt_gt;
    int gpre = (vg + addg) - lg, epre = (ve + adde) - le;
    #pragma unroll
    for (int k = 0; k < 8; k++) {
        int p = tid * 8 + k;
        float v = Mr[p];
        bool isgt = v > thr, iseq = v == thr;
        bool selv = isgt || (iseq && epre < needed);
        if (selv) idxr[gpre + (epre < needed ? epre : needed)] = p;
        gpre += isgt ? 1 : 0;
        epre += iseq ? 1 : 0;
    }
}

// =============== fill ctx (bf16) with uniform-attention result ===============
__global__ void fill_k(const float* __restrict__ meanv, u16* __restrict__ ctxb)
{
    int i = blockIdx.x * 256 + threadIdx.x;
    if (i >= NB * NN * NC) return;
    int c = i & (NC - 1);
    int m = i >> 9;
    int b = m >> 11;
    int h = c >> 6, d = c & 63;
    ctxb[i] = f2b(meanv[(((b << 3) + h) << 6) + d]);
}

// =============== MFMA flash attention, precomputed rowmax, split-K ===============
__global__ __launch_bounds__(256) void attn_mfma_k(const float* __restrict__ Qh,
    const u16* __restrict__ Kb, const u16* __restrict__ Vtb,
    const int* __restrict__ idx, const float* __restrict__ rowmax,
    float* __restrict__ Opart, float* __restrict__ ml)
{
    int yy = blockIdx.x;
    int bh = yy >> 2, split = yy & (KSPLIT - 1);
    int t0 = blockIdx.y * 64;
    int tid = threadIdx.x;
    int wave = tid >> 6, lane = tid & 63;
    int ln = lane & 15, quad = lane >> 4;
    __shared__ u16 Ks[128][72];
    __shared__ u16 Vt[64][136];
    __shared__ u16 Ps[4][16][136];
    __shared__ int rows[64];
    if (tid < 64) rows[tid] = idx[bh * NTOP + t0 + tid];
    __syncthreads();
    frag8 qf[2];
    {
        const float* qp = &Qh[((size_t)bh * NN + rows[wave * 16 + ln]) * DK];
        #pragma unroll
        for (int ks = 0; ks < 2; ks++) {
            float4 a = *(const float4*)&qp[ks * 32 + quad * 8];
            float4 b = *(const float4*)&qp[ks * 32 + quad * 8 + 4];
            union { frag8 f; u16 s[8]; } u;
            u.s[0] = f2b(a.x * 0.125f); u.s[1] = f2b(a.y * 0.125f);
            u.s[2] = f2b(a.z * 0.125f); u.s[3] = f2b(a.w * 0.125f);
            u.s[4] = f2b(b.x * 0.125f); u.s[5] = f2b(b.y * 0.125f);
            u.s[6] = f2b(b.z * 0.125f); u.s[7] = f2b(b.w * 0.125f);
            qf[ks] = u.f;
        }
    }
    float rm[4];
    #pragma unroll
    for (int r = 0; r < 4; r++)
        rm[r] = rowmax[(size_t)bh * NN + rows[wave * 16 + quad * 4 + r]];
    f32x4 accO[4] = {};
    float lrun[4] = {};
    const u16* kbB = Kb + (size_t)bh * NN * DK;
    const u16* vtB = Vtb + (size_t)bh * DK * NN;
    int nc0 = split * (NN / KSPLIT);
    for (int nc = nc0; nc < nc0 + NN / KSPLIT; nc += 128) {
        __syncthreads();
        #pragma unroll
        for (int i = 0; i < 4; i++) {
            int e = tid + i * 256;
            int n = e >> 3, kq = e & 7;
            *(uint4*)&Ks[n][kq * 8] = *(const uint4*)&kbB[(size_t)(nc + n) * DK + kq * 8];
        }
        #pragma unroll
        for (int i = 0; i < 4; i++) {
            int e = tid + i * 256;
            int d = e >> 4, nq = e & 15;
            *(uint4*)&Vt[d][nq * 8] = *(const uint4*)&vtB[(size_t)d * NN + nc + nq * 8];
        }
        __syncthreads();
        f32x4 accS[8] = {};
        #pragma unroll
        for (int nt = 0; nt < 8; nt++) {
            frag8 b0 = *(const frag8*)&Ks[nt * 16 + ln][quad * 8];
            frag8 b1 = *(const frag8*)&Ks[nt * 16 + ln][32 + quad * 8];
            accS[nt] = __builtin_amdgcn_mfma_f32_16x16x32_bf16(qf[0], b0, accS[nt], 0, 0, 0);
            accS[nt] = __builtin_amdgcn_mfma_f32_16x16x32_bf16(qf[1], b1, accS[nt], 0, 0, 0);
        }
        #pragma unroll
        for (int nt = 0; nt < 8; nt++)
            #pragma unroll
            for (int r = 0; r < 4; r++) {
                float p = expf(accS[nt][r] - rm[r]);
                accS[nt][r] = p;
                lrun[r] += p;
            }
        #pragma unroll
        for (int nt = 0; nt < 8; nt++)
            #pragma unroll
            for (int r = 0; r < 4; r++)
                Ps[wave][quad * 4 + r][nt * 16 + ln] = f2b(accS[nt][r]);
        #pragma unroll
        for (int ks = 0; ks < 4; ks++) {
            frag8 pf = *(const frag8*)&Ps[wave][ln][ks * 32 + quad * 8];
            #pragma unroll
            for (int nt2 = 0; nt2 < 4; nt2++) {
                frag8 vf = *(const frag8*)&Vt[nt2 * 16 + ln][ks * 32 + quad * 8];
                accO[nt2] = __builtin_amdgcn_mfma_f32_16x16x32_bf16(pf, vf, accO[nt2], 0, 0, 0);
            }
        }
    }
    #pragma unroll
    for (int r = 0; r < 4; r++) {
        float ls = lrun[r];
        #pragma unroll
        for (int off = 1; off < 16; off <<= 1) ls += __shfl_xor(ls, off);
        int p = t0 + wave * 16 + quad * 4 + r;
        size_t pb = ((size_t)bh * NTOP + p) * KSPLIT + split;
        #pragma unroll
        for (int nt2 = 0; nt2 < 4; nt2++)
            Opart[pb * 64 + nt2 * 16 + ln] = accO[nt2][r];
        if (ln == 0) ml[pb * 2 + 1] = ls;
    }
}

// =============== combine split-K partials -> ctxb (bf16) ===============
__global__ __launch_bounds__(256) void attn_comb_k(const float* __restrict__ Opart,
    const float* __restrict__ ml, const int* __restrict__ idx,
    u16* __restrict__ ctxb)
{
    int gid = blockIdx.x * 4 + (threadIdx.x >> 6);
    int lane = threadIdx.x & 63;
    int bh = gid >> 9;
    int h = bh & 7, b = bh >> 3;
    size_t base = (size_t)gid * KSPLIT;
    float L = 0.f, O = 0.f;
    #pragma unroll
    for (int s = 0; s < KSPLIT; s++) {
        L += ml[(base + s) * 2 + 1];
        O += Opart[(base + s) * 64 + lane];
    }
    int n = idx[gid];
    ctxb[((size_t)(b * NN + n)) * NC + h * DK + lane] = f2b(O / L);
}

// =============== layernorm of A + P0 + P1 + cb; fp32 and/or bf16 out ===============
__global__ __launch_bounds__(256) void ln_k(const float* __restrict__ A,
    const float* __restrict__ P0, const float* __restrict__ P1,
    const float* __restrict__ cb,
    const float* __restrict__ g, const float* __restrict__ bb,
    float* __restrict__ out, u16* __restrict__ outb)
{
    int row = blockIdx.x;
    int tid = threadIdx.x;
    __shared__ float v[NC];
    __shared__ float red[256];
    size_t base = (size_t)row * NC;
    for (int i = tid; i < NC; i += 256)
        v[i] = A[base + i] + P0[base + i] + P1[base + i] + cb[i];
    __syncthreads();
    float ls = 0.f;
    for (int i = tid; i < NC; i += 256) ls += v[i];
    red[tid] = ls; __syncthreads();
    for (int off = 128; off > 0; off >>= 1) {
        if (tid < off) red[tid] += red[tid + off];
        __syncthreads();
    }
    float mu = red[0] / (float)NC;
    __syncthreads();
    float lv = 0.f;
    for (int i = tid; i < NC; i += 256) { float d = v[i] - mu; lv += d * d; }
    red[tid] = lv; __syncthreads();
    for (int off = 128; off > 0; off >>= 1) {
        if (tid < off) red[tid] += red[tid + off];
        __syncthreads();
    }
    float rstd = rsqrtf(red[0] / (float)NC + 1e-5f);
    for (int i = tid; i < NC; i += 256) {
        float r = (v[i] - mu) * rstd * g[i] + bb[i];
        if (out) out[base + i] = r;
        if (outb) outb[base + i] = f2b(r);
    }
}

// =============== maxpool(3,2,1) + ELU + LN over conv partials (fp32) ===============
__global__ __launch_bounds__(256) void pool_ln_k(const float* __restrict__ P0,
    const float* __restrict__ P1, const float* __restrict__ cb,
    const float* __restrict__ g, const float* __restrict__ bb,
    float* __restrict__ outp)
{
    int row = blockIdx.x;
    int j = row & (NPOOL - 1), b = row / NPOOL;
    int tid = threadIdx.x;
    __shared__ float v[NC];
    __shared__ float red[256];
    size_t bbase = (size_t)b * NN * NC;
    for (int i = tid; i < NC; i += 256) {
        float m = -INFINITY;
        int p0 = 2 * j - 1;
        float cbv = cb[i];
        #pragma unroll
        for (int t = 0; t < 3; t++) {
            int p = p0 + t;
            if (p >= 0 && p < NN) {
                size_t off = bbase + (size_t)p * NC + i;
                m = fmaxf(m, P0[off] + P1[off] + cbv);
            }
        }
        v[i] = m > 0.f ? m : expm1f(m);
    }
    __syncthreads();
    float ls = 0.f;
    for (int i = tid; i < NC; i += 256) ls += v[i];
    red[tid] = ls; __syncthreads();
    for (int off = 128; off > 0; off >>= 1) {
        if (tid < off) red[tid] += red[tid + off];
        __syncthreads();
    }
    float mu = red[0] / (float)NC;
    __syncthreads();
    float lv = 0.f;
    for (int i = tid; i < NC; i += 256) { float d = v[i] - mu; lv += d * d; }
    red[tid] = lv; __syncthreads();
    for (int off = 128; off > 0; off >>= 1) {
        if (tid < off) red[tid] += red[tid + off];
        __syncthreads();
    }
    float rstd = rsqrtf(red[0] / (float)NC + 1e-5f);
    for (int i = tid; i < NC; i += 256)
        outp[(size_t)row * NC + i] = (v[i] - mu) * rstd * g[i] + bb[i];
}

extern "C" void kernel_launch(void* const* d_in, const int* in_sizes, int n_in,
                              void* d_out, int out_size, void* d_ws, size_t ws_size,
                              hipStream_t stream)
{
    (void)in_sizes; (void)n_in; (void)out_size; (void)ws_size;
    const float* x      = (const float*)d_in[0];
    const float* qkv_w  = (const float*)d_in[1];
    const float* qkv_b  = (const float*)d_in[2];
    const float* out_w  = (const float*)d_in[3];
    const float* out_b  = (const float*)d_in[4];
    const float* ffn_w1 = (const float*)d_in[5];
    const float* ffn_b1 = (const float*)d_in[6];
    const float* ffn_w2 = (const float*)d_in[7];
    const float* ffn_b2 = (const float*)d_in[8];
    const float* n1_g   = (const float*)d_in[9];
    const float* n1_b   = (const float*)d_in[10];
    const float* n2_g   = (const float*)d_in[11];
    const float* n2_b   = (const float*)d_in[12];
    const float* conv_w = (const float*)d_in[13];
    const float* conv_b = (const float*)d_in[14];
    const float* cn_g   = (const float*)d_in[15];
    const float* cn_b   = (const float*)d_in[16];

    const size_t R = (size_t)NB * NN * NC;     // 2097152
    float* ws = (float*)d_ws;
    float* x1   = ws;                 // R : Kcat during rowstat; Opart; LN1 fp32 out
    float* reg2 = ws + R;             // R : xb+vwT -> Kb+Vtb -> split-K partial P0
    float* Qh   = ws + 2 * R;         // R : Q (dead after attn)
    float* Kh   = ws + 3 * R;         // R : K; later hb
    float* Vh   = ws + 4 * R;         // R : xcat; V; split-K partial P1
    size_t o = 5 * R;
    float* pmax  = ws + o;  o += 65536;   // rowmax (scaled) lives here
    float* psum  = ws + o;  o += 65536;   // (layout stability; unused)
    float* Marr  = ws + o;  o += 32768;
    float* pmean = ws + o;  o += 32768;
    float* meanv = ws + o;  o += 1024;
    int*   idx   = (int*)(ws + o);  o += 8192;
    float* ml    = ws + o;  o += 65536;
    u16*   ctxb  = (u16*)(ws + o);  o += R / 2;
    u16*   x1b   = (u16*)(ws + o);  o += R / 2;   // Qcat lower half
    u16*   x2b   = (u16*)(ws + o);  o += R / 2;   // Qcat upper half; LN2 out
    u16*   owT   = (u16*)(ws + o);  o += 131072;
    u16*   w1T   = (u16*)(ws + o);  o += 524288;  // wcatT early, ffn_w1^T after mfma_qk
    u16*   w2T   = (u16*)(ws + o);  o += 524288;
    u16*   cwT   = (u16*)(ws + o);  o += 393216;
    u16*   xb    = (u16*)reg2;                      // dead after mfma_v
    u16*   vwT   = (u16*)(ws + R + R / 2);          // dead after mfma_v
    u16*   Kb    = (u16*)reg2;                      // dead after attn_mfma
    u16*   Vtb   = (u16*)(ws + R + R / 2);          // dead after attn_mfma
    float* Opart    = x1;
    u16*   hb       = (u16*)(ws + 3 * R);
    float* rowmax   = pmax;
    // split-K fp32 partial pair (time-shared by proj -> FFN2 -> conv):
    float* skP0 = reg2;               // dead region at each use point
    float* skP1 = Vh;
    // concat-fp16 buffers for the MFMA Q/K projection + rowstat:
    u16*   xcat  = (u16*)Vh;          // dead before mfma_v
    u16*   wcatT = w1T;               // dead before castw_t(ffn_w1)
    u16*   Qcat  = x1b;               // (x1b+x2b)
    u16*   Kcat  = (u16*)x1;
    (void)psum;

    // weight / activation casts (w1T region is wcatT until after mfma_qk)
    castw_t<<<dim3(16, 16), 256, 0, stream>>>(out_w, owT, 512, 512, 512, 0);
    castw_t<<<dim3(16, 64), 256, 0, stream>>>(ffn_w2, w2T, 2048, 512, 512, 0);
    castw_t<<<dim3(16, 16), 256, 0, stream>>>(qkv_w, vwT, 512, 512, 1536, 1024);
    castconvw_k<<<3072, 256, 0, stream>>>(conv_w, cwT);
    castx_k<<<2048, 256, 0, stream>>>(x, xb, xcat);
    castw_hl<<<dim3(32, 16), 256, 0, stream>>>(qkv_w, wcatT);

    // Q,K projection via concat-fp16 MFMA (fp32-grade, selection-safe)
    mfma_qk<<<dim3(32, 8), 256, 0, stream>>>(xcat, wcatT, qkv_b, Qh, Kh, Qcat, Kcat);

    // now wcatT dead -> build real w1T; xcat dead -> V projection may write Vh
    castw_t<<<dim3(64, 16), 256, 0, stream>>>(ffn_w1, w1T, 512, 2048, 2048, 0);
    mfma_v<<<dim3(32, 4), 256, 0, stream>>>(xb, vwT, qkv_b + 1024, Vh);

    // pre-cast K/V for MFMA attention (overwrites xb/vwT region)
    castkv_k<<<dim3(NN / 64, NB * NH), 256, 0, stream>>>(Kh, Vh, Kb, Vtb);

    // mean of V: two-stage parallel reduction
    meanv_part_k<<<dim3(32, NB * NH), 256, 0, stream>>>(Vh, pmean);
    meanv_comb_k<<<NB * NH, 64, 0, stream>>>(pmean, meanv);

    // row max/mean of scores via concat-fp16 MFMA; emits Marr + rowmax
    rowstat_mfma_k<<<dim3(NB * NH, NN / 64), 256, 0, stream>>>(Qcat, Kcat, Marr, rowmax);
    topk_k<<<NB * NH, 256, 0, stream>>>(Marr, idx);
    fill_k<<<((int)R + 255) / 256, 256, 0, stream>>>(meanv, ctxb);
    attn_mfma_k<<<dim3(NB * NH * KSPLIT, NTOP / 64), 256, 0, stream>>>(
        Qh, Kb, Vtb, idx, rowmax, Opart, ml);
    attn_comb_k<<<NB * NH * NTOP / 4, 256, 0, stream>>>(Opart, ml, idx, ctxb);

    // proj: split-K x2 (256 wg = full GPU); partials combined in LN1
    mfma_gemm_sk<0><<<dim3(32, 4, 2), 256, 0, stream>>>(
        ctxb, NC, owT, skP0, skP1, NC, NC);

    // x1 = LN(x + proj_p0 + proj_p1 + out_b)
    ln_k<<<NB * NN, 256, 0, stream>>>(x, skP0, skP1, out_b, n1_g, n1_b, x1, x1b);

    // FFN1 (full-K, 512 wg already); FFN2 split-K x2
    mfma_gemm<0><<<dim3(32, 16), 256, 0, stream>>>(
        x1b, NC, w1T, ffn_b1, (float*)nullptr, hb, DFF, NC, 1);
    mfma_gemm_sk<0><<<dim3(32, 4, 2), 256, 0, stream>>>(
        hb, DFF, w2T, skP0, skP1, NC, DFF);

    // x2 = LN(x1 + ffn2_p0 + ffn2_p1 + ffn_b2) -> bf16
    ln_k<<<NB * NN, 256, 0, stream>>>(x1, skP0, skP1, ffn_b2,
                                      n2_g, n2_b, (float*)nullptr, x2b);

    // fused circular conv1d(k=3): split-K x2 MFMA GEMM, K=1536
    mfma_gemm_sk<1><<<dim3(32, 4, 2), 256, 0, stream>>>(
        x2b, NC, cwT, skP0, skP1, NC, 1536);

    pool_ln_k<<<NB * NPOOL, 256, 0, stream>>>(skP0, skP1, conv_b, cn_g, cn_b,
                                              (float*)d_out);
}

// Round 8
// 332.141 us; speedup vs baseline: 1.8014x; 1.0341x over previous
//
#include <hip/hip_runtime.h>
#include <math.h>

#define NB 2
#define NN 2048
#define NC 512
#define NH 8
#define DK 64
#define DFF 2048
#define NTOP 512
#define NPOOL 1024
#define KSPLIT 4

typedef unsigned short u16;
typedef __attribute__((ext_vector_type(8))) short frag8;
typedef __attribute__((ext_vector_type(8))) _Float16 h8;
typedef __attribute__((ext_vector_type(4))) float f32x4;

static __device__ __forceinline__ u16 f2b(float f) {
    union { float f; unsigned int u; } v; v.f = f;
    unsigned int r = (v.u + 0x7fffu + ((v.u >> 16) & 1u)) >> 16;
    return (u16)r;
}
static __device__ __forceinline__ float b2f(u16 v) {
    union { unsigned u; float f; } x; x.u = ((unsigned)v) << 16; return x.f;
}
static __device__ __forceinline__ u16 f2h_bits(float f) {
    union { _Float16 h; u16 u; } v; v.h = (_Float16)f; return v.u;
}
static __device__ __forceinline__ float h2f_bits(u16 u) {
    union { u16 u; _Float16 h; } v; v.u = u; return (float)v.h;
}

// =============== bf16 MFMA GEMM (full-K): used for FFN1 (+gelu) ===============
// Round-4 proven body. m-major grid: A-panel sharers co-XCD.
template<int MODE>
__global__ __launch_bounds__(256) void mfma_gemm(const u16* __restrict__ A, int lda,
    const u16* __restrict__ Bt, const float* __restrict__ bias,
    float* __restrict__ C, u16* __restrict__ Cb, int ldc, int K, int act)
{
    __shared__ u16 As[128][72];
    __shared__ u16 Bs[128][72];
    int tid = threadIdx.x;
    int m0 = blockIdx.x * 128, n0 = blockIdx.y * 128;
    int wave = tid >> 6, lane = tid & 63;
    int ln = lane & 15, quad = lane >> 4;
    int wm = (wave >> 1) * 64, wn = (wave & 1) * 64;
    f32x4 acc[4][4] = {};
    for (int k0 = 0; k0 < K; k0 += 64) {
        #pragma unroll
        for (int i = 0; i < 4; i++) {
            int t = tid + i * 256;
            int m = t >> 3, kq = t & 7;
            size_t aoff;
            if (MODE == 1) {
                int grow = m0 + m;
                int shift = (k0 >> 9) - 1;
                int arow = (grow & ~(NN - 1)) | ((grow + shift) & (NN - 1));
                aoff = (size_t)arow * NC + ((k0 & 511) + kq * 8);
            } else {
                aoff = (size_t)(m0 + m) * lda + k0 + kq * 8;
            }
            *(uint4*)&As[m][kq * 8] = *(const uint4*)&A[aoff];
            *(uint4*)&Bs[m][kq * 8] = *(const uint4*)&Bt[(size_t)(n0 + m) * K + k0 + kq * 8];
        }
        __syncthreads();
        #pragma unroll
        for (int kk = 0; kk < 2; kk++) {
            frag8 af[4], bf[4];
            #pragma unroll
            for (int i = 0; i < 4; i++) {
                af[i] = *(const frag8*)&As[wm + i * 16 + ln][kk * 32 + quad * 8];
                bf[i] = *(const frag8*)&Bs[wn + i * 16 + ln][kk * 32 + quad * 8];
            }
            #pragma unroll
            for (int i = 0; i < 4; i++)
                #pragma unroll
                for (int j = 0; j < 4; j++)
                    acc[i][j] = __builtin_amdgcn_mfma_f32_16x16x32_bf16(
                        af[i], bf[j], acc[i][j], 0, 0, 0);
        }
        __syncthreads();
    }
    #pragma unroll
    for (int i = 0; i < 4; i++) {
        #pragma unroll
        for (int j = 0; j < 4; j++) {
            int col = n0 + wn + j * 16 + ln;
            float bv = bias ? bias[col] : 0.f;
            #pragma unroll
            for (int r = 0; r < 4; r++) {
                int row = m0 + wm + i * 16 + quad * 4 + r;
                float v = acc[i][j][r] + bv;
                if (act == 1) v = 0.5f * v * (1.0f + erff(v * 0.70710678118654752f));
                if (Cb) Cb[(size_t)row * ldc + col] = f2b(v);
                else    C[(size_t)row * ldc + col] = v;
            }
        }
    }
}

// =============== split-K x2 MFMA GEMM: fp32 partials, no bias/act ===============
// proj/FFN2/conv have only 128 wg (half the CUs idle). Split-K doubles the grid
// WITHOUT duplicating A-fetch; partials combined free in ln_k / pool_ln_k.
template<int MODE>
__global__ __launch_bounds__(256) void mfma_gemm_sk(const u16* __restrict__ A, int lda,
    const u16* __restrict__ Bt, float* __restrict__ P0, float* __restrict__ P1,
    int ldc, int K)
{
    __shared__ u16 As[128][72];
    __shared__ u16 Bs[128][72];
    int tid = threadIdx.x;
    int m0 = blockIdx.x * 128, n0 = blockIdx.y * 128;
    int split = blockIdx.z;
    int K2 = K >> 1, kbeg = split * K2;
    int wave = tid >> 6, lane = tid & 63;
    int ln = lane & 15, quad = lane >> 4;
    int wm = (wave >> 1) * 64, wn = (wave & 1) * 64;
    f32x4 acc[4][4] = {};
    for (int k0 = kbeg; k0 < kbeg + K2; k0 += 64) {
        #pragma unroll
        for (int i = 0; i < 4; i++) {
            int t = tid + i * 256;
            int m = t >> 3, kq = t & 7;
            size_t aoff;
            if (MODE == 1) {
                int grow = m0 + m;
                int shift = (k0 >> 9) - 1;
                int arow = (grow & ~(NN - 1)) | ((grow + shift) & (NN - 1));
                aoff = (size_t)arow * NC + ((k0 & 511) + kq * 8);
            } else {
                aoff = (size_t)(m0 + m) * lda + k0 + kq * 8;
            }
            *(uint4*)&As[m][kq * 8] = *(const uint4*)&A[aoff];
            *(uint4*)&Bs[m][kq * 8] = *(const uint4*)&Bt[(size_t)(n0 + m) * K + k0 + kq * 8];
        }
        __syncthreads();
        #pragma unroll
        for (int kk = 0; kk < 2; kk++) {
            frag8 af[4], bf[4];
            #pragma unroll
            for (int i = 0; i < 4; i++) {
                af[i] = *(const frag8*)&As[wm + i * 16 + ln][kk * 32 + quad * 8];
                bf[i] = *(const frag8*)&Bs[wn + i * 16 + ln][kk * 32 + quad * 8];
            }
            #pragma unroll
            for (int i = 0; i < 4; i++)
                #pragma unroll
                for (int j = 0; j < 4; j++)
                    acc[i][j] = __builtin_amdgcn_mfma_f32_16x16x32_bf16(
                        af[i], bf[j], acc[i][j], 0, 0, 0);
        }
        __syncthreads();
    }
    float* P = split ? P1 : P0;
    #pragma unroll
    for (int i = 0; i < 4; i++) {
        #pragma unroll
        for (int j = 0; j < 4; j++) {
            int col = n0 + wn + j * 16 + ln;
            #pragma unroll
            for (int r = 0; r < 4; r++) {
                int row = m0 + wm + i * 16 + quad * 4 + r;
                P[(size_t)row * ldc + col] = acc[i][j][r];
            }
        }
    }
}

// =============== QKV projection: f16 concat-hi/lo MFMA GEMM (fp32-grade) =========
// N=1536 covers Q|K|V in one full-GPU kernel (384 wg); V scatter fp32 head-major.
// Replaces mfma_v (128 wg, half-idle) + its weight cast + the xb activation cast.
__global__ __launch_bounds__(256) void mfma_qkv(const u16* __restrict__ A,
    const u16* __restrict__ Bt, const float* __restrict__ bias,
    float* __restrict__ Qh, float* __restrict__ Kh, float* __restrict__ Vh,
    u16* __restrict__ Qcat, u16* __restrict__ Kcat)
{
    __shared__ u16 As[128][72];
    __shared__ u16 Bs[128][72];
    int tid = threadIdx.x;
    int m0 = blockIdx.x * 128, n0 = blockIdx.y * 128;
    int wave = tid >> 6, lane = tid & 63;
    int ln = lane & 15, quad = lane >> 4;
    int wm = (wave >> 1) * 64, wn = (wave & 1) * 64;
    f32x4 acc[4][4] = {};
    for (int k0 = 0; k0 < 1024; k0 += 64) {
        #pragma unroll
        for (int i = 0; i < 4; i++) {
            int t = tid + i * 256;
            int m = t >> 3, kq = t & 7;
            *(uint4*)&As[m][kq * 8] = *(const uint4*)&A[(size_t)(m0 + m) * 1024 + k0 + kq * 8];
            *(uint4*)&Bs[m][kq * 8] = *(const uint4*)&Bt[(size_t)(n0 + m) * 1024 + k0 + kq * 8];
        }
        __syncthreads();
        #pragma unroll
        for (int kk = 0; kk < 2; kk++) {
            h8 af[4], bf[4];
            #pragma unroll
            for (int i = 0; i < 4; i++) {
                af[i] = *(const h8*)&As[wm + i * 16 + ln][kk * 32 + quad * 8];
                bf[i] = *(const h8*)&Bs[wn + i * 16 + ln][kk * 32 + quad * 8];
            }
            #pragma unroll
            for (int i = 0; i < 4; i++)
                #pragma unroll
                for (int j = 0; j < 4; j++)
                    acc[i][j] = __builtin_amdgcn_mfma_f32_16x16x32_f16(
                        af[i], bf[j], acc[i][j], 0, 0, 0);
        }
        __syncthreads();
    }
    #pragma unroll
    for (int i = 0; i < 4; i++) {
        #pragma unroll
        for (int j = 0; j < 4; j++) {
            int col = n0 + wn + j * 16 + ln;   // 0..1535 : [Q | K | V]
            float bv = bias[col];
            int which = col >> 9;
            int h = (col >> 6) & 7, d = col & 63;
            #pragma unroll
            for (int r = 0; r < 4; r++) {
                int row = m0 + wm + i * 16 + quad * 4 + r;
                int b = row >> 11, n = row & (NN - 1);
                float v = acc[i][j][r] + bv;
                size_t off32 = ((size_t)((b << 3) + h) * NN + n) * DK + d;
                if (which == 2) {
                    Vh[off32] = v;
                } else {
                    size_t offc = ((size_t)((b << 3) + h) * NN + n) * 128 + d;
                    u16 hb_ = f2h_bits(v);
                    u16 lb_ = f2h_bits(v - h2f_bits(hb_));
                    if (which == 0) {
                        Qh[off32] = v;
                        Qcat[offc] = hb_; Qcat[offc + 64] = lb_;
                    } else {
                        Kh[off32] = v;
                        Kcat[offc] = hb_; Kcat[offc + 64] = lb_;
                    }
                }
            }
        }
    }
}

// =============== weight cast+transpose (bf16) ===============
__global__ __launch_bounds__(256) void castw_t(const float* __restrict__ in,
    u16* __restrict__ out, int R, int C, int ldi, int coff)
{
    __shared__ float t[32][33];
    int c0 = blockIdx.x * 32, r0 = blockIdx.y * 32;
    int lx = threadIdx.x & 31, ly = threadIdx.x >> 5;
    #pragma unroll
    for (int i = 0; i < 4; i++)
        t[ly + i * 8][lx] = in[(size_t)(r0 + ly + i * 8) * ldi + coff + c0 + lx];
    __syncthreads();
    #pragma unroll
    for (int i = 0; i < 4; i++)
        out[(size_t)(c0 + ly + i * 8) * R + r0 + lx] = f2b(t[lx][ly + i * 8]);
}

// =============== qkv_w all 1536 cols: transpose + fp16 hi/lo concat ===============
// out[col][k] = hi(w[k][col]), out[col][512+k] = lo;  out is [1536][1024]
__global__ __launch_bounds__(256) void castw_hl(const float* __restrict__ in,
    u16* __restrict__ out)
{
    __shared__ float t[32][33];
    int c0 = blockIdx.x * 32, r0 = blockIdx.y * 32;
    int lx = threadIdx.x & 31, ly = threadIdx.x >> 5;
    #pragma unroll
    for (int i = 0; i < 4; i++)
        t[ly + i * 8][lx] = in[(size_t)(r0 + ly + i * 8) * 1536 + c0 + lx];
    __syncthreads();
    #pragma unroll
    for (int i = 0; i < 4; i++) {
        float v = t[lx][ly + i * 8];
        u16 hb_ = f2h_bits(v);
        u16 lb_ = f2h_bits(v - h2f_bits(hb_));
        size_t ob = (size_t)(c0 + ly + i * 8) * 1024 + r0 + lx;
        out[ob] = hb_;
        out[ob + 512] = lb_;
    }
}

// =============== conv weight cast: [co][ci][t] -> [co][t*512+ci] bf16 ===============
__global__ void castconvw_k(const float* __restrict__ cw, u16* __restrict__ out)
{
    int i = blockIdx.x * 256 + threadIdx.x;
    if (i >= 3 * NC * NC) return;
    int t = i % 3, ci = (i / 3) & (NC - 1), co = i / (3 * NC);
    out[(size_t)co * 1536 + t * NC + ci] = f2b(cw[i]);
}

// =============== x: fp32 [M][512] -> concat hi/lo fp16 [M][1024] ===============
__global__ void castx_k(const float* __restrict__ in, u16* __restrict__ xcat)
{
    int i = blockIdx.x * 256 + threadIdx.x;
    if (i >= (NB * NN * NC) / 4) return;
    int m = i >> 7, kq = i & 127;
    float4 v = ((const float4*)in)[i];
    ushort4 h, l;
    h.x = f2h_bits(v.x); h.y = f2h_bits(v.y);
    h.z = f2h_bits(v.z); h.w = f2h_bits(v.w);
    l.x = f2h_bits(v.x - h2f_bits(h.x));
    l.y = f2h_bits(v.y - h2f_bits(h.y));
    l.z = f2h_bits(v.z - h2f_bits(h.z));
    l.w = f2h_bits(v.w - h2f_bits(h.w));
    *(ushort4*)&xcat[(size_t)m * 1024 + kq * 4] = h;
    *(ushort4*)&xcat[(size_t)m * 1024 + 512 + kq * 4] = l;
}

// =============== K,V -> bf16 (V transposed per bh) ===============
__global__ __launch_bounds__(256) void castkv_k(const float* __restrict__ Kh,
    const float* __restrict__ Vh, u16* __restrict__ Kb, u16* __restrict__ Vtb)
{
    int bh = blockIdx.y;
    int n0 = blockIdx.x * 64;
    __shared__ float vt[64][68];
    int tid = threadIdx.x;
    const float* kin = Kh + ((size_t)bh * NN + n0) * DK;
    u16* kout = Kb + ((size_t)bh * NN + n0) * DK;
    const float* vin = Vh + ((size_t)bh * NN + n0) * DK;
    #pragma unroll
    for (int i = 0; i < 4; i++) {
        int t = tid + i * 256;
        int n = t >> 4, dq = t & 15;
        float4 v = *(const float4*)&kin[(size_t)n * DK + dq * 4];
        ushort4 o;
        o.x = f2b(v.x); o.y = f2b(v.y); o.z = f2b(v.z); o.w = f2b(v.w);
        *(ushort4*)&kout[(size_t)n * DK + dq * 4] = o;
        float4 w = *(const float4*)&vin[(size_t)n * DK + dq * 4];
        vt[dq * 4 + 0][n] = w.x; vt[dq * 4 + 1][n] = w.y;
        vt[dq * 4 + 2][n] = w.z; vt[dq * 4 + 3][n] = w.w;
    }
    __syncthreads();
    #pragma unroll
    for (int i = 0; i < 4; i++) {
        int t = tid + i * 256;
        int d = t >> 4, nq = t & 15;
        float4 v = *(const float4*)&vt[d][nq * 4];
        ushort4 o;
        o.x = f2b(v.x); o.y = f2b(v.y); o.z = f2b(v.z); o.w = f2b(v.w);
        *(ushort4*)&Vtb[((size_t)bh * DK + d) * NN + n0 + nq * 4] = o;
    }
}

// =============== mean of V: stage 1, 512 blocks, coalesced partials ===============
__global__ __launch_bounds__(256) void meanv_part_k(const float* __restrict__ Vh,
    float* __restrict__ pmean)
{
    int bh = blockIdx.y, chunk = blockIdx.x;   // 32 chunks of 64 rows
    int tid = threadIdx.x;
    int d = tid & 63, sub = tid >> 6;
    const float* vb = Vh + ((size_t)bh * NN + chunk * 64 + sub * 16) * DK;
    float s = 0.f;
    #pragma unroll
    for (int r = 0; r < 16; r++) s += vb[(size_t)r * DK + d];
    __shared__ float red[256];
    red[tid] = s;
    __syncthreads();
    if (sub == 0)
        pmean[((size_t)bh * 32 + chunk) * 64 + d] =
            red[d] + red[64 + d] + red[128 + d] + red[192 + d];
}

// =============== mean of V: stage 2 combine ===============
__global__ void meanv_comb_k(const float* __restrict__ pmean, float* __restrict__ meanv)
{
    int bh = blockIdx.x;
    int d = threadIdx.x;   // 64 threads
    float s = 0.f;
    #pragma unroll
    for (int c = 0; c < 32; c++) s += pmean[((size_t)bh * 32 + c) * 64 + d];
    meanv[bh * DK + d] = s * (1.0f / (float)NN);
}

// =============== rowstat via concat-fp16 MFMA; emits Marr and scaled rowmax ========
__global__ __launch_bounds__(256) void rowstat_mfma_k(const u16* __restrict__ Qcat,
    const u16* __restrict__ Kcat, float* __restrict__ Marr, float* __restrict__ rowmax)
{
    int bh = blockIdx.x;
    int m0 = blockIdx.y * 64;
    int tid = threadIdx.x;
    int wave = tid >> 6, lane = tid & 63;
    int ln = lane & 15, quad = lane >> 4;
    __shared__ u16 Ks[128][136];
    h8 qf[4];
    {
        const u16* qp = &Qcat[((size_t)bh * NN + m0 + wave * 16 + ln) * 128];
        #pragma unroll
        for (int ks = 0; ks < 4; ks++)
            qf[ks] = *(const h8*)&qp[ks * 32 + quad * 8];
    }
    f32x4 vmax, vsum;
    #pragma unroll
    for (int r = 0; r < 4; r++) { vmax[r] = -INFINITY; vsum[r] = 0.f; }
    const u16* kB = Kcat + (size_t)bh * NN * 128;
    for (int nc = 0; nc < NN; nc += 128) {
        __syncthreads();
        #pragma unroll
        for (int i = 0; i < 8; i++) {
            int e = tid + i * 256;
            int n = e >> 4, kq = e & 15;
            *(uint4*)&Ks[n][kq * 8] = *(const uint4*)&kB[(size_t)(nc + n) * 128 + kq * 8];
        }
        __syncthreads();
        f32x4 accS[8] = {};
        #pragma unroll
        for (int nt = 0; nt < 8; nt++) {
            #pragma unroll
            for (int ks = 0; ks < 4; ks++) {
                h8 kf = *(const h8*)&Ks[nt * 16 + ln][ks * 32 + quad * 8];
                accS[nt] = __builtin_amdgcn_mfma_f32_16x16x32_f16(
                    qf[ks], kf, accS[nt], 0, 0, 0);
            }
        }
        #pragma unroll
        for (int nt = 0; nt < 8; nt++)
            #pragma unroll
            for (int r = 0; r < 4; r++) {
                vmax[r] = fmaxf(vmax[r], accS[nt][r]);
                vsum[r] += accS[nt][r];
            }
    }
    #pragma unroll
    for (int r = 0; r < 4; r++) {
        float mx = vmax[r], sm = vsum[r];
        #pragma unroll
        for (int off = 1; off < 16; off <<= 1) {
            mx = fmaxf(mx, __shfl_xor(mx, off));
            sm += __shfl_xor(sm, off);
        }
        if (ln == 0) {
            int m = m0 + wave * 16 + quad * 4 + r;
            Marr[(size_t)bh * NN + m] = (mx - sm * (1.0f / (float)NN)) * 0.125f;
            rowmax[(size_t)bh * NN + m] = mx * 0.125f;
        }
    }
}

// =============== top-512 per (b,h): radix-select, wave-shfl scans ===============
__global__ __launch_bounds__(256) void topk_k(const float* __restrict__ Marr,
                                              int* __restrict__ idx)
{
    int bh = blockIdx.x;
    const float* Mr = Marr + (size_t)bh * NN;
    int* idxr = idx + (size_t)bh * NTOP;
    __shared__ int hist[256];
    __shared__ int suf[256];
    __shared__ int wred[4], wred2[4];
    __shared__ int bin_sh, rank_sh;
    int tid = threadIdx.x;
    int lane = tid & 63, w = tid >> 6;
    unsigned prefix = 0;
    int rank = NTOP;
    for (int pass = 0; pass < 4; pass++) {
        int shift = 24 - pass * 8;
        unsigned mask_hi = (pass == 0) ? 0u : (0xFFFFFFFFu << (shift + 8));
        hist[tid] = 0;
        __syncthreads();
        for (int i = tid; i < NN; i += 256) {
            union { float f; unsigned u; } v; v.f = Mr[i];
            unsigned k = (v.u & 0x80000000u) ? ~v.u : (v.u | 0x80000000u);
            if ((k & mask_hi) == prefix)
                atomicAdd(&hist[(k >> shift) & 255], 1);
        }
        __syncthreads();
        int v = hist[tid];
        #pragma unroll
        for (int off = 1; off < 64; off <<= 1) {
            int t = __shfl_down(v, off);
            if (lane + off < 64) v += t;
        }
        if (lane == 0) wred[w] = v;
        __syncthreads();
        int add = 0;
        #pragma unroll
        for (int w2 = 0; w2 < 4; w2++) if (w2 > w) add += wred[w2];
        suf[tid] = v + add;
        __syncthreads();
        int sv = suf[tid];
        int nxt = (tid < 255) ? suf[tid + 1] : 0;
        if (sv >= rank && nxt < rank) { bin_sh = tid; rank_sh = rank - nxt; }
        __syncthreads();
        prefix |= ((unsigned)bin_sh << shift);
        rank = rank_sh;
        __syncthreads();
    }
    union { unsigned u; float f; } tv;
    tv.u = (prefix & 0x80000000u) ? (prefix & 0x7FFFFFFFu) : ~prefix;
    float thr = tv.f;
    int lg = 0, le = 0;
    #pragma unroll
    for (int k = 0; k < 8; k++) {
        float v = Mr[tid * 8 + k];
        lg += (v > thr) ? 1 : 0;
        le += (v == thr) ? 1 : 0;
    }
    int vg = lg, ve = le;
    #pragma unroll
    for (int off = 1; off < 64; off <<= 1) {
        int tg = __shfl_up(vg, off);
        int te = __shfl_up(ve, off);
        if (lane >= off) { vg += tg; ve += te; }
    }
    if (lane == 63) { wred[w] = vg; wred2[w] = ve; }
    __syncthreads();
    int addg = 0, adde = 0, totg = 0;
    #pragma unroll
    for (int w2 = 0; w2 < 4; w2++) {
        totg += wred[w2];
        if (w2 < w) { addg += wred[w2]; adde += wred2[w2]; }
    }
    int cnt_gt = totg;
    int needed = NTOP - cnt_gt;
    int gpre = (vg + addg) - lg, epre = (ve + adde) - le;
    #pragma unroll
    for (int k = 0; k < 8; k++) {
        int p = tid * 8 + k;
        float v = Mr[p];
        bool isgt = v > thr, iseq = v == thr;
        bool selv = isgt || (iseq && epre < needed);
        if (selv) idxr[gpre + (epre < needed ? epre : needed)] = p;
        gpre += isgt ? 1 : 0;
        epre += iseq ? 1 : 0;
    }
}

// =============== fill ctx (bf16) with uniform-attention result ===============
__global__ void fill_k(const float* __restrict__ meanv, u16* __restrict__ ctxb)
{
    int i = blockIdx.x * 256 + threadIdx.x;
    if (i >= NB * NN * NC) return;
    int c = i & (NC - 1);
    int m = i >> 9;
    int b = m >> 11;
    int h = c >> 6, d = c & 63;
    ctxb[i] = f2b(meanv[(((b << 3) + h) << 6) + d]);
}

// =============== MFMA flash attention, precomputed rowmax, split-K ===============
__global__ __launch_bounds__(256) void attn_mfma_k(const float* __restrict__ Qh,
    const u16* __restrict__ Kb, const u16* __restrict__ Vtb,
    const int* __restrict__ idx, const float* __restrict__ rowmax,
    float* __restrict__ Opart, float* __restrict__ ml)
{
    int yy = blockIdx.x;
    int bh = yy >> 2, split = yy & (KSPLIT - 1);
    int t0 = blockIdx.y * 64;
    int tid = threadIdx.x;
    int wave = tid >> 6, lane = tid & 63;
    int ln = lane & 15, quad = lane >> 4;
    __shared__ u16 Ks[128][72];
    __shared__ u16 Vt[64][136];
    __shared__ u16 Ps[4][16][136];
    __shared__ int rows[64];
    if (tid < 64) rows[tid] = idx[bh * NTOP + t0 + tid];
    __syncthreads();
    frag8 qf[2];
    {
        const float* qp = &Qh[((size_t)bh * NN + rows[wave * 16 + ln]) * DK];
        #pragma unroll
        for (int ks = 0; ks < 2; ks++) {
            float4 a = *(const float4*)&qp[ks * 32 + quad * 8];
            float4 b = *(const float4*)&qp[ks * 32 + quad * 8 + 4];
            union { frag8 f; u16 s[8]; } u;
            u.s[0] = f2b(a.x * 0.125f); u.s[1] = f2b(a.y * 0.125f);
            u.s[2] = f2b(a.z * 0.125f); u.s[3] = f2b(a.w * 0.125f);
            u.s[4] = f2b(b.x * 0.125f); u.s[5] = f2b(b.y * 0.125f);
            u.s[6] = f2b(b.z * 0.125f); u.s[7] = f2b(b.w * 0.125f);
            qf[ks] = u.f;
        }
    }
    float rm[4];
    #pragma unroll
    for (int r = 0; r < 4; r++)
        rm[r] = rowmax[(size_t)bh * NN + rows[wave * 16 + quad * 4 + r]];
    f32x4 accO[4] = {};
    float lrun[4] = {};
    const u16* kbB = Kb + (size_t)bh * NN * DK;
    const u16* vtB = Vtb + (size_t)bh * DK * NN;
    int nc0 = split * (NN / KSPLIT);
    for (int nc = nc0; nc < nc0 + NN / KSPLIT; nc += 128) {
        __syncthreads();
        #pragma unroll
        for (int i = 0; i < 4; i++) {
            int e = tid + i * 256;
            int n = e >> 3, kq = e & 7;
            *(uint4*)&Ks[n][kq * 8] = *(const uint4*)&kbB[(size_t)(nc + n) * DK + kq * 8];
        }
        #pragma unroll
        for (int i = 0; i < 4; i++) {
            int e = tid + i * 256;
            int d = e >> 4, nq = e & 15;
            *(uint4*)&Vt[d][nq * 8] = *(const uint4*)&vtB[(size_t)d * NN + nc + nq * 8];
        }
        __syncthreads();
        f32x4 accS[8] = {};
        #pragma unroll
        for (int nt = 0; nt < 8; nt++) {
            frag8 b0 = *(const frag8*)&Ks[nt * 16 + ln][quad * 8];
            frag8 b1 = *(const frag8*)&Ks[nt * 16 + ln][32 + quad * 8];
            accS[nt] = __builtin_amdgcn_mfma_f32_16x16x32_bf16(qf[0], b0, accS[nt], 0, 0, 0);
            accS[nt] = __builtin_amdgcn_mfma_f32_16x16x32_bf16(qf[1], b1, accS[nt], 0, 0, 0);
        }
        #pragma unroll
        for (int nt = 0; nt < 8; nt++)
            #pragma unroll
            for (int r = 0; r < 4; r++) {
                float p = expf(accS[nt][r] - rm[r]);
                accS[nt][r] = p;
                lrun[r] += p;
            }
        #pragma unroll
        for (int nt = 0; nt < 8; nt++)
            #pragma unroll
            for (int r = 0; r < 4; r++)
                Ps[wave][quad * 4 + r][nt * 16 + ln] = f2b(accS[nt][r]);
        #pragma unroll
        for (int ks = 0; ks < 4; ks++) {
            frag8 pf = *(const frag8*)&Ps[wave][ln][ks * 32 + quad * 8];
            #pragma unroll
            for (int nt2 = 0; nt2 < 4; nt2++) {
                frag8 vf = *(const frag8*)&Vt[nt2 * 16 + ln][ks * 32 + quad * 8];
                accO[nt2] = __builtin_amdgcn_mfma_f32_16x16x32_bf16(pf, vf, accO[nt2], 0, 0, 0);
            }
        }
    }
    #pragma unroll
    for (int r = 0; r < 4; r++) {
        float ls = lrun[r];
        #pragma unroll
        for (int off = 1; off < 16; off <<= 1) ls += __shfl_xor(ls, off);
        int p = t0 + wave * 16 + quad * 4 + r;
        size_t pb = ((size_t)bh * NTOP + p) * KSPLIT + split;
        #pragma unroll
        for (int nt2 = 0; nt2 < 4; nt2++)
            Opart[pb * 64 + nt2 * 16 + ln] = accO[nt2][r];
        if (ln == 0) ml[pb * 2 + 1] = ls;
    }
}

// =============== combine split-K partials -> ctxb (bf16) ===============
__global__ __launch_bounds__(256) void attn_comb_k(const float* __restrict__ Opart,
    const float* __restrict__ ml, const int* __restrict__ idx,
    u16* __restrict__ ctxb)
{
    int gid = blockIdx.x * 4 + (threadIdx.x >> 6);
    int lane = threadIdx.x & 63;
    int bh = gid >> 9;
    int h = bh & 7, b = bh >> 3;
    size_t base = (size_t)gid * KSPLIT;
    float L = 0.f, O = 0.f;
    #pragma unroll
    for (int s = 0; s < KSPLIT; s++) {
        L += ml[(base + s) * 2 + 1];
        O += Opart[(base + s) * 64 + lane];
    }
    int n = idx[gid];
    ctxb[((size_t)(b * NN + n)) * NC + h * DK + lane] = f2b(O / L);
}

// =============== layernorm of A + P0 + P1 + cb; fp32 and/or bf16 out ===============
__global__ __launch_bounds__(256) void ln_k(const float* __restrict__ A,
    const float* __restrict__ P0, const float* __restrict__ P1,
    const float* __restrict__ cb,
    const float* __restrict__ g, const float* __restrict__ bb,
    float* __restrict__ out, u16* __restrict__ outb)
{
    int row = blockIdx.x;
    int tid = threadIdx.x;
    __shared__ float v[NC];
    __shared__ float red[256];
    size_t base = (size_t)row * NC;
    for (int i = tid; i < NC; i += 256)
        v[i] = A[base + i] + P0[base + i] + P1[base + i] + cb[i];
    __syncthreads();
    float ls = 0.f;
    for (int i = tid; i < NC; i += 256) ls += v[i];
    red[tid] = ls; __syncthreads();
    for (int off = 128; off > 0; off >>= 1) {
        if (tid < off) red[tid] += red[tid + off];
        __syncthreads();
    }
    float mu = red[0] / (float)NC;
    __syncthreads();
    float lv = 0.f;
    for (int i = tid; i < NC; i += 256) { float d = v[i] - mu; lv += d * d; }
    red[tid] = lv; __syncthreads();
    for (int off = 128; off > 0; off >>= 1) {
        if (tid < off) red[tid] += red[tid + off];
        __syncthreads();
    }
    float rstd = rsqrtf(red[0] / (float)NC + 1e-5f);
    for (int i = tid; i < NC; i += 256) {
        float r = (v[i] - mu) * rstd * g[i] + bb[i];
        if (out) out[base + i] = r;
        if (outb) outb[base + i] = f2b(r);
    }
}

// =============== maxpool(3,2,1) + ELU + LN over conv partials (fp32) ===============
__global__ __launch_bounds__(256) void pool_ln_k(const float* __restrict__ P0,
    const float* __restrict__ P1, const float* __restrict__ cb,
    const float* __restrict__ g, const float* __restrict__ bb,
    float* __restrict__ outp)
{
    int row = blockIdx.x;
    int j = row & (NPOOL - 1), b = row / NPOOL;
    int tid = threadIdx.x;
    __shared__ float v[NC];
    __shared__ float red[256];
    size_t bbase = (size_t)b * NN * NC;
    for (int i = tid; i < NC; i += 256) {
        float m = -INFINITY;
        int p0 = 2 * j - 1;
        float cbv = cb[i];
        #pragma unroll
        for (int t = 0; t < 3; t++) {
            int p = p0 + t;
            if (p >= 0 && p < NN) {
                size_t off = bbase + (size_t)p * NC + i;
                m = fmaxf(m, P0[off] + P1[off] + cbv);
            }
        }
        v[i] = m > 0.f ? m : expm1f(m);
    }
    __syncthreads();
    float ls = 0.f;
    for (int i = tid; i < NC; i += 256) ls += v[i];
    red[tid] = ls; __syncthreads();
    for (int off = 128; off > 0; off >>= 1) {
        if (tid < off) red[tid] += red[tid + off];
        __syncthreads();
    }
    float mu = red[0] / (float)NC;
    __syncthreads();
    float lv = 0.f;
    for (int i = tid; i < NC; i += 256) { float d = v[i] - mu; lv += d * d; }
    red[tid] = lv; __syncthreads();
    for (int off = 128; off > 0; off >>= 1) {
        if (tid < off) red[tid] += red[tid + off];
        __syncthreads();
    }
    float rstd = rsqrtf(red[0] / (float)NC + 1e-5f);
    for (int i = tid; i < NC; i += 256)
        outp[(size_t)row * NC + i] = (v[i] - mu) * rstd * g[i] + bb[i];
}

extern "C" void kernel_launch(void* const* d_in, const int* in_sizes, int n_in,
                              void* d_out, int out_size, void* d_ws, size_t ws_size,
                              hipStream_t stream)
{
    (void)in_sizes; (void)n_in; (void)out_size; (void)ws_size;
    const float* x      = (const float*)d_in[0];
    const float* qkv_w  = (const float*)d_in[1];
    const float* qkv_b  = (const float*)d_in[2];
    const float* out_w  = (const float*)d_in[3];
    const float* out_b  = (const float*)d_in[4];
    const float* ffn_w1 = (const float*)d_in[5];
    const float* ffn_b1 = (const float*)d_in[6];
    const float* ffn_w2 = (const float*)d_in[7];
    const float* ffn_b2 = (const float*)d_in[8];
    const float* n1_g   = (const float*)d_in[9];
    const float* n1_b   = (const float*)d_in[10];
    const float* n2_g   = (const float*)d_in[11];
    const float* n2_b   = (const float*)d_in[12];
    const float* conv_w = (const float*)d_in[13];
    const float* conv_b = (const float*)d_in[14];
    const float* cn_g   = (const float*)d_in[15];
    const float* cn_b   = (const float*)d_in[16];

    const size_t R = (size_t)NB * NN * NC;     // 2097152
    float* ws = (float*)d_ws;
    float* x1   = ws;                 // R : Kcat during rowstat; Opart; LN1 fp32 out
    float* reg2 = ws + R;             // R : xcat -> Kb+Vtb -> split-K partial P0
    float* Qh   = ws + 2 * R;         // R : Q (dead after attn)
    float* Kh   = ws + 3 * R;         // R : K; later hb
    float* Vh   = ws + 4 * R;         // R : V fp32; split-K partial P1
    size_t o = 5 * R;
    float* pmax  = ws + o;  o += 65536;   // rowmax (scaled) lives here
    float* psum  = ws + o;  o += 65536;   // (layout stability; unused)
    float* Marr  = ws + o;  o += 32768;
    float* pmean = ws + o;  o += 32768;
    float* meanv = ws + o;  o += 1024;
    int*   idx   = (int*)(ws + o);  o += 8192;
    float* ml    = ws + o;  o += 65536;
    u16*   ctxb  = (u16*)(ws + o);  o += R / 2;
    u16*   x1b   = (u16*)(ws + o);  o += R / 2;   // Qcat lower half
    u16*   x2b   = (u16*)(ws + o);  o += R / 2;   // Qcat upper half; LN2 out
    u16*   owT   = (u16*)(ws + o);  o += 131072;
    u16*   w1T   = (u16*)(ws + o);  o += 524288;  // wcatT(lo) early, ffn_w1^T after qkv
    u16*   w2T   = (u16*)(ws + o);  o += 524288;  // wcatT(hi) early, ffn_w2^T after qkv
    u16*   cwT   = (u16*)(ws + o);  o += 393216;
    u16*   Kb    = (u16*)reg2;                      // dead after attn_mfma
    u16*   Vtb   = (u16*)(ws + R + R / 2);          // dead after attn_mfma
    float* Opart    = x1;
    u16*   hb       = (u16*)(ws + 3 * R);
    float* rowmax   = pmax;
    // split-K fp32 partial pair (time-shared by proj -> FFN2 -> conv):
    float* skP0 = reg2;               // dead region at each use point
    float* skP1 = Vh;
    // concat-fp16 buffers for the fused QKV projection + rowstat:
    u16*   xcat  = (u16*)reg2;        // [4096][1024] fp16 — dead after mfma_qkv
    u16*   wcatT = w1T;               // [1536][1024] fp16 spans w1T+w2T (contiguous)
    u16*   Qcat  = x1b;               // (x1b+x2b)
    u16*   Kcat  = (u16*)x1;
    (void)psum;

    // early casts into regions not needed until later
    castw_t<<<dim3(16, 16), 256, 0, stream>>>(out_w, owT, 512, 512, 512, 0);
    castconvw_k<<<3072, 256, 0, stream>>>(conv_w, cwT);
    castx_k<<<2048, 256, 0, stream>>>(x, xcat);
    castw_hl<<<dim3(48, 16), 256, 0, stream>>>(qkv_w, wcatT);

    // fused Q,K,V projection via concat-fp16 MFMA (fp32-grade, selection-safe)
    // grid (32 m-tiles, 12 n-tiles) = 384 wg — full GPU; replaces mfma_qk + mfma_v
    mfma_qkv<<<dim3(32, 12), 256, 0, stream>>>(xcat, wcatT, qkv_b,
                                               Qh, Kh, Vh, Qcat, Kcat);

    // wcatT dead -> build real w1T/w2T
    castw_t<<<dim3(64, 16), 256, 0, stream>>>(ffn_w1, w1T, 512, 2048, 2048, 0);
    castw_t<<<dim3(16, 64), 256, 0, stream>>>(ffn_w2, w2T, 2048, 512, 512, 0);

    // pre-cast K/V for MFMA attention (overwrites dead xcat region)
    castkv_k<<<dim3(NN / 64, NB * NH), 256, 0, stream>>>(Kh, Vh, Kb, Vtb);

    // mean of V: two-stage parallel reduction
    meanv_part_k<<<dim3(32, NB * NH), 256, 0, stream>>>(Vh, pmean);
    meanv_comb_k<<<NB * NH, 64, 0, stream>>>(pmean, meanv);

    // row max/mean of scores via concat-fp16 MFMA; emits Marr + rowmax
    rowstat_mfma_k<<<dim3(NB * NH, NN / 64), 256, 0, stream>>>(Qcat, Kcat, Marr, rowmax);
    topk_k<<<NB * NH, 256, 0, stream>>>(Marr, idx);
    fill_k<<<((int)R + 255) / 256, 256, 0, stream>>>(meanv, ctxb);
    attn_mfma_k<<<dim3(NB * NH * KSPLIT, NTOP / 64), 256, 0, stream>>>(
        Qh, Kb, Vtb, idx, rowmax, Opart, ml);
    attn_comb_k<<<NB * NH * NTOP / 4, 256, 0, stream>>>(Opart, ml, idx, ctxb);

    // proj: split-K x2 (256 wg = full GPU); partials combined in LN1
    mfma_gemm_sk<0><<<dim3(32, 4, 2), 256, 0, stream>>>(
        ctxb, NC, owT, skP0, skP1, NC, NC);

    // x1 = LN(x + proj_p0 + proj_p1 + out_b)
    ln_k<<<NB * NN, 256, 0, stream>>>(x, skP0, skP1, out_b, n1_g, n1_b, x1, x1b);

    // FFN1 (full-K, 512 wg already); FFN2 split-K x2
    mfma_gemm<0><<<dim3(32, 16), 256, 0, stream>>>(
        x1b, NC, w1T, ffn_b1, (float*)nullptr, hb, DFF, NC, 1);
    mfma_gemm_sk<0><<<dim3(32, 4, 2), 256, 0, stream>>>(
        hb, DFF, w2T, skP0, skP1, NC, DFF);

    // x2 = LN(x1 + ffn2_p0 + ffn2_p1 + ffn_b2) -> bf16
    ln_k<<<NB * NN, 256, 0, stream>>>(x1, skP0, skP1, ffn_b2,
                                      n2_g, n2_b, (float*)nullptr, x2b);

    // fused circular conv1d(k=3): split-K x2 MFMA GEMM, K=1536
    mfma_gemm_sk<1><<<dim3(32, 4, 2), 256, 0, stream>>>(
        x2b, NC, cwT, skP0, skP1, NC, 1536);

    pool_ln_k<<<NB * NPOOL, 256, 0, stream>>>(skP0, skP1, conv_b, cn_g, cn_b,
                                              (float*)d_out);
}

// Round 9
// 324.242 us; speedup vs baseline: 1.8452x; 1.0244x over previous
//
#include <hip/hip_runtime.h>
#include <math.h>

#define NB 2
#define NN 2048
#define NC 512
#define NH 8
#define DK 64
#define DFF 2048
#define NTOP 512
#define NPOOL 1024
#define KSPLIT 4

typedef unsigned short u16;
typedef __attribute__((ext_vector_type(8))) short frag8;
typedef __attribute__((ext_vector_type(8))) _Float16 h8;
typedef __attribute__((ext_vector_type(4))) float f32x4;

static __device__ __forceinline__ u16 f2b(float f) {
    union { float f; unsigned int u; } v; v.f = f;
    unsigned int r = (v.u + 0x7fffu + ((v.u >> 16) & 1u)) >> 16;
    return (u16)r;
}
static __device__ __forceinline__ float b2f(u16 v) {
    union { unsigned u; float f; } x; x.u = ((unsigned)v) << 16; return x.f;
}
static __device__ __forceinline__ u16 f2h_bits(float f) {
    union { _Float16 h; u16 u; } v; v.h = (_Float16)f; return v.u;
}
static __device__ __forceinline__ float h2f_bits(u16 u) {
    union { u16 u; _Float16 h; } v; v.u = u; return (float)v.h;
}

// =============== bf16 MFMA GEMM (full-K): used for FFN1 (+gelu) ===============
template<int MODE>
__global__ __launch_bounds__(256) void mfma_gemm(const u16* __restrict__ A, int lda,
    const u16* __restrict__ Bt, const float* __restrict__ bias,
    float* __restrict__ C, u16* __restrict__ Cb, int ldc, int K, int act)
{
    __shared__ u16 As[128][72];
    __shared__ u16 Bs[128][72];
    int tid = threadIdx.x;
    int m0 = blockIdx.x * 128, n0 = blockIdx.y * 128;
    int wave = tid >> 6, lane = tid & 63;
    int ln = lane & 15, quad = lane >> 4;
    int wm = (wave >> 1) * 64, wn = (wave & 1) * 64;
    f32x4 acc[4][4] = {};
    for (int k0 = 0; k0 < K; k0 += 64) {
        #pragma unroll
        for (int i = 0; i < 4; i++) {
            int t = tid + i * 256;
            int m = t >> 3, kq = t & 7;
            size_t aoff;
            if (MODE == 1) {
                int grow = m0 + m;
                int shift = (k0 >> 9) - 1;
                int arow = (grow & ~(NN - 1)) | ((grow + shift) & (NN - 1));
                aoff = (size_t)arow * NC + ((k0 & 511) + kq * 8);
            } else {
                aoff = (size_t)(m0 + m) * lda + k0 + kq * 8;
            }
            *(uint4*)&As[m][kq * 8] = *(const uint4*)&A[aoff];
            *(uint4*)&Bs[m][kq * 8] = *(const uint4*)&Bt[(size_t)(n0 + m) * K + k0 + kq * 8];
        }
        __syncthreads();
        #pragma unroll
        for (int kk = 0; kk < 2; kk++) {
            frag8 af[4], bf[4];
            #pragma unroll
            for (int i = 0; i < 4; i++) {
                af[i] = *(const frag8*)&As[wm + i * 16 + ln][kk * 32 + quad * 8];
                bf[i] = *(const frag8*)&Bs[wn + i * 16 + ln][kk * 32 + quad * 8];
            }
            #pragma unroll
            for (int i = 0; i < 4; i++)
                #pragma unroll
                for (int j = 0; j < 4; j++)
                    acc[i][j] = __builtin_amdgcn_mfma_f32_16x16x32_bf16(
                        af[i], bf[j], acc[i][j], 0, 0, 0);
        }
        __syncthreads();
    }
    #pragma unroll
    for (int i = 0; i < 4; i++) {
        #pragma unroll
        for (int j = 0; j < 4; j++) {
            int col = n0 + wn + j * 16 + ln;
            float bv = bias ? bias[col] : 0.f;
            #pragma unroll
            for (int r = 0; r < 4; r++) {
                int row = m0 + wm + i * 16 + quad * 4 + r;
                float v = acc[i][j][r] + bv;
                if (act == 1) v = 0.5f * v * (1.0f + erff(v * 0.70710678118654752f));
                if (Cb) Cb[(size_t)row * ldc + col] = f2b(v);
                else    C[(size_t)row * ldc + col] = v;
            }
        }
    }
}

// =============== split-K x2 MFMA GEMM: fp32 partials, no bias/act ===============
template<int MODE>
__global__ __launch_bounds__(256) void mfma_gemm_sk(const u16* __restrict__ A, int lda,
    const u16* __restrict__ Bt, float* __restrict__ P0, float* __restrict__ P1,
    int ldc, int K)
{
    __shared__ u16 As[128][72];
    __shared__ u16 Bs[128][72];
    int tid = threadIdx.x;
    int m0 = blockIdx.x * 128, n0 = blockIdx.y * 128;
    int split = blockIdx.z;
    int K2 = K >> 1, kbeg = split * K2;
    int wave = tid >> 6, lane = tid & 63;
    int ln = lane & 15, quad = lane >> 4;
    int wm = (wave >> 1) * 64, wn = (wave & 1) * 64;
    f32x4 acc[4][4] = {};
    for (int k0 = kbeg; k0 < kbeg + K2; k0 += 64) {
        #pragma unroll
        for (int i = 0; i < 4; i++) {
            int t = tid + i * 256;
            int m = t >> 3, kq = t & 7;
            size_t aoff;
            if (MODE == 1) {
                int grow = m0 + m;
                int shift = (k0 >> 9) - 1;
                int arow = (grow & ~(NN - 1)) | ((grow + shift) & (NN - 1));
                aoff = (size_t)arow * NC + ((k0 & 511) + kq * 8);
            } else {
                aoff = (size_t)(m0 + m) * lda + k0 + kq * 8;
            }
            *(uint4*)&As[m][kq * 8] = *(const uint4*)&A[aoff];
            *(uint4*)&Bs[m][kq * 8] = *(const uint4*)&Bt[(size_t)(n0 + m) * K + k0 + kq * 8];
        }
        __syncthreads();
        #pragma unroll
        for (int kk = 0; kk < 2; kk++) {
            frag8 af[4], bf[4];
            #pragma unroll
            for (int i = 0; i < 4; i++) {
                af[i] = *(const frag8*)&As[wm + i * 16 + ln][kk * 32 + quad * 8];
                bf[i] = *(const frag8*)&Bs[wn + i * 16 + ln][kk * 32 + quad * 8];
            }
            #pragma unroll
            for (int i = 0; i < 4; i++)
                #pragma unroll
                for (int j = 0; j < 4; j++)
                    acc[i][j] = __builtin_amdgcn_mfma_f32_16x16x32_bf16(
                        af[i], bf[j], acc[i][j], 0, 0, 0);
        }
        __syncthreads();
    }
    float* P = split ? P1 : P0;
    #pragma unroll
    for (int i = 0; i < 4; i++) {
        #pragma unroll
        for (int j = 0; j < 4; j++) {
            int col = n0 + wn + j * 16 + ln;
            #pragma unroll
            for (int r = 0; r < 4; r++) {
                int row = m0 + wm + i * 16 + quad * 4 + r;
                P[(size_t)row * ldc + col] = acc[i][j][r];
            }
        }
    }
}

// =============== QKV projection: f16 concat-hi/lo MFMA GEMM (fp32-grade) =========
// Emits: Q -> Qbs (bf16, pre-scaled 0.125, head-major) + Qcat (fp16 hi/lo);
//        K -> Kb (bf16, head-major) + Kcat; V -> Vh fp32 head-major.
// Qh/Kh fp32 intermediates eliminated (consumers only ever downcast them).
__global__ __launch_bounds__(256) void mfma_qkv(const u16* __restrict__ A,
    const u16* __restrict__ Bt, const float* __restrict__ bias,
    u16* __restrict__ Qbs, u16* __restrict__ Kb, float* __restrict__ Vh,
    u16* __restrict__ Qcat, u16* __restrict__ Kcat)
{
    __shared__ u16 As[128][72];
    __shared__ u16 Bs[128][72];
    int tid = threadIdx.x;
    int m0 = blockIdx.x * 128, n0 = blockIdx.y * 128;
    int wave = tid >> 6, lane = tid & 63;
    int ln = lane & 15, quad = lane >> 4;
    int wm = (wave >> 1) * 64, wn = (wave & 1) * 64;
    f32x4 acc[4][4] = {};
    for (int k0 = 0; k0 < 1024; k0 += 64) {
        #pragma unroll
        for (int i = 0; i < 4; i++) {
            int t = tid + i * 256;
            int m = t >> 3, kq = t & 7;
            *(uint4*)&As[m][kq * 8] = *(const uint4*)&A[(size_t)(m0 + m) * 1024 + k0 + kq * 8];
            *(uint4*)&Bs[m][kq * 8] = *(const uint4*)&Bt[(size_t)(n0 + m) * 1024 + k0 + kq * 8];
        }
        __syncthreads();
        #pragma unroll
        for (int kk = 0; kk < 2; kk++) {
            h8 af[4], bf[4];
            #pragma unroll
            for (int i = 0; i < 4; i++) {
                af[i] = *(const h8*)&As[wm + i * 16 + ln][kk * 32 + quad * 8];
                bf[i] = *(const h8*)&Bs[wn + i * 16 + ln][kk * 32 + quad * 8];
            }
            #pragma unroll
            for (int i = 0; i < 4; i++)
                #pragma unroll
                for (int j = 0; j < 4; j++)
                    acc[i][j] = __builtin_amdgcn_mfma_f32_16x16x32_f16(
                        af[i], bf[j], acc[i][j], 0, 0, 0);
        }
        __syncthreads();
    }
    #pragma unroll
    for (int i = 0; i < 4; i++) {
        #pragma unroll
        for (int j = 0; j < 4; j++) {
            int col = n0 + wn + j * 16 + ln;   // 0..1535 : [Q | K | V]
            float bv = bias[col];
            int which = col >> 9;
            int h = (col >> 6) & 7, d = col & 63;
            #pragma unroll
            for (int r = 0; r < 4; r++) {
                int row = m0 + wm + i * 16 + quad * 4 + r;
                int b = row >> 11, n = row & (NN - 1);
                float v = acc[i][j][r] + bv;
                size_t off32 = ((size_t)((b << 3) + h) * NN + n) * DK + d;
                if (which == 2) {
                    Vh[off32] = v;
                } else {
                    size_t offc = ((size_t)((b << 3) + h) * NN + n) * 128 + d;
                    u16 hb_ = f2h_bits(v);
                    u16 lb_ = f2h_bits(v - h2f_bits(hb_));
                    if (which == 0) {
                        Qbs[off32] = f2b(v * 0.125f);
                        Qcat[offc] = hb_; Qcat[offc + 64] = lb_;
                    } else {
                        Kb[off32] = f2b(v);
                        Kcat[offc] = hb_; Kcat[offc + 64] = lb_;
                    }
                }
            }
        }
    }
}

// =============== weight cast+transpose (bf16) ===============
__global__ __launch_bounds__(256) void castw_t(const float* __restrict__ in,
    u16* __restrict__ out, int R, int C, int ldi, int coff)
{
    __shared__ float t[32][33];
    int c0 = blockIdx.x * 32, r0 = blockIdx.y * 32;
    int lx = threadIdx.x & 31, ly = threadIdx.x >> 5;
    #pragma unroll
    for (int i = 0; i < 4; i++)
        t[ly + i * 8][lx] = in[(size_t)(r0 + ly + i * 8) * ldi + coff + c0 + lx];
    __syncthreads();
    #pragma unroll
    for (int i = 0; i < 4; i++)
        out[(size_t)(c0 + ly + i * 8) * R + r0 + lx] = f2b(t[lx][ly + i * 8]);
}

// =============== qkv_w all 1536 cols: transpose + fp16 hi/lo concat ===============
__global__ __launch_bounds__(256) void castw_hl(const float* __restrict__ in,
    u16* __restrict__ out)
{
    __shared__ float t[32][33];
    int c0 = blockIdx.x * 32, r0 = blockIdx.y * 32;
    int lx = threadIdx.x & 31, ly = threadIdx.x >> 5;
    #pragma unroll
    for (int i = 0; i < 4; i++)
        t[ly + i * 8][lx] = in[(size_t)(r0 + ly + i * 8) * 1536 + c0 + lx];
    __syncthreads();
    #pragma unroll
    for (int i = 0; i < 4; i++) {
        float v = t[lx][ly + i * 8];
        u16 hb_ = f2h_bits(v);
        u16 lb_ = f2h_bits(v - h2f_bits(hb_));
        size_t ob = (size_t)(c0 + ly + i * 8) * 1024 + r0 + lx;
        out[ob] = hb_;
        out[ob + 512] = lb_;
    }
}

// =============== conv weight cast: [co][ci][t] -> [co][t*512+ci] bf16 ===============
__global__ void castconvw_k(const float* __restrict__ cw, u16* __restrict__ out)
{
    int i = blockIdx.x * 256 + threadIdx.x;
    if (i >= 3 * NC * NC) return;
    int t = i % 3, ci = (i / 3) & (NC - 1), co = i / (3 * NC);
    out[(size_t)co * 1536 + t * NC + ci] = f2b(cw[i]);
}

// =============== x: fp32 [M][512] -> concat hi/lo fp16 [M][1024] ===============
__global__ void castx_k(const float* __restrict__ in, u16* __restrict__ xcat)
{
    int i = blockIdx.x * 256 + threadIdx.x;
    if (i >= (NB * NN * NC) / 4) return;
    int m = i >> 7, kq = i & 127;
    float4 v = ((const float4*)in)[i];
    ushort4 h, l;
    h.x = f2h_bits(v.x); h.y = f2h_bits(v.y);
    h.z = f2h_bits(v.z); h.w = f2h_bits(v.w);
    l.x = f2h_bits(v.x - h2f_bits(h.x));
    l.y = f2h_bits(v.y - h2f_bits(h.y));
    l.z = f2h_bits(v.z - h2f_bits(h.z));
    l.w = f2h_bits(v.w - h2f_bits(h.w));
    *(ushort4*)&xcat[(size_t)m * 1024 + kq * 4] = h;
    *(ushort4*)&xcat[(size_t)m * 1024 + 512 + kq * 4] = l;
}

// =============== V transpose -> Vtb bf16, + fused meanv partial sums ===============
__global__ __launch_bounds__(256) void castv_k(const float* __restrict__ Vh,
    u16* __restrict__ Vtb, float* __restrict__ pmean)
{
    int bh = blockIdx.y;
    int n0 = blockIdx.x * 64;
    __shared__ float vt[64][68];
    __shared__ float red[256];
    int tid = threadIdx.x;
    const float* vin = Vh + ((size_t)bh * NN + n0) * DK;
    #pragma unroll
    for (int i = 0; i < 4; i++) {
        int t = tid + i * 256;
        int n = t >> 4, dq = t & 15;
        float4 w = *(const float4*)&vin[(size_t)n * DK + dq * 4];
        vt[dq * 4 + 0][n] = w.x; vt[dq * 4 + 1][n] = w.y;
        vt[dq * 4 + 2][n] = w.z; vt[dq * 4 + 3][n] = w.w;
    }
    __syncthreads();
    #pragma unroll
    for (int i = 0; i < 4; i++) {
        int t = tid + i * 256;
        int d = t >> 4, nq = t & 15;
        float4 v = *(const float4*)&vt[d][nq * 4];
        ushort4 o;
        o.x = f2b(v.x); o.y = f2b(v.y); o.z = f2b(v.z); o.w = f2b(v.w);
        *(ushort4*)&Vtb[((size_t)bh * DK + d) * NN + n0 + nq * 4] = o;
    }
    // fused meanv partial: same (sub*16+r) order as the old meanv_part_k (bit-exact)
    int d = tid & 63, sub = tid >> 6;
    float s = 0.f;
    #pragma unroll
    for (int r = 0; r < 16; r++) s += vt[d][sub * 16 + r];
    red[tid] = s;
    __syncthreads();
    if (sub == 0)
        pmean[((size_t)bh * 32 + (n0 >> 6)) * 64 + d] =
            red[d] + red[64 + d] + red[128 + d] + red[192 + d];
}

// =============== mean of V: stage 2 combine ===============
__global__ void meanv_comb_k(const float* __restrict__ pmean, float* __restrict__ meanv)
{
    int bh = blockIdx.x;
    int d = threadIdx.x;   // 64 threads
    float s = 0.f;
    #pragma unroll
    for (int c = 0; c < 32; c++) s += pmean[((size_t)bh * 32 + c) * 64 + d];
    meanv[bh * DK + d] = s * (1.0f / (float)NN);
}

// =============== rowstat via concat-fp16 MFMA; emits Marr and scaled rowmax ========
__global__ __launch_bounds__(256) void rowstat_mfma_k(const u16* __restrict__ Qcat,
    const u16* __restrict__ Kcat, float* __restrict__ Marr, float* __restrict__ rowmax)
{
    int bh = blockIdx.x;
    int m0 = blockIdx.y * 64;
    int tid = threadIdx.x;
    int wave = tid >> 6, lane = tid & 63;
    int ln = lane & 15, quad = lane >> 4;
    __shared__ u16 Ks[128][136];
    h8 qf[4];
    {
        const u16* qp = &Qcat[((size_t)bh * NN + m0 + wave * 16 + ln) * 128];
        #pragma unroll
        for (int ks = 0; ks < 4; ks++)
            qf[ks] = *(const h8*)&qp[ks * 32 + quad * 8];
    }
    f32x4 vmax, vsum;
    #pragma unroll
    for (int r = 0; r < 4; r++) { vmax[r] = -INFINITY; vsum[r] = 0.f; }
    const u16* kB = Kcat + (size_t)bh * NN * 128;
    for (int nc = 0; nc < NN; nc += 128) {
        __syncthreads();
        #pragma unroll
        for (int i = 0; i < 8; i++) {
            int e = tid + i * 256;
            int n = e >> 4, kq = e & 15;
            *(uint4*)&Ks[n][kq * 8] = *(const uint4*)&kB[(size_t)(nc + n) * 128 + kq * 8];
        }
        __syncthreads();
        f32x4 accS[8] = {};
        #pragma unroll
        for (int nt = 0; nt < 8; nt++) {
            #pragma unroll
            for (int ks = 0; ks < 4; ks++) {
                h8 kf = *(const h8*)&Ks[nt * 16 + ln][ks * 32 + quad * 8];
                accS[nt] = __builtin_amdgcn_mfma_f32_16x16x32_f16(
                    qf[ks], kf, accS[nt], 0, 0, 0);
            }
        }
        #pragma unroll
        for (int nt = 0; nt < 8; nt++)
            #pragma unroll
            for (int r = 0; r < 4; r++) {
                vmax[r] = fmaxf(vmax[r], accS[nt][r]);
                vsum[r] += accS[nt][r];
            }
    }
    #pragma unroll
    for (int r = 0; r < 4; r++) {
        float mx = vmax[r], sm = vsum[r];
        #pragma unroll
        for (int off = 1; off < 16; off <<= 1) {
            mx = fmaxf(mx, __shfl_xor(mx, off));
            sm += __shfl_xor(sm, off);
        }
        if (ln == 0) {
            int m = m0 + wave * 16 + quad * 4 + r;
            Marr[(size_t)bh * NN + m] = (mx - sm * (1.0f / (float)NN)) * 0.125f;
            rowmax[(size_t)bh * NN + m] = mx * 0.125f;
        }
    }
}

// =============== top-512 per (b,h): radix-select, wave-shfl scans ===============
__global__ __launch_bounds__(256) void topk_k(const float* __restrict__ Marr,
                                              int* __restrict__ idx)
{
    int bh = blockIdx.x;
    const float* Mr = Marr + (size_t)bh * NN;
    int* idxr = idx + (size_t)bh * NTOP;
    __shared__ int hist[256];
    __shared__ int suf[256];
    __shared__ int wred[4], wred2[4];
    __shared__ int bin_sh, rank_sh;
    int tid = threadIdx.x;
    int lane = tid & 63, w = tid >> 6;
    unsigned prefix = 0;
    int rank = NTOP;
    for (int pass = 0; pass < 4; pass++) {
        int shift = 24 - pass * 8;
        unsigned mask_hi = (pass == 0) ? 0u : (0xFFFFFFFFu << (shift + 8));
        hist[tid] = 0;
        __syncthreads();
        for (int i = tid; i < NN; i += 256) {
            union { float f; unsigned u; } v; v.f = Mr[i];
            unsigned k = (v.u & 0x80000000u) ? ~v.u : (v.u | 0x80000000u);
            if ((k & mask_hi) == prefix)
                atomicAdd(&hist[(k >> shift) & 255], 1);
        }
        __syncthreads();
        int v = hist[tid];
        #pragma unroll
        for (int off = 1; off < 64; off <<= 1) {
            int t = __shfl_down(v, off);
            if (lane + off < 64) v += t;
        }
        if (lane == 0) wred[w] = v;
        __syncthreads();
        int add = 0;
        #pragma unroll
        for (int w2 = 0; w2 < 4; w2++) if (w2 > w) add += wred[w2];
        suf[tid] = v + add;
        __syncthreads();
        int sv = suf[tid];
        int nxt = (tid < 255) ? suf[tid + 1] : 0;
        if (sv >= rank && nxt < rank) { bin_sh = tid; rank_sh = rank - nxt; }
        __syncthreads();
        prefix |= ((unsigned)bin_sh << shift);
        rank = rank_sh;
        __syncthreads();
    }
    union { unsigned u; float f; } tv;
    tv.u = (prefix & 0x80000000u) ? (prefix & 0x7FFFFFFFu) : ~prefix;
    float thr = tv.f;
    int lg = 0, le = 0;
    #pragma unroll
    for (int k = 0; k < 8; k++) {
        float v = Mr[tid * 8 + k];
        lg += (v > thr) ? 1 : 0;
        le += (v == thr) ? 1 : 0;
    }
    int vg = lg, ve = le;
    #pragma unroll
    for (int off = 1; off < 64; off <<= 1) {
        int tg = __shfl_up(vg, off);
        int te = __shfl_up(ve, off);
        if (lane >= off) { vg += tg; ve += te; }
    }
    if (lane == 63) { wred[w] = vg; wred2[w] = ve; }
    __syncthreads();
    int addg = 0, adde = 0, totg = 0;
    #pragma unroll
    for (int w2 = 0; w2 < 4; w2++) {
        totg += wred[w2];
        if (w2 < w) { addg += wred[w2]; adde += wred2[w2]; }
    }
    int cnt_gt = totg;
    int needed = NTOP - cnt_gt;
    int gpre = (vg + addg) - lg, epre = (ve + adde) - le;
    #pragma unroll
    for (int k = 0; k < 8; k++) {
        int p = tid * 8 + k;
        float v = Mr[p];
        bool isgt = v > thr, iseq = v == thr;
        bool selv = isgt || (iseq && epre < needed);
        if (selv) idxr[gpre + (epre < needed ? epre : needed)] = p;
        gpre += isgt ? 1 : 0;
        epre += iseq ? 1 : 0;
    }
}

// =============== fill ctx (bf16) with uniform-attention result, ushort8 ===========
__global__ void fill_k(const float* __restrict__ meanv, u16* __restrict__ ctxb)
{
    int i = blockIdx.x * 256 + threadIdx.x;      // 8-elem groups
    if (i >= (NB * NN * NC) / 8) return;
    int c = (i * 8) & (NC - 1);
    int m = (i * 8) >> 9;
    int b = m >> 11;
    int h = c >> 6, d = c & 63;
    const float* mv = &meanv[(((b << 3) + h) << 6) + d];
    float4 v0 = *(const float4*)mv;
    float4 v1 = *(const float4*)(mv + 4);
    union { u16 s[8]; uint4 u; } r;
    r.s[0] = f2b(v0.x); r.s[1] = f2b(v0.y); r.s[2] = f2b(v0.z); r.s[3] = f2b(v0.w);
    r.s[4] = f2b(v1.x); r.s[5] = f2b(v1.y); r.s[6] = f2b(v1.z); r.s[7] = f2b(v1.w);
    *(uint4*)&ctxb[(size_t)i * 8] = r.u;
}

// =============== MFMA flash attention, precomputed rowmax, split-K ===============
// Q read directly as pre-scaled bf16 (Qbs) — no fp32 fetch + convert.
__global__ __launch_bounds__(256) void attn_mfma_k(const u16* __restrict__ Qbs,
    const u16* __restrict__ Kb, const u16* __restrict__ Vtb,
    const int* __restrict__ idx, const float* __restrict__ rowmax,
    float* __restrict__ Opart, float* __restrict__ ml)
{
    int yy = blockIdx.x;
    int bh = yy >> 2, split = yy & (KSPLIT - 1);
    int t0 = blockIdx.y * 64;
    int tid = threadIdx.x;
    int wave = tid >> 6, lane = tid & 63;
    int ln = lane & 15, quad = lane >> 4;
    __shared__ u16 Ks[128][72];
    __shared__ u16 Vt[64][136];
    __shared__ u16 Ps[4][16][136];
    __shared__ int rows[64];
    if (tid < 64) rows[tid] = idx[bh * NTOP + t0 + tid];
    __syncthreads();
    frag8 qf[2];
    {
        const u16* qp = &Qbs[((size_t)bh * NN + rows[wave * 16 + ln]) * DK];
        qf[0] = *(const frag8*)&qp[quad * 8];
        qf[1] = *(const frag8*)&qp[32 + quad * 8];
    }
    float rm[4];
    #pragma unroll
    for (int r = 0; r < 4; r++)
        rm[r] = rowmax[(size_t)bh * NN + rows[wave * 16 + quad * 4 + r]];
    f32x4 accO[4] = {};
    float lrun[4] = {};
    const u16* kbB = Kb + (size_t)bh * NN * DK;
    const u16* vtB = Vtb + (size_t)bh * DK * NN;
    int nc0 = split * (NN / KSPLIT);
    for (int nc = nc0; nc < nc0 + NN / KSPLIT; nc += 128) {
        __syncthreads();
        #pragma unroll
        for (int i = 0; i < 4; i++) {
            int e = tid + i * 256;
            int n = e >> 3, kq = e & 7;
            *(uint4*)&Ks[n][kq * 8] = *(const uint4*)&kbB[(size_t)(nc + n) * DK + kq * 8];
        }
        #pragma unroll
        for (int i = 0; i < 4; i++) {
            int e = tid + i * 256;
            int d = e >> 4, nq = e & 15;
            *(uint4*)&Vt[d][nq * 8] = *(const uint4*)&vtB[(size_t)d * NN + nc + nq * 8];
        }
        __syncthreads();
        f32x4 accS[8] = {};
        #pragma unroll
        for (int nt = 0; nt < 8; nt++) {
            frag8 b0 = *(const frag8*)&Ks[nt * 16 + ln][quad * 8];
            frag8 b1 = *(const frag8*)&Ks[nt * 16 + ln][32 + quad * 8];
            accS[nt] = __builtin_amdgcn_mfma_f32_16x16x32_bf16(qf[0], b0, accS[nt], 0, 0, 0);
            accS[nt] = __builtin_amdgcn_mfma_f32_16x16x32_bf16(qf[1], b1, accS[nt], 0, 0, 0);
        }
        #pragma unroll
        for (int nt = 0; nt < 8; nt++)
            #pragma unroll
            for (int r = 0; r < 4; r++) {
                float p = expf(accS[nt][r] - rm[r]);
                accS[nt][r] = p;
                lrun[r] += p;
            }
        #pragma unroll
        for (int nt = 0; nt < 8; nt++)
            #pragma unroll
            for (int r = 0; r < 4; r++)
                Ps[wave][quad * 4 + r][nt * 16 + ln] = f2b(accS[nt][r]);
        #pragma unroll
        for (int ks = 0; ks < 4; ks++) {
            frag8 pf = *(const frag8*)&Ps[wave][ln][ks * 32 + quad * 8];
            #pragma unroll
            for (int nt2 = 0; nt2 < 4; nt2++) {
                frag8 vf = *(const frag8*)&Vt[nt2 * 16 + ln][ks * 32 + quad * 8];
                accO[nt2] = __builtin_amdgcn_mfma_f32_16x16x32_bf16(pf, vf, accO[nt2], 0, 0, 0);
            }
        }
    }
    #pragma unroll
    for (int r = 0; r < 4; r++) {
        float ls = lrun[r];
        #pragma unroll
        for (int off = 1; off < 16; off <<= 1) ls += __shfl_xor(ls, off);
        int p = t0 + wave * 16 + quad * 4 + r;
        size_t pb = ((size_t)bh * NTOP + p) * KSPLIT + split;
        #pragma unroll
        for (int nt2 = 0; nt2 < 4; nt2++)
            Opart[pb * 64 + nt2 * 16 + ln] = accO[nt2][r];
        if (ln == 0) ml[pb * 2 + 1] = ls;
    }
}

// =============== combine split-K partials -> ctxb (bf16) ===============
__global__ __launch_bounds__(256) void attn_comb_k(const float* __restrict__ Opart,
    const float* __restrict__ ml, const int* __restrict__ idx,
    u16* __restrict__ ctxb)
{
    int gid = blockIdx.x * 4 + (threadIdx.x >> 6);
    int lane = threadIdx.x & 63;
    int bh = gid >> 9;
    int h = bh & 7, b = bh >> 3;
    size_t base = (size_t)gid * KSPLIT;
    float L = 0.f, O = 0.f;
    #pragma unroll
    for (int s = 0; s < KSPLIT; s++) {
        L += ml[(base + s) * 2 + 1];
        O += Opart[(base + s) * 64 + lane];
    }
    int n = idx[gid];
    ctxb[((size_t)(b * NN + n)) * NC + h * DK + lane] = f2b(O / L);
}

// =============== layernorm of A + P0 + P1 + cb; fp32 and/or bf16 out ===============
__global__ __launch_bounds__(256) void ln_k(const float* __restrict__ A,
    const float* __restrict__ P0, const float* __restrict__ P1,
    const float* __restrict__ cb,
    const float* __restrict__ g, const float* __restrict__ bb,
    float* __restrict__ out, u16* __restrict__ outb)
{
    int row = blockIdx.x;
    int tid = threadIdx.x;
    __shared__ float v[NC];
    __shared__ float red[256];
    size_t base = (size_t)row * NC;
    for (int i = tid; i < NC; i += 256)
        v[i] = A[base + i] + P0[base + i] + P1[base + i] + cb[i];
    __syncthreads();
    float ls = 0.f;
    for (int i = tid; i < NC; i += 256) ls += v[i];
    red[tid] = ls; __syncthreads();
    for (int off = 128; off > 0; off >>= 1) {
        if (tid < off) red[tid] += red[tid + off];
        __syncthreads();
    }
    float mu = red[0] / (float)NC;
    __syncthreads();
    float lv = 0.f;
    for (int i = tid; i < NC; i += 256) { float d = v[i] - mu; lv += d * d; }
    red[tid] = lv; __syncthreads();
    for (int off = 128; off > 0; off >>= 1) {
        if (tid < off) red[tid] += red[tid + off];
        __syncthreads();
    }
    float rstd = rsqrtf(red[0] / (float)NC + 1e-5f);
    for (int i = tid; i < NC; i += 256) {
        float r = (v[i] - mu) * rstd * g[i] + bb[i];
        if (out) out[base + i] = r;
        if (outb) outb[base + i] = f2b(r);
    }
}

// =============== maxpool(3,2,1) + ELU + LN over conv partials (fp32) ===============
__global__ __launch_bounds__(256) void pool_ln_k(const float* __restrict__ P0,
    const float* __restrict__ P1, const float* __restrict__ cb,
    const float* __restrict__ g, const float* __restrict__ bb,
    float* __restrict__ outp)
{
    int row = blockIdx.x;
    int j = row & (NPOOL - 1), b = row / NPOOL;
    int tid = threadIdx.x;
    __shared__ float v[NC];
    __shared__ float red[256];
    size_t bbase = (size_t)b * NN * NC;
    for (int i = tid; i < NC; i += 256) {
        float m = -INFINITY;
        int p0 = 2 * j - 1;
        float cbv = cb[i];
        #pragma unroll
        for (int t = 0; t < 3; t++) {
            int p = p0 + t;
            if (p >= 0 && p < NN) {
                size_t off = bbase + (size_t)p * NC + i;
                m = fmaxf(m, P0[off] + P1[off] + cbv);
            }
        }
        v[i] = m > 0.f ? m : expm1f(m);
    }
    __syncthreads();
    float ls = 0.f;
    for (int i = tid; i < NC; i += 256) ls += v[i];
    red[tid] = ls; __syncthreads();
    for (int off = 128; off > 0; off >>= 1) {
        if (tid < off) red[tid] += red[tid + off];
        __syncthreads();
    }
    float mu = red[0] / (float)NC;
    __syncthreads();
    float lv = 0.f;
    for (int i = tid; i < NC; i += 256) { float d = v[i] - mu; lv += d * d; }
    red[tid] = lv; __syncthreads();
    for (int off = 128; off > 0; off >>= 1) {
        if (tid < off) red[tid] += red[tid + off];
        __syncthreads();
    }
    float rstd = rsqrtf(red[0] / (float)NC + 1e-5f);
    for (int i = tid; i < NC; i += 256)
        outp[(size_t)row * NC + i] = (v[i] - mu) * rstd * g[i] + bb[i];
}

extern "C" void kernel_launch(void* const* d_in, const int* in_sizes, int n_in,
                              void* d_out, int out_size, void* d_ws, size_t ws_size,
                              hipStream_t stream)
{
    (void)in_sizes; (void)n_in; (void)out_size; (void)ws_size;
    const float* x      = (const float*)d_in[0];
    const float* qkv_w  = (const float*)d_in[1];
    const float* qkv_b  = (const float*)d_in[2];
    const float* out_w  = (const float*)d_in[3];
    const float* out_b  = (const float*)d_in[4];
    const float* ffn_w1 = (const float*)d_in[5];
    const float* ffn_b1 = (const float*)d_in[6];
    const float* ffn_w2 = (const float*)d_in[7];
    const float* ffn_b2 = (const float*)d_in[8];
    const float* n1_g   = (const float*)d_in[9];
    const float* n1_b   = (const float*)d_in[10];
    const float* n2_g   = (const float*)d_in[11];
    const float* n2_b   = (const float*)d_in[12];
    const float* conv_w = (const float*)d_in[13];
    const float* conv_b = (const float*)d_in[14];
    const float* cn_g   = (const float*)d_in[15];
    const float* cn_b   = (const float*)d_in[16];

    const size_t R = (size_t)NB * NN * NC;     // 2097152
    float* ws = (float*)d_ws;
    float* x1   = ws;                 // R : Kcat during rowstat; Opart; LN1 fp32 out
    float* reg2 = ws + R;             // R : xcat -> Vtb(2nd half) -> split-K P0
    float* QhR  = ws + 2 * R;         // R : Qbs + Kb (bf16, head-major)
    float* Kh   = ws + 3 * R;         // R : hb (FFN1 out)
    float* Vh   = ws + 4 * R;         // R : V fp32; split-K partial P1
    size_t o = 5 * R;
    float* pmax  = ws + o;  o += 65536;   // rowmax (scaled) lives here
    float* psum  = ws + o;  o += 65536;   // (layout stability; unused)
    float* Marr  = ws + o;  o += 32768;
    float* pmean = ws + o;  o += 32768;
    float* meanv = ws + o;  o += 1024;
    int*   idx   = (int*)(ws + o);  o += 8192;
    float* ml    = ws + o;  o += 65536;
    u16*   ctxb  = (u16*)(ws + o);  o += R / 2;
    u16*   x1b   = (u16*)(ws + o);  o += R / 2;   // Qcat lower half
    u16*   x2b   = (u16*)(ws + o);  o += R / 2;   // Qcat upper half; LN2 out
    u16*   owT   = (u16*)(ws + o);  o += 131072;
    u16*   w1T   = (u16*)(ws + o);  o += 524288;  // wcatT(lo) early, ffn_w1^T after qkv
    u16*   w2T   = (u16*)(ws + o);  o += 524288;  // wcatT(hi) early, ffn_w2^T after qkv
    u16*   cwT   = (u16*)(ws + o);  o += 393216;
    u16*   Qbs   = (u16*)QhR;                       // [16][2048][64] bf16 pre-scaled
    u16*   Kb    = (u16*)(QhR + R / 2);             // [16][2048][64] bf16
    u16*   Vtb   = (u16*)(ws + R + R / 2);          // [16][64][2048] bf16; dead after attn
    float* Opart    = x1;
    u16*   hb       = (u16*)Kh;
    float* rowmax   = pmax;
    // split-K fp32 partial pair (time-shared by proj -> FFN2 -> conv):
    float* skP0 = reg2;               // dead region at each use point
    float* skP1 = Vh;
    // concat-fp16 buffers for the fused QKV projection + rowstat:
    u16*   xcat  = (u16*)reg2;        // [4096][1024] fp16 — dead after mfma_qkv
    u16*   wcatT = w1T;               // [1536][1024] fp16 spans w1T+w2T (contiguous)
    u16*   Qcat  = x1b;               // (x1b+x2b)
    u16*   Kcat  = (u16*)x1;
    (void)psum;

    // early casts into regions not needed until later
    castw_t<<<dim3(16, 16), 256, 0, stream>>>(out_w, owT, 512, 512, 512, 0);
    castconvw_k<<<3072, 256, 0, stream>>>(conv_w, cwT);
    castx_k<<<2048, 256, 0, stream>>>(x, xcat);
    castw_hl<<<dim3(48, 16), 256, 0, stream>>>(qkv_w, wcatT);

    // fused Q,K,V projection: emits Qbs/Kb bf16 + Qcat/Kcat fp16 + Vh fp32
    mfma_qkv<<<dim3(32, 12), 256, 0, stream>>>(xcat, wcatT, qkv_b,
                                               Qbs, Kb, Vh, Qcat, Kcat);

    // wcatT dead -> build real w1T/w2T
    castw_t<<<dim3(64, 16), 256, 0, stream>>>(ffn_w1, w1T, 512, 2048, 2048, 0);
    castw_t<<<dim3(16, 64), 256, 0, stream>>>(ffn_w2, w2T, 2048, 512, 512, 0);

    // V transpose -> Vtb (into dead xcat 2nd half) + fused meanv partials
    castv_k<<<dim3(NN / 64, NB * NH), 256, 0, stream>>>(Vh, Vtb, pmean);
    meanv_comb_k<<<NB * NH, 64, 0, stream>>>(pmean, meanv);

    // row max/mean of scores via concat-fp16 MFMA; emits Marr + rowmax
    rowstat_mfma_k<<<dim3(NB * NH, NN / 64), 256, 0, stream>>>(Qcat, Kcat, Marr, rowmax);
    topk_k<<<NB * NH, 256, 0, stream>>>(Marr, idx);
    fill_k<<<(int)(R / 8 / 256), 256, 0, stream>>>(meanv, ctxb);
    attn_mfma_k<<<dim3(NB * NH * KSPLIT, NTOP / 64), 256, 0, stream>>>(
        Qbs, Kb, Vtb, idx, rowmax, Opart, ml);
    attn_comb_k<<<NB * NH * NTOP / 4, 256, 0, stream>>>(Opart, ml, idx, ctxb);

    // proj: split-K x2 (256 wg = full GPU); partials combined in LN1
    mfma_gemm_sk<0><<<dim3(32, 4, 2), 256, 0, stream>>>(
        ctxb, NC, owT, skP0, skP1, NC, NC);

    // x1 = LN(x + proj_p0 + proj_p1 + out_b)
    ln_k<<<NB * NN, 256, 0, stream>>>(x, skP0, skP1, out_b, n1_g, n1_b, x1, x1b);

    // FFN1 (full-K, 512 wg already); FFN2 split-K x2
    mfma_gemm<0><<<dim3(32, 16), 256, 0, stream>>>(
        x1b, NC, w1T, ffn_b1, (float*)nullptr, hb, DFF, NC, 1);
    mfma_gemm_sk<0><<<dim3(32, 4, 2), 256, 0, stream>>>(
        hb, DFF, w2T, skP0, skP1, NC, DFF);

    // x2 = LN(x1 + ffn2_p0 + ffn2_p1 + ffn_b2) -> bf16
    ln_k<<<NB * NN, 256, 0, stream>>>(x1, skP0, skP1, ffn_b2,
                                      n2_g, n2_b, (float*)nullptr, x2b);

    // fused circular conv1d(k=3): split-K x2 MFMA GEMM, K=1536
    mfma_gemm_sk<1><<<dim3(32, 4, 2), 256, 0, stream>>>(
        x2b, NC, cwT, skP0, skP1, NC, 1536);

    pool_ln_k<<<NB * NPOOL, 256, 0, stream>>>(skP0, skP1, conv_b, cn_g, cn_b,
                                              (float*)d_out);
}

// Round 10
// 320.458 us; speedup vs baseline: 1.8670x; 1.0118x over previous
//
#include <hip/hip_runtime.h>
#include <math.h>

#define NB 2
#define NN 2048
#define NC 512
#define NH 8
#define DK 64
#define DFF 2048
#define NTOP 512
#define NPOOL 1024
#define KSPLIT 4

typedef unsigned short u16;
typedef __attribute__((ext_vector_type(8))) short frag8;
typedef __attribute__((ext_vector_type(8))) _Float16 h8;
typedef __attribute__((ext_vector_type(4))) float f32x4;

static __device__ __forceinline__ u16 f2b(float f) {
    union { float f; unsigned int u; } v; v.f = f;
    unsigned int r = (v.u + 0x7fffu + ((v.u >> 16) & 1u)) >> 16;
    return (u16)r;
}
static __device__ __forceinline__ float b2f(u16 v) {
    union { unsigned u; float f; } x; x.u = ((unsigned)v) << 16; return x.f;
}
static __device__ __forceinline__ u16 f2h_bits(float f) {
    union { _Float16 h; u16 u; } v; v.h = (_Float16)f; return v.u;
}
static __device__ __forceinline__ float h2f_bits(u16 u) {
    union { u16 u; _Float16 h; } v; v.u = u; return (float)v.h;
}

// =============== bf16 MFMA GEMM (full-K): used for FFN1 (+gelu) ===============
template<int MODE>
__global__ __launch_bounds__(256) void mfma_gemm(const u16* __restrict__ A, int lda,
    const u16* __restrict__ Bt, const float* __restrict__ bias,
    float* __restrict__ C, u16* __restrict__ Cb, int ldc, int K, int act)
{
    __shared__ u16 As[128][72];
    __shared__ u16 Bs[128][72];
    int tid = threadIdx.x;
    int m0 = blockIdx.x * 128, n0 = blockIdx.y * 128;
    int wave = tid >> 6, lane = tid & 63;
    int ln = lane & 15, quad = lane >> 4;
    int wm = (wave >> 1) * 64, wn = (wave & 1) * 64;
    f32x4 acc[4][4] = {};
    for (int k0 = 0; k0 < K; k0 += 64) {
        #pragma unroll
        for (int i = 0; i < 4; i++) {
            int t = tid + i * 256;
            int m = t >> 3, kq = t & 7;
            size_t aoff;
            if (MODE == 1) {
                int grow = m0 + m;
                int shift = (k0 >> 9) - 1;
                int arow = (grow & ~(NN - 1)) | ((grow + shift) & (NN - 1));
                aoff = (size_t)arow * NC + ((k0 & 511) + kq * 8);
            } else {
                aoff = (size_t)(m0 + m) * lda + k0 + kq * 8;
            }
            *(uint4*)&As[m][kq * 8] = *(const uint4*)&A[aoff];
            *(uint4*)&Bs[m][kq * 8] = *(const uint4*)&Bt[(size_t)(n0 + m) * K + k0 + kq * 8];
        }
        __syncthreads();
        #pragma unroll
        for (int kk = 0; kk < 2; kk++) {
            frag8 af[4], bf[4];
            #pragma unroll
            for (int i = 0; i < 4; i++) {
                af[i] = *(const frag8*)&As[wm + i * 16 + ln][kk * 32 + quad * 8];
                bf[i] = *(const frag8*)&Bs[wn + i * 16 + ln][kk * 32 + quad * 8];
            }
            #pragma unroll
            for (int i = 0; i < 4; i++)
                #pragma unroll
                for (int j = 0; j < 4; j++)
                    acc[i][j] = __builtin_amdgcn_mfma_f32_16x16x32_bf16(
                        af[i], bf[j], acc[i][j], 0, 0, 0);
        }
        __syncthreads();
    }
    #pragma unroll
    for (int i = 0; i < 4; i++) {
        #pragma unroll
        for (int j = 0; j < 4; j++) {
            int col = n0 + wn + j * 16 + ln;
            float bv = bias ? bias[col] : 0.f;
            #pragma unroll
            for (int r = 0; r < 4; r++) {
                int row = m0 + wm + i * 16 + quad * 4 + r;
                float v = acc[i][j][r] + bv;
                if (act == 1) v = 0.5f * v * (1.0f + erff(v * 0.70710678118654752f));
                if (Cb) Cb[(size_t)row * ldc + col] = f2b(v);
                else    C[(size_t)row * ldc + col] = v;
            }
        }
    }
}

// =============== split-K x2 MFMA GEMM: fp32 partials, no bias/act ===============
template<int MODE>
__global__ __launch_bounds__(256) void mfma_gemm_sk(const u16* __restrict__ A, int lda,
    const u16* __restrict__ Bt, float* __restrict__ P0, float* __restrict__ P1,
    int ldc, int K)
{
    __shared__ u16 As[128][72];
    __shared__ u16 Bs[128][72];
    int tid = threadIdx.x;
    int m0 = blockIdx.x * 128, n0 = blockIdx.y * 128;
    int split = blockIdx.z;
    int K2 = K >> 1, kbeg = split * K2;
    int wave = tid >> 6, lane = tid & 63;
    int ln = lane & 15, quad = lane >> 4;
    int wm = (wave >> 1) * 64, wn = (wave & 1) * 64;
    f32x4 acc[4][4] = {};
    for (int k0 = kbeg; k0 < kbeg + K2; k0 += 64) {
        #pragma unroll
        for (int i = 0; i < 4; i++) {
            int t = tid + i * 256;
            int m = t >> 3, kq = t & 7;
            size_t aoff;
            if (MODE == 1) {
                int grow = m0 + m;
                int shift = (k0 >> 9) - 1;
                int arow = (grow & ~(NN - 1)) | ((grow + shift) & (NN - 1));
                aoff = (size_t)arow * NC + ((k0 & 511) + kq * 8);
            } else {
                aoff = (size_t)(m0 + m) * lda + k0 + kq * 8;
            }
            *(uint4*)&As[m][kq * 8] = *(const uint4*)&A[aoff];
            *(uint4*)&Bs[m][kq * 8] = *(const uint4*)&Bt[(size_t)(n0 + m) * K + k0 + kq * 8];
        }
        __syncthreads();
        #pragma unroll
        for (int kk = 0; kk < 2; kk++) {
            frag8 af[4], bf[4];
            #pragma unroll
            for (int i = 0; i < 4; i++) {
                af[i] = *(const frag8*)&As[wm + i * 16 + ln][kk * 32 + quad * 8];
                bf[i] = *(const frag8*)&Bs[wn + i * 16 + ln][kk * 32 + quad * 8];
            }
            #pragma unroll
            for (int i = 0; i < 4; i++)
                #pragma unroll
                for (int j = 0; j < 4; j++)
                    acc[i][j] = __builtin_amdgcn_mfma_f32_16x16x32_bf16(
                        af[i], bf[j], acc[i][j], 0, 0, 0);
        }
        __syncthreads();
    }
    float* P = split ? P1 : P0;
    #pragma unroll
    for (int i = 0; i < 4; i++) {
        #pragma unroll
        for (int j = 0; j < 4; j++) {
            int col = n0 + wn + j * 16 + ln;
            #pragma unroll
            for (int r = 0; r < 4; r++) {
                int row = m0 + wm + i * 16 + quad * 4 + r;
                P[(size_t)row * ldc + col] = acc[i][j][r];
            }
        }
    }
}

// =============== QKV projection: f16 concat-hi/lo MFMA GEMM (fp32-grade) =========
__global__ __launch_bounds__(256) void mfma_qkv(const u16* __restrict__ A,
    const u16* __restrict__ Bt, const float* __restrict__ bias,
    u16* __restrict__ Qbs, u16* __restrict__ Kb, float* __restrict__ Vh,
    u16* __restrict__ Qcat, u16* __restrict__ Kcat)
{
    __shared__ u16 As[128][72];
    __shared__ u16 Bs[128][72];
    int tid = threadIdx.x;
    int m0 = blockIdx.x * 128, n0 = blockIdx.y * 128;
    int wave = tid >> 6, lane = tid & 63;
    int ln = lane & 15, quad = lane >> 4;
    int wm = (wave >> 1) * 64, wn = (wave & 1) * 64;
    f32x4 acc[4][4] = {};
    for (int k0 = 0; k0 < 1024; k0 += 64) {
        #pragma unroll
        for (int i = 0; i < 4; i++) {
            int t = tid + i * 256;
            int m = t >> 3, kq = t & 7;
            *(uint4*)&As[m][kq * 8] = *(const uint4*)&A[(size_t)(m0 + m) * 1024 + k0 + kq * 8];
            *(uint4*)&Bs[m][kq * 8] = *(const uint4*)&Bt[(size_t)(n0 + m) * 1024 + k0 + kq * 8];
        }
        __syncthreads();
        #pragma unroll
        for (int kk = 0; kk < 2; kk++) {
            h8 af[4], bf[4];
            #pragma unroll
            for (int i = 0; i < 4; i++) {
                af[i] = *(const h8*)&As[wm + i * 16 + ln][kk * 32 + quad * 8];
                bf[i] = *(const h8*)&Bs[wn + i * 16 + ln][kk * 32 + quad * 8];
            }
            #pragma unroll
            for (int i = 0; i < 4; i++)
                #pragma unroll
                for (int j = 0; j < 4; j++)
                    acc[i][j] = __builtin_amdgcn_mfma_f32_16x16x32_f16(
                        af[i], bf[j], acc[i][j], 0, 0, 0);
        }
        __syncthreads();
    }
    #pragma unroll
    for (int i = 0; i < 4; i++) {
        #pragma unroll
        for (int j = 0; j < 4; j++) {
            int col = n0 + wn + j * 16 + ln;   // 0..1535 : [Q | K | V]
            float bv = bias[col];
            int which = col >> 9;
            int h = (col >> 6) & 7, d = col & 63;
            #pragma unroll
            for (int r = 0; r < 4; r++) {
                int row = m0 + wm + i * 16 + quad * 4 + r;
                int b = row >> 11, n = row & (NN - 1);
                float v = acc[i][j][r] + bv;
                size_t off32 = ((size_t)((b << 3) + h) * NN + n) * DK + d;
                if (which == 2) {
                    Vh[off32] = v;
                } else {
                    size_t offc = ((size_t)((b << 3) + h) * NN + n) * 128 + d;
                    u16 hb_ = f2h_bits(v);
                    u16 lb_ = f2h_bits(v - h2f_bits(hb_));
                    if (which == 0) {
                        Qbs[off32] = f2b(v * 0.125f);
                        Qcat[offc] = hb_; Qcat[offc + 64] = lb_;
                    } else {
                        Kb[off32] = f2b(v);
                        Kcat[offc] = hb_; Kcat[offc + 64] = lb_;
                    }
                }
            }
        }
    }
}

// =============== weight cast+transpose (bf16), single matrix ===============
__global__ __launch_bounds__(256) void castw_t(const float* __restrict__ in,
    u16* __restrict__ out, int R, int C, int ldi, int coff)
{
    __shared__ float t[32][33];
    int c0 = blockIdx.x * 32, r0 = blockIdx.y * 32;
    int lx = threadIdx.x & 31, ly = threadIdx.x >> 5;
    #pragma unroll
    for (int i = 0; i < 4; i++)
        t[ly + i * 8][lx] = in[(size_t)(r0 + ly + i * 8) * ldi + coff + c0 + lx];
    __syncthreads();
    #pragma unroll
    for (int i = 0; i < 4; i++)
        out[(size_t)(c0 + ly + i * 8) * R + r0 + lx] = f2b(t[lx][ly + i * 8]);
}

// =============== both FFN weight casts in ONE launch (flattened grid) ===========
__global__ __launch_bounds__(256) void castffnw_k(const float* __restrict__ w1,
    const float* __restrict__ w2, u16* __restrict__ w1T, u16* __restrict__ w2T)
{
    __shared__ float t[32][33];
    int b = blockIdx.x;
    const float* in; u16* out; int ldi, R, c0, r0;
    if (b < 1024) {            // ffn_w1 [512][2048] -> w1T [2048][512]
        in = w1; out = w1T; ldi = 2048; R = 512;
        c0 = (b & 63) * 32; r0 = (b >> 6) * 32;
    } else {                   // ffn_w2 [2048][512] -> w2T [512][2048]
        b -= 1024;
        in = w2; out = w2T; ldi = 512; R = 2048;
        c0 = (b & 15) * 32; r0 = (b >> 4) * 32;
    }
    int lx = threadIdx.x & 31, ly = threadIdx.x >> 5;
    #pragma unroll
    for (int i = 0; i < 4; i++)
        t[ly + i * 8][lx] = in[(size_t)(r0 + ly + i * 8) * ldi + c0 + lx];
    __syncthreads();
    #pragma unroll
    for (int i = 0; i < 4; i++)
        out[(size_t)(c0 + ly + i * 8) * R + r0 + lx] = f2b(t[lx][ly + i * 8]);
}

// =============== qkv_w all 1536 cols: transpose + fp16 hi/lo concat ===============
__global__ __launch_bounds__(256) void castw_hl(const float* __restrict__ in,
    u16* __restrict__ out)
{
    __shared__ float t[32][33];
    int c0 = blockIdx.x * 32, r0 = blockIdx.y * 32;
    int lx = threadIdx.x & 31, ly = threadIdx.x >> 5;
    #pragma unroll
    for (int i = 0; i < 4; i++)
        t[ly + i * 8][lx] = in[(size_t)(r0 + ly + i * 8) * 1536 + c0 + lx];
    __syncthreads();
    #pragma unroll
    for (int i = 0; i < 4; i++) {
        float v = t[lx][ly + i * 8];
        u16 hb_ = f2h_bits(v);
        u16 lb_ = f2h_bits(v - h2f_bits(hb_));
        size_t ob = (size_t)(c0 + ly + i * 8) * 1024 + r0 + lx;
        out[ob] = hb_;
        out[ob + 512] = lb_;
    }
}

// =============== conv weight cast, coalesced ushort4 writes ===============
// out[co][t*512+ci] = bf16(cw[co][ci][t]); thread = (co, t, 4 consecutive ci)
__global__ void castconvw_k(const float* __restrict__ cw, u16* __restrict__ out)
{
    int g = blockIdx.x * 256 + threadIdx.x;
    if (g >= 3 * NC * NC / 4) return;           // 196608
    int co = g / 384;
    int rem = g - co * 384;
    int t = rem >> 7;
    int ci0 = (rem & 127) * 4;
    const float* src = cw + (size_t)co * 1536 + t;
    ushort4 o;
    o.x = f2b(src[(ci0 + 0) * 3]);
    o.y = f2b(src[(ci0 + 1) * 3]);
    o.z = f2b(src[(ci0 + 2) * 3]);
    o.w = f2b(src[(ci0 + 3) * 3]);
    *(ushort4*)&out[(size_t)co * 1536 + t * NC + ci0] = o;
}

// =============== x: fp32 [M][512] -> concat hi/lo fp16 [M][1024] ===============
__global__ void castx_k(const float* __restrict__ in, u16* __restrict__ xcat)
{
    int i = blockIdx.x * 256 + threadIdx.x;
    if (i >= (NB * NN * NC) / 4) return;
    int m = i >> 7, kq = i & 127;
    float4 v = ((const float4*)in)[i];
    ushort4 h, l;
    h.x = f2h_bits(v.x); h.y = f2h_bits(v.y);
    h.z = f2h_bits(v.z); h.w = f2h_bits(v.w);
    l.x = f2h_bits(v.x - h2f_bits(h.x));
    l.y = f2h_bits(v.y - h2f_bits(h.y));
    l.z = f2h_bits(v.z - h2f_bits(h.z));
    l.w = f2h_bits(v.w - h2f_bits(h.w));
    *(ushort4*)&xcat[(size_t)m * 1024 + kq * 4] = h;
    *(ushort4*)&xcat[(size_t)m * 1024 + 512 + kq * 4] = l;
}

// =============== V transpose -> Vtb bf16, + fused meanv partial sums ===============
__global__ __launch_bounds__(256) void castv_k(const float* __restrict__ Vh,
    u16* __restrict__ Vtb, float* __restrict__ pmean)
{
    int bh = blockIdx.y;
    int n0 = blockIdx.x * 64;
    __shared__ float vt[64][68];
    __shared__ float red[256];
    int tid = threadIdx.x;
    const float* vin = Vh + ((size_t)bh * NN + n0) * DK;
    #pragma unroll
    for (int i = 0; i < 4; i++) {
        int t = tid + i * 256;
        int n = t >> 4, dq = t & 15;
        float4 w = *(const float4*)&vin[(size_t)n * DK + dq * 4];
        vt[dq * 4 + 0][n] = w.x; vt[dq * 4 + 1][n] = w.y;
        vt[dq * 4 + 2][n] = w.z; vt[dq * 4 + 3][n] = w.w;
    }
    __syncthreads();
    #pragma unroll
    for (int i = 0; i < 4; i++) {
        int t = tid + i * 256;
        int d = t >> 4, nq = t & 15;
        float4 v = *(const float4*)&vt[d][nq * 4];
        ushort4 o;
        o.x = f2b(v.x); o.y = f2b(v.y); o.z = f2b(v.z); o.w = f2b(v.w);
        *(ushort4*)&Vtb[((size_t)bh * DK + d) * NN + n0 + nq * 4] = o;
    }
    int d = tid & 63, sub = tid >> 6;
    float s = 0.f;
    #pragma unroll
    for (int r = 0; r < 16; r++) s += vt[d][sub * 16 + r];
    red[tid] = s;
    __syncthreads();
    if (sub == 0)
        pmean[((size_t)bh * 32 + (n0 >> 6)) * 64 + d] =
            red[d] + red[64 + d] + red[128 + d] + red[192 + d];
}

// =============== rowstat via concat-fp16 MFMA; emits Marr and scaled rowmax ========
__global__ __launch_bounds__(256) void rowstat_mfma_k(const u16* __restrict__ Qcat,
    const u16* __restrict__ Kcat, float* __restrict__ Marr, float* __restrict__ rowmax)
{
    int bh = blockIdx.x;
    int m0 = blockIdx.y * 64;
    int tid = threadIdx.x;
    int wave = tid >> 6, lane = tid & 63;
    int ln = lane & 15, quad = lane >> 4;
    __shared__ u16 Ks[128][136];
    h8 qf[4];
    {
        const u16* qp = &Qcat[((size_t)bh * NN + m0 + wave * 16 + ln) * 128];
        #pragma unroll
        for (int ks = 0; ks < 4; ks++)
            qf[ks] = *(const h8*)&qp[ks * 32 + quad * 8];
    }
    f32x4 vmax, vsum;
    #pragma unroll
    for (int r = 0; r < 4; r++) { vmax[r] = -INFINITY; vsum[r] = 0.f; }
    const u16* kB = Kcat + (size_t)bh * NN * 128;
    for (int nc = 0; nc < NN; nc += 128) {
        __syncthreads();
        #pragma unroll
        for (int i = 0; i < 8; i++) {
            int e = tid + i * 256;
            int n = e >> 4, kq = e & 15;
            *(uint4*)&Ks[n][kq * 8] = *(const uint4*)&kB[(size_t)(nc + n) * 128 + kq * 8];
        }
        __syncthreads();
        f32x4 accS[8] = {};
        #pragma unroll
        for (int nt = 0; nt < 8; nt++) {
            #pragma unroll
            for (int ks = 0; ks < 4; ks++) {
                h8 kf = *(const h8*)&Ks[nt * 16 + ln][ks * 32 + quad * 8];
                accS[nt] = __builtin_amdgcn_mfma_f32_16x16x32_f16(
                    qf[ks], kf, accS[nt], 0, 0, 0);
            }
        }
        #pragma unroll
        for (int nt = 0; nt < 8; nt++)
            #pragma unroll
            for (int r = 0; r < 4; r++) {
                vmax[r] = fmaxf(vmax[r], accS[nt][r]);
                vsum[r] += accS[nt][r];
            }
    }
    #pragma unroll
    for (int r = 0; r < 4; r++) {
        float mx = vmax[r], sm = vsum[r];
        #pragma unroll
        for (int off = 1; off < 16; off <<= 1) {
            mx = fmaxf(mx, __shfl_xor(mx, off));
            sm += __shfl_xor(sm, off);
        }
        if (ln == 0) {
            int m = m0 + wave * 16 + quad * 4 + r;
            Marr[(size_t)bh * NN + m] = (mx - sm * (1.0f / (float)NN)) * 0.125f;
            rowmax[(size_t)bh * NN + m] = mx * 0.125f;
        }
    }
}

// =============== top-512 per (b,h) + fused meanv combine (first 64 lanes) =========
__global__ __launch_bounds__(256) void topk_k(const float* __restrict__ Marr,
    const float* __restrict__ pmean, float* __restrict__ meanv,
    int* __restrict__ idx)
{
    int bh = blockIdx.x;
    int tid = threadIdx.x;
    // fused meanv combine (independent of the select below; fill_k runs later)
    if (tid < 64) {
        float s = 0.f;
        #pragma unroll
        for (int c = 0; c < 32; c++) s += pmean[((size_t)bh * 32 + c) * 64 + tid];
        meanv[bh * DK + tid] = s * (1.0f / (float)NN);
    }
    const float* Mr = Marr + (size_t)bh * NN;
    int* idxr = idx + (size_t)bh * NTOP;
    __shared__ int hist[256];
    __shared__ int suf[256];
    __shared__ int wred[4], wred2[4];
    __shared__ int bin_sh, rank_sh;
    int lane = tid & 63, w = tid >> 6;
    unsigned prefix = 0;
    int rank = NTOP;
    for (int pass = 0; pass < 4; pass++) {
        int shift = 24 - pass * 8;
        unsigned mask_hi = (pass == 0) ? 0u : (0xFFFFFFFFu << (shift + 8));
        hist[tid] = 0;
        __syncthreads();
        for (int i = tid; i < NN; i += 256) {
            union { float f; unsigned u; } v; v.f = Mr[i];
            unsigned k = (v.u & 0x80000000u) ? ~v.u : (v.u | 0x80000000u);
            if ((k & mask_hi) == prefix)
                atomicAdd(&hist[(k >> shift) & 255], 1);
        }
        __syncthreads();
        int v = hist[tid];
        #pragma unroll
        for (int off = 1; off < 64; off <<= 1) {
            int t = __shfl_down(v, off);
            if (lane + off < 64) v += t;
        }
        if (lane == 0) wred[w] = v;
        __syncthreads();
        int add = 0;
        #pragma unroll
        for (int w2 = 0; w2 < 4; w2++) if (w2 > w) add += wred[w2];
        suf[tid] = v + add;
        __syncthreads();
        int sv = suf[tid];
        int nxt = (tid < 255) ? suf[tid + 1] : 0;
        if (sv >= rank && nxt < rank) { bin_sh = tid; rank_sh = rank - nxt; }
        __syncthreads();
        prefix |= ((unsigned)bin_sh << shift);
        rank = rank_sh;
        __syncthreads();
    }
    union { unsigned u; float f; } tv;
    tv.u = (prefix & 0x80000000u) ? (prefix & 0x7FFFFFFFu) : ~prefix;
    float thr = tv.f;
    int lg = 0, le = 0;
    #pragma unroll
    for (int k = 0; k < 8; k++) {
        float v = Mr[tid * 8 + k];
        lg += (v > thr) ? 1 : 0;
        le += (v == thr) ? 1 : 0;
    }
    int vg = lg, ve = le;
    #pragma unroll
    for (int off = 1; off < 64; off <<= 1) {
        int tg = __shfl_up(vg, off);
        int te = __shfl_up(ve, off);
        if (lane >= off) { vg += tg; ve += te; }
    }
    if (lane == 63) { wred[w] = vg; wred2[w] = ve; }
    __syncthreads();
    int addg = 0, adde = 0, totg = 0;
    #pragma unroll
    for (int w2 = 0; w2 < 4; w2++) {
        totg += wred[w2];
        if (w2 < w) { addg += wred[w2]; adde += wred2[w2]; }
    }
    int cnt_gt = totg;
    int needed = NTOP - cnt_gt;
    int gpre = (vg + addg) - lg, epre = (ve + adde) - le;
    #pragma unroll
    for (int k = 0; k < 8; k++) {
        int p = tid * 8 + k;
        float v = Mr[p];
        bool isgt = v > thr, iseq = v == thr;
        bool selv = isgt || (iseq && epre < needed);
        if (selv) idxr[gpre + (epre < needed ? epre : needed)] = p;
        gpre += isgt ? 1 : 0;
        epre += iseq ? 1 : 0;
    }
}

// =============== fill ctx (bf16) with uniform-attention result, ushort8 ===========
__global__ void fill_k(const float* __restrict__ meanv, u16* __restrict__ ctxb)
{
    int i = blockIdx.x * 256 + threadIdx.x;      // 8-elem groups
    if (i >= (NB * NN * NC) / 8) return;
    int c = (i * 8) & (NC - 1);
    int m = (i * 8) >> 9;
    int b = m >> 11;
    int h = c >> 6, d = c & 63;
    const float* mv = &meanv[(((b << 3) + h) << 6) + d];
    float4 v0 = *(const float4*)mv;
    float4 v1 = *(const float4*)(mv + 4);
    union { u16 s[8]; uint4 u; } r;
    r.s[0] = f2b(v0.x); r.s[1] = f2b(v0.y); r.s[2] = f2b(v0.z); r.s[3] = f2b(v0.w);
    r.s[4] = f2b(v1.x); r.s[5] = f2b(v1.y); r.s[6] = f2b(v1.z); r.s[7] = f2b(v1.w);
    *(uint4*)&ctxb[(size_t)i * 8] = r.u;
}

// =============== MFMA flash attention, precomputed rowmax, split-K ===============
__global__ __launch_bounds__(256) void attn_mfma_k(const u16* __restrict__ Qbs,
    const u16* __restrict__ Kb, const u16* __restrict__ Vtb,
    const int* __restrict__ idx, const float* __restrict__ rowmax,
    float* __restrict__ Opart, float* __restrict__ ml)
{
    int yy = blockIdx.x;
    int bh = yy >> 2, split = yy & (KSPLIT - 1);
    int t0 = blockIdx.y * 64;
    int tid = threadIdx.x;
    int wave = tid >> 6, lane = tid & 63;
    int ln = lane & 15, quad = lane >> 4;
    __shared__ u16 Ks[128][72];
    __shared__ u16 Vt[64][136];
    __shared__ u16 Ps[4][16][136];
    __shared__ int rows[64];
    if (tid < 64) rows[tid] = idx[bh * NTOP + t0 + tid];
    __syncthreads();
    frag8 qf[2];
    {
        const u16* qp = &Qbs[((size_t)bh * NN + rows[wave * 16 + ln]) * DK];
        qf[0] = *(const frag8*)&qp[quad * 8];
        qf[1] = *(const frag8*)&qp[32 + quad * 8];
    }
    float rm[4];
    #pragma unroll
    for (int r = 0; r < 4; r++)
        rm[r] = rowmax[(size_t)bh * NN + rows[wave * 16 + quad * 4 + r]];
    f32x4 accO[4] = {};
    float lrun[4] = {};
    const u16* kbB = Kb + (size_t)bh * NN * DK;
    const u16* vtB = Vtb + (size_t)bh * DK * NN;
    int nc0 = split * (NN / KSPLIT);
    for (int nc = nc0; nc < nc0 + NN / KSPLIT; nc += 128) {
        __syncthreads();
        #pragma unroll
        for (int i = 0; i < 4; i++) {
            int e = tid + i * 256;
            int n = e >> 3, kq = e & 7;
            *(uint4*)&Ks[n][kq * 8] = *(const uint4*)&kbB[(size_t)(nc + n) * DK + kq * 8];
        }
        #pragma unroll
        for (int i = 0; i < 4; i++) {
            int e = tid + i * 256;
            int d = e >> 4, nq = e & 15;
            *(uint4*)&Vt[d][nq * 8] = *(const uint4*)&vtB[(size_t)d * NN + nc + nq * 8];
        }
        __syncthreads();
        f32x4 accS[8] = {};
        #pragma unroll
        for (int nt = 0; nt < 8; nt++) {
            frag8 b0 = *(const frag8*)&Ks[nt * 16 + ln][quad * 8];
            frag8 b1 = *(const frag8*)&Ks[nt * 16 + ln][32 + quad * 8];
            accS[nt] = __builtin_amdgcn_mfma_f32_16x16x32_bf16(qf[0], b0, accS[nt], 0, 0, 0);
            accS[nt] = __builtin_amdgcn_mfma_f32_16x16x32_bf16(qf[1], b1, accS[nt], 0, 0, 0);
        }
        #pragma unroll
        for (int nt = 0; nt < 8; nt++)
            #pragma unroll
            for (int r = 0; r < 4; r++) {
                float p = expf(accS[nt][r] - rm[r]);
                accS[nt][r] = p;
                lrun[r] += p;
            }
        #pragma unroll
        for (int nt = 0; nt < 8; nt++)
            #pragma unroll
            for (int r = 0; r < 4; r++)
                Ps[wave][quad * 4 + r][nt * 16 + ln] = f2b(accS[nt][r]);
        #pragma unroll
        for (int ks = 0; ks < 4; ks++) {
            frag8 pf = *(const frag8*)&Ps[wave][ln][ks * 32 + quad * 8];
            #pragma unroll
            for (int nt2 = 0; nt2 < 4; nt2++) {
                frag8 vf = *(const frag8*)&Vt[nt2 * 16 + ln][ks * 32 + quad * 8];
                accO[nt2] = __builtin_amdgcn_mfma_f32_16x16x32_bf16(pf, vf, accO[nt2], 0, 0, 0);
            }
        }
    }
    #pragma unroll
    for (int r = 0; r < 4; r++) {
        float ls = lrun[r];
        #pragma unroll
        for (int off = 1; off < 16; off <<= 1) ls += __shfl_xor(ls, off);
        int p = t0 + wave * 16 + quad * 4 + r;
        size_t pb = ((size_t)bh * NTOP + p) * KSPLIT + split;
        #pragma unroll
        for (int nt2 = 0; nt2 < 4; nt2++)
            Opart[pb * 64 + nt2 * 16 + ln] = accO[nt2][r];
        if (ln == 0) ml[pb] = ls;
    }
}

// =============== combine split-K partials -> ctxb (bf16) ===============
__global__ __launch_bounds__(256) void attn_comb_k(const float* __restrict__ Opart,
    const float* __restrict__ ml, const int* __restrict__ idx,
    u16* __restrict__ ctxb)
{
    int gid = blockIdx.x * 4 + (threadIdx.x >> 6);
    int lane = threadIdx.x & 63;
    int bh = gid >> 9;
    int h = bh & 7, b = bh >> 3;
    size_t base = (size_t)gid * KSPLIT;
    float L = 0.f, O = 0.f;
    #pragma unroll
    for (int s = 0; s < KSPLIT; s++) {
        L += ml[base + s];
        O += Opart[(base + s) * 64 + lane];
    }
    int n = idx[gid];
    ctxb[((size_t)(b * NN + n)) * NC + h * DK + lane] = f2b(O / L);
}

// =============== layernorm of A + P0 + P1 + cb (float2-vectorized) ===============
__global__ __launch_bounds__(256) void ln_k(const float* __restrict__ A,
    const float* __restrict__ P0, const float* __restrict__ P1,
    const float* __restrict__ cb,
    const float* __restrict__ g, const float* __restrict__ bb,
    float* __restrict__ out, u16* __restrict__ outb)
{
    int row = blockIdx.x;
    int tid = threadIdx.x;
    __shared__ float v[NC];
    __shared__ float red[256];
    size_t base = (size_t)row * NC;
    float2 a  = *(const float2*)&A[base + tid * 2];
    float2 p0 = *(const float2*)&P0[base + tid * 2];
    float2 p1 = *(const float2*)&P1[base + tid * 2];
    float2 c2 = *(const float2*)&cb[tid * 2];
    float v0 = a.x + p0.x + p1.x + c2.x;
    float v1 = a.y + p0.y + p1.y + c2.y;
    v[tid * 2] = v0; v[tid * 2 + 1] = v1;
    red[tid] = v0 + v1;
    __syncthreads();
    for (int off = 128; off > 0; off >>= 1) {
        if (tid < off) red[tid] += red[tid + off];
        __syncthreads();
    }
    float mu = red[0] / (float)NC;
    __syncthreads();
    float d0 = v0 - mu, d1 = v1 - mu;
    red[tid] = d0 * d0 + d1 * d1;
    __syncthreads();
    for (int off = 128; off > 0; off >>= 1) {
        if (tid < off) red[tid] += red[tid + off];
        __syncthreads();
    }
    float rstd = rsqrtf(red[0] / (float)NC + 1e-5f);
    float2 g2 = *(const float2*)&g[tid * 2];
    float2 b2 = *(const float2*)&bb[tid * 2];
    float r0 = d0 * rstd * g2.x + b2.x;
    float r1 = d1 * rstd * g2.y + b2.y;
    if (out) { float2 o; o.x = r0; o.y = r1; *(float2*)&out[base + tid * 2] = o; }
    if (outb) {
        union { u16 s[2]; unsigned u; } w2;
        w2.s[0] = f2b(r0); w2.s[1] = f2b(r1);
        *(unsigned*)&outb[base + tid * 2] = w2.u;
    }
}

// =============== maxpool(3,2,1)+ELU+LN over conv partials (float2) ===============
__global__ __launch_bounds__(256) void pool_ln_k(const float* __restrict__ P0,
    const float* __restrict__ P1, const float* __restrict__ cb,
    const float* __restrict__ g, const float* __restrict__ bb,
    float* __restrict__ outp)
{
    int row = blockIdx.x;
    int j = row & (NPOOL - 1), b = row / NPOOL;
    int tid = threadIdx.x;
    __shared__ float red[256];
    size_t bbase = (size_t)b * NN * NC;
    float2 c2 = *(const float2*)&cb[tid * 2];
    float m0 = -INFINITY, m1 = -INFINITY;
    int p0r = 2 * j - 1;
    #pragma unroll
    for (int t = 0; t < 3; t++) {
        int p = p0r + t;
        if (p >= 0 && p < NN) {
            size_t off = bbase + (size_t)p * NC + tid * 2;
            float2 a = *(const float2*)&P0[off];
            float2 c = *(const float2*)&P1[off];
            m0 = fmaxf(m0, a.x + c.x + c2.x);
            m1 = fmaxf(m1, a.y + c.y + c2.y);
        }
    }
    float v0 = m0 > 0.f ? m0 : expm1f(m0);
    float v1 = m1 > 0.f ? m1 : expm1f(m1);
    red[tid] = v0 + v1;
    __syncthreads();
    for (int off = 128; off > 0; off >>= 1) {
        if (tid < off) red[tid] += red[tid + off];
        __syncthreads();
    }
    float mu = red[0] / (float)NC;
    __syncthreads();
    float d0 = v0 - mu, d1 = v1 - mu;
    red[tid] = d0 * d0 + d1 * d1;
    __syncthreads();
    for (int off = 128; off > 0; off >>= 1) {
        if (tid < off) red[tid] += red[tid + off];
        __syncthreads();
    }
    float rstd = rsqrtf(red[0] / (float)NC + 1e-5f);
    float2 g2 = *(const float2*)&g[tid * 2];
    float2 b2 = *(const float2*)&bb[tid * 2];
    float2 o;
    o.x = d0 * rstd * g2.x + b2.x;
    o.y = d1 * rstd * g2.y + b2.y;
    *(float2*)&outp[(size_t)row * NC + tid * 2] = o;
}

extern "C" void kernel_launch(void* const* d_in, const int* in_sizes, int n_in,
                              void* d_out, int out_size, void* d_ws, size_t ws_size,
                              hipStream_t stream)
{
    (void)in_sizes; (void)n_in; (void)out_size; (void)ws_size;
    const float* x      = (const float*)d_in[0];
    const float* qkv_w  = (const float*)d_in[1];
    const float* qkv_b  = (const float*)d_in[2];
    const float* out_w  = (const float*)d_in[3];
    const float* out_b  = (const float*)d_in[4];
    const float* ffn_w1 = (const float*)d_in[5];
    const float* ffn_b1 = (const float*)d_in[6];
    const float* ffn_w2 = (const float*)d_in[7];
    const float* ffn_b2 = (const float*)d_in[8];
    const float* n1_g   = (const float*)d_in[9];
    const float* n1_b   = (const float*)d_in[10];
    const float* n2_g   = (const float*)d_in[11];
    const float* n2_b   = (const float*)d_in[12];
    const float* conv_w = (const float*)d_in[13];
    const float* conv_b = (const float*)d_in[14];
    const float* cn_g   = (const float*)d_in[15];
    const float* cn_b   = (const float*)d_in[16];

    const size_t R = (size_t)NB * NN * NC;     // 2097152
    float* ws = (float*)d_ws;
    float* x1   = ws;                 // R : Kcat during rowstat; Opart
    float* reg2 = ws + R;             // R : xcat -> Vtb(2nd half) -> split-K P0
    float* QhR  = ws + 2 * R;         // R : Qbs + Kb (bf16, head-major)
    float* Kh   = ws + 3 * R;         // R : hb (FFN1 out)
    float* Vh   = ws + 4 * R;         // R : V fp32; split-K partial P1
    size_t o = 5 * R;
    float* pmax  = ws + o;  o += 65536;   // rowmax (scaled)
    float* psum  = ws + o;  o += 65536;   // (layout stability; unused)
    float* Marr  = ws + o;  o += 32768;
    float* pmean = ws + o;  o += 32768;
    float* meanv = ws + o;  o += 1024;
    int*   idx   = (int*)(ws + o);  o += 8192;
    float* ml    = ws + o;  o += 65536;
    u16*   ctxb  = (u16*)(ws + o);  o += R / 2;
    u16*   x1b   = (u16*)(ws + o);  o += R / 2;   // Qcat lower half
    u16*   x2b   = (u16*)(ws + o);  o += R / 2;   // Qcat upper half; LN2 out
    u16*   owT   = (u16*)(ws + o);  o += 131072;
    u16*   w1T   = (u16*)(ws + o);  o += 524288;  // wcatT(lo) early
    u16*   w2T   = (u16*)(ws + o);  o += 524288;  // wcatT(hi) early
    u16*   cwT   = (u16*)(ws + o);  o += 393216;
    u16*   Qbs   = (u16*)QhR;                       // [16][2048][64] bf16 pre-scaled
    u16*   Kb    = (u16*)(QhR + R / 2);             // [16][2048][64] bf16
    u16*   Vtb   = (u16*)(ws + R + R / 2);          // [16][64][2048] bf16
    float* Opart    = x1;
    u16*   hb       = (u16*)Kh;
    float* rowmax   = pmax;
    float* skP0 = reg2;
    float* skP1 = Vh;
    u16*   xcat  = (u16*)reg2;        // dead after mfma_qkv
    u16*   wcatT = w1T;               // [1536][1024] fp16 spans w1T+w2T
    u16*   Qcat  = x1b;               // (x1b+x2b)
    u16*   Kcat  = (u16*)x1;
    (void)psum;

    // early casts into regions not needed until later
    castw_t<<<dim3(16, 16), 256, 0, stream>>>(out_w, owT, 512, 512, 512, 0);
    castconvw_k<<<768, 256, 0, stream>>>(conv_w, cwT);
    castx_k<<<2048, 256, 0, stream>>>(x, xcat);
    castw_hl<<<dim3(48, 16), 256, 0, stream>>>(qkv_w, wcatT);

    // fused Q,K,V projection: emits Qbs/Kb bf16 + Qcat/Kcat fp16 + Vh fp32
    mfma_qkv<<<dim3(32, 12), 256, 0, stream>>>(xcat, wcatT, qkv_b,
                                               Qbs, Kb, Vh, Qcat, Kcat);

    // wcatT dead -> build both FFN weight transposes in one launch
    castffnw_k<<<2048, 256, 0, stream>>>(ffn_w1, ffn_w2, w1T, w2T);

    // V transpose -> Vtb + fused meanv partials
    castv_k<<<dim3(NN / 64, NB * NH), 256, 0, stream>>>(Vh, Vtb, pmean);

    // row max/mean of scores; emits Marr + rowmax
    rowstat_mfma_k<<<dim3(NB * NH, NN / 64), 256, 0, stream>>>(Qcat, Kcat, Marr, rowmax);
    // top-512 select (+ fused meanv combine)
    topk_k<<<NB * NH, 256, 0, stream>>>(Marr, pmean, meanv, idx);
    fill_k<<<(int)(R / 8 / 256), 256, 0, stream>>>(meanv, ctxb);
    attn_mfma_k<<<dim3(NB * NH * KSPLIT, NTOP / 64), 256, 0, stream>>>(
        Qbs, Kb, Vtb, idx, rowmax, Opart, ml);
    attn_comb_k<<<NB * NH * NTOP / 4, 256, 0, stream>>>(Opart, ml, idx, ctxb);

    // proj: split-K x2; partials combined in LN1
    mfma_gemm_sk<0><<<dim3(32, 4, 2), 256, 0, stream>>>(
        ctxb, NC, owT, skP0, skP1, NC, NC);

    // x1 = LN(x + proj_p0 + proj_p1 + out_b)
    ln_k<<<NB * NN, 256, 0, stream>>>(x, skP0, skP1, out_b, n1_g, n1_b, x1, x1b);

    // FFN1 (full-K); FFN2 split-K x2
    mfma_gemm<0><<<dim3(32, 16), 256, 0, stream>>>(
        x1b, NC, w1T, ffn_b1, (float*)nullptr, hb, DFF, NC, 1);
    mfma_gemm_sk<0><<<dim3(32, 4, 2), 256, 0, stream>>>(
        hb, DFF, w2T, skP0, skP1, NC, DFF);

    // x2 = LN(x1 + ffn2_p0 + ffn2_p1 + ffn_b2) -> bf16
    ln_k<<<NB * NN, 256, 0, stream>>>(x1, skP0, skP1, ffn_b2,
                                      n2_g, n2_b, (float*)nullptr, x2b);

    // fused circular conv1d(k=3): split-K x2 MFMA GEMM, K=1536
    mfma_gemm_sk<1><<<dim3(32, 4, 2), 256, 0, stream>>>(
        x2b, NC, cwT, skP0, skP1, NC, 1536);

    pool_ln_k<<<NB * NPOOL, 256, 0, stream>>>(skP0, skP1, conv_b, cn_g, cn_b,
                                              (float*)d_out);
}

// Round 11
// 314.501 us; speedup vs baseline: 1.9024x; 1.0189x over previous
//
#include <hip/hip_runtime.h>
#include <math.h>

#define NB 2
#define NN 2048
#define NC 512
#define NH 8
#define DK 64
#define DFF 2048
#define NTOP 512
#define NPOOL 1024
#define KSPLIT 4

typedef unsigned short u16;
typedef __attribute__((ext_vector_type(8))) short frag8;
typedef __attribute__((ext_vector_type(8))) _Float16 h8;
typedef __attribute__((ext_vector_type(4))) float f32x4;

static __device__ __forceinline__ u16 f2b(float f) {
    union { float f; unsigned int u; } v; v.f = f;
    unsigned int r = (v.u + 0x7fffu + ((v.u >> 16) & 1u)) >> 16;
    return (u16)r;
}
static __device__ __forceinline__ float b2f(u16 v) {
    union { unsigned u; float f; } x; x.u = ((unsigned)v) << 16; return x.f;
}
static __device__ __forceinline__ u16 f2h_bits(float f) {
    union { _Float16 h; u16 u; } v; v.h = (_Float16)f; return v.u;
}
static __device__ __forceinline__ float h2f_bits(u16 u) {
    union { u16 u; _Float16 h; } v; v.u = u; return (float)v.h;
}

// =============== bf16 MFMA GEMM (full-K): used for FFN1 (+gelu) ===============
template<int MODE>
__global__ __launch_bounds__(256) void mfma_gemm(const u16* __restrict__ A, int lda,
    const u16* __restrict__ Bt, const float* __restrict__ bias,
    float* __restrict__ C, u16* __restrict__ Cb, int ldc, int K, int act)
{
    __shared__ u16 As[128][72];
    __shared__ u16 Bs[128][72];
    int tid = threadIdx.x;
    int m0 = blockIdx.x * 128, n0 = blockIdx.y * 128;
    int wave = tid >> 6, lane = tid & 63;
    int ln = lane & 15, quad = lane >> 4;
    int wm = (wave >> 1) * 64, wn = (wave & 1) * 64;
    f32x4 acc[4][4] = {};
    for (int k0 = 0; k0 < K; k0 += 64) {
        #pragma unroll
        for (int i = 0; i < 4; i++) {
            int t = tid + i * 256;
            int m = t >> 3, kq = t & 7;
            size_t aoff;
            if (MODE == 1) {
                int grow = m0 + m;
                int shift = (k0 >> 9) - 1;
                int arow = (grow & ~(NN - 1)) | ((grow + shift) & (NN - 1));
                aoff = (size_t)arow * NC + ((k0 & 511) + kq * 8);
            } else {
                aoff = (size_t)(m0 + m) * lda + k0 + kq * 8;
            }
            *(uint4*)&As[m][kq * 8] = *(const uint4*)&A[aoff];
            *(uint4*)&Bs[m][kq * 8] = *(const uint4*)&Bt[(size_t)(n0 + m) * K + k0 + kq * 8];
        }
        __syncthreads();
        #pragma unroll
        for (int kk = 0; kk < 2; kk++) {
            frag8 af[4], bf[4];
            #pragma unroll
            for (int i = 0; i < 4; i++) {
                af[i] = *(const frag8*)&As[wm + i * 16 + ln][kk * 32 + quad * 8];
                bf[i] = *(const frag8*)&Bs[wn + i * 16 + ln][kk * 32 + quad * 8];
            }
            #pragma unroll
            for (int i = 0; i < 4; i++)
                #pragma unroll
                for (int j = 0; j < 4; j++)
                    acc[i][j] = __builtin_amdgcn_mfma_f32_16x16x32_bf16(
                        af[i], bf[j], acc[i][j], 0, 0, 0);
        }
        __syncthreads();
    }
    #pragma unroll
    for (int i = 0; i < 4; i++) {
        #pragma unroll
        for (int j = 0; j < 4; j++) {
            int col = n0 + wn + j * 16 + ln;
            float bv = bias ? bias[col] : 0.f;
            #pragma unroll
            for (int r = 0; r < 4; r++) {
                int row = m0 + wm + i * 16 + quad * 4 + r;
                float v = acc[i][j][r] + bv;
                if (act == 1) v = 0.5f * v * (1.0f + erff(v * 0.70710678118654752f));
                if (Cb) Cb[(size_t)row * ldc + col] = f2b(v);
                else    C[(size_t)row * ldc + col] = v;
            }
        }
    }
}

// =============== split-K x2 MFMA GEMM: fp32 partials, no bias/act ===============
template<int MODE>
__global__ __launch_bounds__(256) void mfma_gemm_sk(const u16* __restrict__ A, int lda,
    const u16* __restrict__ Bt, float* __restrict__ P0, float* __restrict__ P1,
    int ldc, int K)
{
    __shared__ u16 As[128][72];
    __shared__ u16 Bs[128][72];
    int tid = threadIdx.x;
    int m0 = blockIdx.x * 128, n0 = blockIdx.y * 128;
    int split = blockIdx.z;
    int K2 = K >> 1, kbeg = split * K2;
    int wave = tid >> 6, lane = tid & 63;
    int ln = lane & 15, quad = lane >> 4;
    int wm = (wave >> 1) * 64, wn = (wave & 1) * 64;
    f32x4 acc[4][4] = {};
    for (int k0 = kbeg; k0 < kbeg + K2; k0 += 64) {
        #pragma unroll
        for (int i = 0; i < 4; i++) {
            int t = tid + i * 256;
            int m = t >> 3, kq = t & 7;
            size_t aoff;
            if (MODE == 1) {
                int grow = m0 + m;
                int shift = (k0 >> 9) - 1;
                int arow = (grow & ~(NN - 1)) | ((grow + shift) & (NN - 1));
                aoff = (size_t)arow * NC + ((k0 & 511) + kq * 8);
            } else {
                aoff = (size_t)(m0 + m) * lda + k0 + kq * 8;
            }
            *(uint4*)&As[m][kq * 8] = *(const uint4*)&A[aoff];
            *(uint4*)&Bs[m][kq * 8] = *(const uint4*)&Bt[(size_t)(n0 + m) * K + k0 + kq * 8];
        }
        __syncthreads();
        #pragma unroll
        for (int kk = 0; kk < 2; kk++) {
            frag8 af[4], bf[4];
            #pragma unroll
            for (int i = 0; i < 4; i++) {
                af[i] = *(const frag8*)&As[wm + i * 16 + ln][kk * 32 + quad * 8];
                bf[i] = *(const frag8*)&Bs[wn + i * 16 + ln][kk * 32 + quad * 8];
            }
            #pragma unroll
            for (int i = 0; i < 4; i++)
                #pragma unroll
                for (int j = 0; j < 4; j++)
                    acc[i][j] = __builtin_amdgcn_mfma_f32_16x16x32_bf16(
                        af[i], bf[j], acc[i][j], 0, 0, 0);
        }
        __syncthreads();
    }
    float* P = split ? P1 : P0;
    #pragma unroll
    for (int i = 0; i < 4; i++) {
        #pragma unroll
        for (int j = 0; j < 4; j++) {
            int col = n0 + wn + j * 16 + ln;
            #pragma unroll
            for (int r = 0; r < 4; r++) {
                int row = m0 + wm + i * 16 + quad * 4 + r;
                P[(size_t)row * ldc + col] = acc[i][j][r];
            }
        }
    }
}

// =============== QKV projection: f16 concat-hi/lo MFMA GEMM (fp32-grade) =========
__global__ __launch_bounds__(256) void mfma_qkv(const u16* __restrict__ A,
    const u16* __restrict__ Bt, const float* __restrict__ bias,
    u16* __restrict__ Qbs, u16* __restrict__ Kb, float* __restrict__ Vh,
    u16* __restrict__ Qcat, u16* __restrict__ Kcat)
{
    __shared__ u16 As[128][72];
    __shared__ u16 Bs[128][72];
    int tid = threadIdx.x;
    int m0 = blockIdx.x * 128, n0 = blockIdx.y * 128;
    int wave = tid >> 6, lane = tid & 63;
    int ln = lane & 15, quad = lane >> 4;
    int wm = (wave >> 1) * 64, wn = (wave & 1) * 64;
    f32x4 acc[4][4] = {};
    for (int k0 = 0; k0 < 1024; k0 += 64) {
        #pragma unroll
        for (int i = 0; i < 4; i++) {
            int t = tid + i * 256;
            int m = t >> 3, kq = t & 7;
            *(uint4*)&As[m][kq * 8] = *(const uint4*)&A[(size_t)(m0 + m) * 1024 + k0 + kq * 8];
            *(uint4*)&Bs[m][kq * 8] = *(const uint4*)&Bt[(size_t)(n0 + m) * 1024 + k0 + kq * 8];
        }
        __syncthreads();
        #pragma unroll
        for (int kk = 0; kk < 2; kk++) {
            h8 af[4], bf[4];
            #pragma unroll
            for (int i = 0; i < 4; i++) {
                af[i] = *(const h8*)&As[wm + i * 16 + ln][kk * 32 + quad * 8];
                bf[i] = *(const h8*)&Bs[wn + i * 16 + ln][kk * 32 + quad * 8];
            }
            #pragma unroll
            for (int i = 0; i < 4; i++)
                #pragma unroll
                for (int j = 0; j < 4; j++)
                    acc[i][j] = __builtin_amdgcn_mfma_f32_16x16x32_f16(
                        af[i], bf[j], acc[i][j], 0, 0, 0);
        }
        __syncthreads();
    }
    #pragma unroll
    for (int i = 0; i < 4; i++) {
        #pragma unroll
        for (int j = 0; j < 4; j++) {
            int col = n0 + wn + j * 16 + ln;   // 0..1535 : [Q | K | V]
            float bv = bias[col];
            int which = col >> 9;
            int h = (col >> 6) & 7, d = col & 63;
            #pragma unroll
            for (int r = 0; r < 4; r++) {
                int row = m0 + wm + i * 16 + quad * 4 + r;
                int b = row >> 11, n = row & (NN - 1);
                float v = acc[i][j][r] + bv;
                size_t off32 = ((size_t)((b << 3) + h) * NN + n) * DK + d;
                if (which == 2) {
                    Vh[off32] = v;
                } else {
                    size_t offc = ((size_t)((b << 3) + h) * NN + n) * 128 + d;
                    u16 hb_ = f2h_bits(v);
                    u16 lb_ = f2h_bits(v - h2f_bits(hb_));
                    if (which == 0) {
                        Qbs[off32] = f2b(v * 0.125f);
                        Qcat[offc] = hb_; Qcat[offc + 64] = lb_;
                    } else {
                        Kb[off32] = f2b(v);
                        Kcat[offc] = hb_; Kcat[offc + 64] = lb_;
                    }
                }
            }
        }
    }
}

// =============== megacast: castx + castw_hl + castw_t(out_w) + castconvw ==========
// One launch; whole blocks take one role; outputs are disjoint.
__global__ __launch_bounds__(256) void megacast_k(const float* __restrict__ x,
    const float* __restrict__ qkv_w, const float* __restrict__ out_w,
    const float* __restrict__ cw,
    u16* __restrict__ xcat, u16* __restrict__ wcatT, u16* __restrict__ owT,
    u16* __restrict__ cwT)
{
    __shared__ float t[32][33];
    int b = blockIdx.x;
    int tid = threadIdx.x;
    if (b < 2048) {
        // castx: fp32 [M][512] -> concat hi/lo fp16 [M][1024]
        int i = b * 256 + tid;
        int m = i >> 7, kq = i & 127;
        float4 v = ((const float4*)x)[i];
        ushort4 h, l;
        h.x = f2h_bits(v.x); h.y = f2h_bits(v.y);
        h.z = f2h_bits(v.z); h.w = f2h_bits(v.w);
        l.x = f2h_bits(v.x - h2f_bits(h.x));
        l.y = f2h_bits(v.y - h2f_bits(h.y));
        l.z = f2h_bits(v.z - h2f_bits(h.z));
        l.w = f2h_bits(v.w - h2f_bits(h.w));
        *(ushort4*)&xcat[(size_t)m * 1024 + kq * 4] = h;
        *(ushort4*)&xcat[(size_t)m * 1024 + 512 + kq * 4] = l;
    } else if (b < 2816) {
        // castw_hl: qkv_w all 1536 cols -> [1536][1024] fp16 hi/lo
        int lb = b - 2048;
        int c0 = (lb % 48) * 32, r0 = (lb / 48) * 32;
        int lx = tid & 31, ly = tid >> 5;
        #pragma unroll
        for (int i = 0; i < 4; i++)
            t[ly + i * 8][lx] = qkv_w[(size_t)(r0 + ly + i * 8) * 1536 + c0 + lx];
        __syncthreads();
        #pragma unroll
        for (int i = 0; i < 4; i++) {
            float v = t[lx][ly + i * 8];
            u16 hb_ = f2h_bits(v);
            u16 lb_ = f2h_bits(v - h2f_bits(hb_));
            size_t ob = (size_t)(c0 + ly + i * 8) * 1024 + r0 + lx;
            wcatT[ob] = hb_;
            wcatT[ob + 512] = lb_;
        }
    } else if (b < 3072) {
        // castw_t(out_w): [512][512] -> owT [512][512] bf16
        int lb = b - 2816;
        int c0 = (lb % 16) * 32, r0 = (lb / 16) * 32;
        int lx = tid & 31, ly = tid >> 5;
        #pragma unroll
        for (int i = 0; i < 4; i++)
            t[ly + i * 8][lx] = out_w[(size_t)(r0 + ly + i * 8) * 512 + c0 + lx];
        __syncthreads();
        #pragma unroll
        for (int i = 0; i < 4; i++)
            owT[(size_t)(c0 + ly + i * 8) * 512 + r0 + lx] = f2b(t[lx][ly + i * 8]);
    } else {
        // castconvw: out[co][t*512+ci] = bf16(cw[co][ci][t]), ushort4 stores
        int g = (b - 3072) * 256 + tid;
        int co = g / 384;
        int rem = g - co * 384;
        int tt = rem >> 7;
        int ci0 = (rem & 127) * 4;
        const float* src = cw + (size_t)co * 1536 + tt;
        ushort4 o;
        o.x = f2b(src[(ci0 + 0) * 3]);
        o.y = f2b(src[(ci0 + 1) * 3]);
        o.z = f2b(src[(ci0 + 2) * 3]);
        o.w = f2b(src[(ci0 + 3) * 3]);
        *(ushort4*)&cwT[(size_t)co * 1536 + tt * NC + ci0] = o;
    }
}

// =============== post-QKV merge: both FFN weight casts + castv (+meanv part) ======
__global__ __launch_bounds__(256) void castffnv_k(const float* __restrict__ w1,
    const float* __restrict__ w2, u16* __restrict__ w1T, u16* __restrict__ w2T,
    const float* __restrict__ Vh, u16* __restrict__ Vtb, float* __restrict__ pmean)
{
    __shared__ float t[32][33];
    __shared__ float vt[64][68];
    __shared__ float red[256];
    int b = blockIdx.x;
    int tid = threadIdx.x;
    if (b < 2048) {
        const float* in; u16* out; int ldi, R, c0, r0;
        if (b < 1024) {            // ffn_w1 [512][2048] -> w1T [2048][512]
            in = w1; out = w1T; ldi = 2048; R = 512;
            c0 = (b & 63) * 32; r0 = (b >> 6) * 32;
        } else {                   // ffn_w2 [2048][512] -> w2T [512][2048]
            int lb = b - 1024;
            in = w2; out = w2T; ldi = 512; R = 2048;
            c0 = (lb & 15) * 32; r0 = (lb >> 4) * 32;
        }
        int lx = tid & 31, ly = tid >> 5;
        #pragma unroll
        for (int i = 0; i < 4; i++)
            t[ly + i * 8][lx] = in[(size_t)(r0 + ly + i * 8) * ldi + c0 + lx];
        __syncthreads();
        #pragma unroll
        for (int i = 0; i < 4; i++)
            out[(size_t)(c0 + ly + i * 8) * R + r0 + lx] = f2b(t[lx][ly + i * 8]);
    } else {
        // castv: V transpose -> Vtb bf16 + fused meanv partial sums
        int lb = b - 2048;
        int n0 = (lb & 31) * 64;
        int bh = lb >> 5;
        const float* vin = Vh + ((size_t)bh * NN + n0) * DK;
        #pragma unroll
        for (int i = 0; i < 4; i++) {
            int e = tid + i * 256;
            int n = e >> 4, dq = e & 15;
            float4 w = *(const float4*)&vin[(size_t)n * DK + dq * 4];
            vt[dq * 4 + 0][n] = w.x; vt[dq * 4 + 1][n] = w.y;
            vt[dq * 4 + 2][n] = w.z; vt[dq * 4 + 3][n] = w.w;
        }
        __syncthreads();
        #pragma unroll
        for (int i = 0; i < 4; i++) {
            int e = tid + i * 256;
            int d = e >> 4, nq = e & 15;
            float4 v = *(const float4*)&vt[d][nq * 4];
            ushort4 o;
            o.x = f2b(v.x); o.y = f2b(v.y); o.z = f2b(v.z); o.w = f2b(v.w);
            *(ushort4*)&Vtb[((size_t)bh * DK + d) * NN + n0 + nq * 4] = o;
        }
        int d = tid & 63, sub = tid >> 6;
        float s = 0.f;
        #pragma unroll
        for (int r = 0; r < 16; r++) s += vt[d][sub * 16 + r];
        red[tid] = s;
        __syncthreads();
        if (sub == 0)
            pmean[((size_t)bh * 32 + (n0 >> 6)) * 64 + d] =
                red[d] + red[64 + d] + red[128 + d] + red[192 + d];
    }
}

// =============== rowstat via concat-fp16 MFMA; emits Marr and scaled rowmax ========
__global__ __launch_bounds__(256) void rowstat_mfma_k(const u16* __restrict__ Qcat,
    const u16* __restrict__ Kcat, float* __restrict__ Marr, float* __restrict__ rowmax)
{
    int bh = blockIdx.x;
    int m0 = blockIdx.y * 64;
    int tid = threadIdx.x;
    int wave = tid >> 6, lane = tid & 63;
    int ln = lane & 15, quad = lane >> 4;
    __shared__ u16 Ks[128][136];
    h8 qf[4];
    {
        const u16* qp = &Qcat[((size_t)bh * NN + m0 + wave * 16 + ln) * 128];
        #pragma unroll
        for (int ks = 0; ks < 4; ks++)
            qf[ks] = *(const h8*)&qp[ks * 32 + quad * 8];
    }
    f32x4 vmax, vsum;
    #pragma unroll
    for (int r = 0; r < 4; r++) { vmax[r] = -INFINITY; vsum[r] = 0.f; }
    const u16* kB = Kcat + (size_t)bh * NN * 128;
    for (int nc = 0; nc < NN; nc += 128) {
        __syncthreads();
        #pragma unroll
        for (int i = 0; i < 8; i++) {
            int e = tid + i * 256;
            int n = e >> 4, kq = e & 15;
            *(uint4*)&Ks[n][kq * 8] = *(const uint4*)&kB[(size_t)(nc + n) * 128 + kq * 8];
        }
        __syncthreads();
        f32x4 accS[8] = {};
        #pragma unroll
        for (int nt = 0; nt < 8; nt++) {
            #pragma unroll
            for (int ks = 0; ks < 4; ks++) {
                h8 kf = *(const h8*)&Ks[nt * 16 + ln][ks * 32 + quad * 8];
                accS[nt] = __builtin_amdgcn_mfma_f32_16x16x32_f16(
                    qf[ks], kf, accS[nt], 0, 0, 0);
            }
        }
        #pragma unroll
        for (int nt = 0; nt < 8; nt++)
            #pragma unroll
            for (int r = 0; r < 4; r++) {
                vmax[r] = fmaxf(vmax[r], accS[nt][r]);
                vsum[r] += accS[nt][r];
            }
    }
    #pragma unroll
    for (int r = 0; r < 4; r++) {
        float mx = vmax[r], sm = vsum[r];
        #pragma unroll
        for (int off = 1; off < 16; off <<= 1) {
            mx = fmaxf(mx, __shfl_xor(mx, off));
            sm += __shfl_xor(sm, off);
        }
        if (ln == 0) {
            int m = m0 + wave * 16 + quad * 4 + r;
            Marr[(size_t)bh * NN + m] = (mx - sm * (1.0f / (float)NN)) * 0.125f;
            rowmax[(size_t)bh * NN + m] = mx * 0.125f;
        }
    }
}

// =============== top-512 per (b,h) + fused meanv combine (first 64 lanes) =========
__global__ __launch_bounds__(256) void topk_k(const float* __restrict__ Marr,
    const float* __restrict__ pmean, float* __restrict__ meanv,
    int* __restrict__ idx)
{
    int bh = blockIdx.x;
    int tid = threadIdx.x;
    if (tid < 64) {
        float s = 0.f;
        #pragma unroll
        for (int c = 0; c < 32; c++) s += pmean[((size_t)bh * 32 + c) * 64 + tid];
        meanv[bh * DK + tid] = s * (1.0f / (float)NN);
    }
    const float* Mr = Marr + (size_t)bh * NN;
    int* idxr = idx + (size_t)bh * NTOP;
    __shared__ int hist[256];
    __shared__ int suf[256];
    __shared__ int wred[4], wred2[4];
    __shared__ int bin_sh, rank_sh;
    int lane = tid & 63, w = tid >> 6;
    unsigned prefix = 0;
    int rank = NTOP;
    for (int pass = 0; pass < 4; pass++) {
        int shift = 24 - pass * 8;
        unsigned mask_hi = (pass == 0) ? 0u : (0xFFFFFFFFu << (shift + 8));
        hist[tid] = 0;
        __syncthreads();
        for (int i = tid; i < NN; i += 256) {
            union { float f; unsigned u; } v; v.f = Mr[i];
            unsigned k = (v.u & 0x80000000u) ? ~v.u : (v.u | 0x80000000u);
            if ((k & mask_hi) == prefix)
                atomicAdd(&hist[(k >> shift) & 255], 1);
        }
        __syncthreads();
        int v = hist[tid];
        #pragma unroll
        for (int off = 1; off < 64; off <<= 1) {
            int t = __shfl_down(v, off);
            if (lane + off < 64) v += t;
        }
        if (lane == 0) wred[w] = v;
        __syncthreads();
        int add = 0;
        #pragma unroll
        for (int w2 = 0; w2 < 4; w2++) if (w2 > w) add += wred[w2];
        suf[tid] = v + add;
        __syncthreads();
        int sv = suf[tid];
        int nxt = (tid < 255) ? suf[tid + 1] : 0;
        if (sv >= rank && nxt < rank) { bin_sh = tid; rank_sh = rank - nxt; }
        __syncthreads();
        prefix |= ((unsigned)bin_sh << shift);
        rank = rank_sh;
        __syncthreads();
    }
    union { unsigned u; float f; } tv;
    tv.u = (prefix & 0x80000000u) ? (prefix & 0x7FFFFFFFu) : ~prefix;
    float thr = tv.f;
    int lg = 0, le = 0;
    #pragma unroll
    for (int k = 0; k < 8; k++) {
        float v = Mr[tid * 8 + k];
        lg += (v > thr) ? 1 : 0;
        le += (v == thr) ? 1 : 0;
    }
    int vg = lg, ve = le;
    #pragma unroll
    for (int off = 1; off < 64; off <<= 1) {
        int tg = __shfl_up(vg, off);
        int te = __shfl_up(ve, off);
        if (lane >= off) { vg += tg; ve += te; }
    }
    if (lane == 63) { wred[w] = vg; wred2[w] = ve; }
    __syncthreads();
    int addg = 0, adde = 0, totg = 0;
    #pragma unroll
    for (int w2 = 0; w2 < 4; w2++) {
        totg += wred[w2];
        if (w2 < w) { addg += wred[w2]; adde += wred2[w2]; }
    }
    int cnt_gt = totg;
    int needed = NTOP - cnt_gt;
    int gpre = (vg + addg) - lg, epre = (ve + adde) - le;
    #pragma unroll
    for (int k = 0; k < 8; k++) {
        int p = tid * 8 + k;
        float v = Mr[p];
        bool isgt = v > thr, iseq = v == thr;
        bool selv = isgt || (iseq && epre < needed);
        if (selv) idxr[gpre + (epre < needed ? epre : needed)] = p;
        gpre += isgt ? 1 : 0;
        epre += iseq ? 1 : 0;
    }
}

// =============== fill ctx (bf16) with uniform-attention result, ushort8 ===========
__global__ void fill_k(const float* __restrict__ meanv, u16* __restrict__ ctxb)
{
    int i = blockIdx.x * 256 + threadIdx.x;      // 8-elem groups
    if (i >= (NB * NN * NC) / 8) return;
    int c = (i * 8) & (NC - 1);
    int m = (i * 8) >> 9;
    int b = m >> 11;
    int h = c >> 6, d = c & 63;
    const float* mv = &meanv[(((b << 3) + h) << 6) + d];
    float4 v0 = *(const float4*)mv;
    float4 v1 = *(const float4*)(mv + 4);
    union { u16 s[8]; uint4 u; } r;
    r.s[0] = f2b(v0.x); r.s[1] = f2b(v0.y); r.s[2] = f2b(v0.z); r.s[3] = f2b(v0.w);
    r.s[4] = f2b(v1.x); r.s[5] = f2b(v1.y); r.s[6] = f2b(v1.z); r.s[7] = f2b(v1.w);
    *(uint4*)&ctxb[(size_t)i * 8] = r.u;
}

// =============== MFMA flash attention, precomputed rowmax, split-K ===============
__global__ __launch_bounds__(256) void attn_mfma_k(const u16* __restrict__ Qbs,
    const u16* __restrict__ Kb, const u16* __restrict__ Vtb,
    const int* __restrict__ idx, const float* __restrict__ rowmax,
    float* __restrict__ Opart, float* __restrict__ ml)
{
    int yy = blockIdx.x;
    int bh = yy >> 2, split = yy & (KSPLIT - 1);
    int t0 = blockIdx.y * 64;
    int tid = threadIdx.x;
    int wave = tid >> 6, lane = tid & 63;
    int ln = lane & 15, quad = lane >> 4;
    __shared__ u16 Ks[128][72];
    __shared__ u16 Vt[64][136];
    __shared__ u16 Ps[4][16][136];
    __shared__ int rows[64];
    if (tid < 64) rows[tid] = idx[bh * NTOP + t0 + tid];
    __syncthreads();
    frag8 qf[2];
    {
        const u16* qp = &Qbs[((size_t)bh * NN + rows[wave * 16 + ln]) * DK];
        qf[0] = *(const frag8*)&qp[quad * 8];
        qf[1] = *(const frag8*)&qp[32 + quad * 8];
    }
    float rm[4];
    #pragma unroll
    for (int r = 0; r < 4; r++)
        rm[r] = rowmax[(size_t)bh * NN + rows[wave * 16 + quad * 4 + r]];
    f32x4 accO[4] = {};
    float lrun[4] = {};
    const u16* kbB = Kb + (size_t)bh * NN * DK;
    const u16* vtB = Vtb + (size_t)bh * DK * NN;
    int nc0 = split * (NN / KSPLIT);
    for (int nc = nc0; nc < nc0 + NN / KSPLIT; nc += 128) {
        __syncthreads();
        #pragma unroll
        for (int i = 0; i < 4; i++) {
            int e = tid + i * 256;
            int n = e >> 3, kq = e & 7;
            *(uint4*)&Ks[n][kq * 8] = *(const uint4*)&kbB[(size_t)(nc + n) * DK + kq * 8];
        }
        #pragma unroll
        for (int i = 0; i < 4; i++) {
            int e = tid + i * 256;
            int d = e >> 4, nq = e & 15;
            *(uint4*)&Vt[d][nq * 8] = *(const uint4*)&vtB[(size_t)d * NN + nc + nq * 8];
        }
        __syncthreads();
        f32x4 accS[8] = {};
        #pragma unroll
        for (int nt = 0; nt < 8; nt++) {
            frag8 b0 = *(const frag8*)&Ks[nt * 16 + ln][quad * 8];
            frag8 b1 = *(const frag8*)&Ks[nt * 16 + ln][32 + quad * 8];
            accS[nt] = __builtin_amdgcn_mfma_f32_16x16x32_bf16(qf[0], b0, accS[nt], 0, 0, 0);
            accS[nt] = __builtin_amdgcn_mfma_f32_16x16x32_bf16(qf[1], b1, accS[nt], 0, 0, 0);
        }
        #pragma unroll
        for (int nt = 0; nt < 8; nt++)
            #pragma unroll
            for (int r = 0; r < 4; r++) {
                float p = expf(accS[nt][r] - rm[r]);
                accS[nt][r] = p;
                lrun[r] += p;
            }
        #pragma unroll
        for (int nt = 0; nt < 8; nt++)
            #pragma unroll
            for (int r = 0; r < 4; r++)
                Ps[wave][quad * 4 + r][nt * 16 + ln] = f2b(accS[nt][r]);
        #pragma unroll
        for (int ks = 0; ks < 4; ks++) {
            frag8 pf = *(const frag8*)&Ps[wave][ln][ks * 32 + quad * 8];
            #pragma unroll
            for (int nt2 = 0; nt2 < 4; nt2++) {
                frag8 vf = *(const frag8*)&Vt[nt2 * 16 + ln][ks * 32 + quad * 8];
                accO[nt2] = __builtin_amdgcn_mfma_f32_16x16x32_bf16(pf, vf, accO[nt2], 0, 0, 0);
            }
        }
    }
    #pragma unroll
    for (int r = 0; r < 4; r++) {
        float ls = lrun[r];
        #pragma unroll
        for (int off = 1; off < 16; off <<= 1) ls += __shfl_xor(ls, off);
        int p = t0 + wave * 16 + quad * 4 + r;
        size_t pb = ((size_t)bh * NTOP + p) * KSPLIT + split;
        #pragma unroll
        for (int nt2 = 0; nt2 < 4; nt2++)
            Opart[pb * 64 + nt2 * 16 + ln] = accO[nt2][r];
        if (ln == 0) ml[pb] = ls;
    }
}

// =============== combine split-K partials -> ctxb (bf16) ===============
__global__ __launch_bounds__(256) void attn_comb_k(const float* __restrict__ Opart,
    const float* __restrict__ ml, const int* __restrict__ idx,
    u16* __restrict__ ctxb)
{
    int gid = blockIdx.x * 4 + (threadIdx.x >> 6);
    int lane = threadIdx.x & 63;
    int bh = gid >> 9;
    int h = bh & 7, b = bh >> 3;
    size_t base = (size_t)gid * KSPLIT;
    float L = 0.f, O = 0.f;
    #pragma unroll
    for (int s = 0; s < KSPLIT; s++) {
        L += ml[base + s];
        O += Opart[(base + s) * 64 + lane];
    }
    int n = idx[gid];
    ctxb[((size_t)(b * NN + n)) * NC + h * DK + lane] = f2b(O / L);
}

// =============== layernorm of A + P0 + P1 + cb (float2-vectorized) ===============
__global__ __launch_bounds__(256) void ln_k(const float* __restrict__ A,
    const float* __restrict__ P0, const float* __restrict__ P1,
    const float* __restrict__ cb,
    const float* __restrict__ g, const float* __restrict__ bb,
    float* __restrict__ out, u16* __restrict__ outb)
{
    int row = blockIdx.x;
    int tid = threadIdx.x;
    __shared__ float red[256];
    size_t base = (size_t)row * NC;
    float2 a  = *(const float2*)&A[base + tid * 2];
    float2 p0 = *(const float2*)&P0[base + tid * 2];
    float2 p1 = *(const float2*)&P1[base + tid * 2];
    float2 c2 = *(const float2*)&cb[tid * 2];
    float v0 = a.x + p0.x + p1.x + c2.x;
    float v1 = a.y + p0.y + p1.y + c2.y;
    red[tid] = v0 + v1;
    __syncthreads();
    for (int off = 128; off > 0; off >>= 1) {
        if (tid < off) red[tid] += red[tid + off];
        __syncthreads();
    }
    float mu = red[0] / (float)NC;
    __syncthreads();
    float d0 = v0 - mu, d1 = v1 - mu;
    red[tid] = d0 * d0 + d1 * d1;
    __syncthreads();
    for (int off = 128; off > 0; off >>= 1) {
        if (tid < off) red[tid] += red[tid + off];
        __syncthreads();
    }
    float rstd = rsqrtf(red[0] / (float)NC + 1e-5f);
    float2 g2 = *(const float2*)&g[tid * 2];
    float2 b2 = *(const float2*)&bb[tid * 2];
    float r0 = d0 * rstd * g2.x + b2.x;
    float r1 = d1 * rstd * g2.y + b2.y;
    if (out) { float2 o; o.x = r0; o.y = r1; *(float2*)&out[base + tid * 2] = o; }
    if (outb) {
        union { u16 s[2]; unsigned u; } w2;
        w2.s[0] = f2b(r0); w2.s[1] = f2b(r1);
        *(unsigned*)&outb[base + tid * 2] = w2.u;
    }
}

// =============== maxpool(3,2,1)+ELU+LN over conv partials (float2) ===============
__global__ __launch_bounds__(256) void pool_ln_k(const float* __restrict__ P0,
    const float* __restrict__ P1, const float* __restrict__ cb,
    const float* __restrict__ g, const float* __restrict__ bb,
    float* __restrict__ outp)
{
    int row = blockIdx.x;
    int j = row & (NPOOL - 1), b = row / NPOOL;
    int tid = threadIdx.x;
    __shared__ float red[256];
    size_t bbase = (size_t)b * NN * NC;
    float2 c2 = *(const float2*)&cb[tid * 2];
    float m0 = -INFINITY, m1 = -INFINITY;
    int p0r = 2 * j - 1;
    #pragma unroll
    for (int t = 0; t < 3; t++) {
        int p = p0r + t;
        if (p >= 0 && p < NN) {
            size_t off = bbase + (size_t)p * NC + tid * 2;
            float2 a = *(const float2*)&P0[off];
            float2 c = *(const float2*)&P1[off];
            m0 = fmaxf(m0, a.x + c.x + c2.x);
            m1 = fmaxf(m1, a.y + c.y + c2.y);
        }
    }
    float v0 = m0 > 0.f ? m0 : expm1f(m0);
    float v1 = m1 > 0.f ? m1 : expm1f(m1);
    red[tid] = v0 + v1;
    __syncthreads();
    for (int off = 128; off > 0; off >>= 1) {
        if (tid < off) red[tid] += red[tid + off];
        __syncthreads();
    }
    float mu = red[0] / (float)NC;
    __syncthreads();
    float d0 = v0 - mu, d1 = v1 - mu;
    red[tid] = d0 * d0 + d1 * d1;
    __syncthreads();
    for (int off = 128; off > 0; off >>= 1) {
        if (tid < off) red[tid] += red[tid + off];
        __syncthreads();
    }
    float rstd = rsqrtf(red[0] / (float)NC + 1e-5f);
    float2 g2 = *(const float2*)&g[tid * 2];
    float2 b2 = *(const float2*)&bb[tid * 2];
    float2 o;
    o.x = d0 * rstd * g2.x + b2.x;
    o.y = d1 * rstd * g2.y + b2.y;
    *(float2*)&outp[(size_t)row * NC + tid * 2] = o;
}

extern "C" void kernel_launch(void* const* d_in, const int* in_sizes, int n_in,
                              void* d_out, int out_size, void* d_ws, size_t ws_size,
                              hipStream_t stream)
{
    (void)in_sizes; (void)n_in; (void)out_size; (void)ws_size;
    const float* x      = (const float*)d_in[0];
    const float* qkv_w  = (const float*)d_in[1];
    const float* qkv_b  = (const float*)d_in[2];
    const float* out_w  = (const float*)d_in[3];
    const float* out_b  = (const float*)d_in[4];
    const float* ffn_w1 = (const float*)d_in[5];
    const float* ffn_b1 = (const float*)d_in[6];
    const float* ffn_w2 = (const float*)d_in[7];
    const float* ffn_b2 = (const float*)d_in[8];
    const float* n1_g   = (const float*)d_in[9];
    const float* n1_b   = (const float*)d_in[10];
    const float* n2_g   = (const float*)d_in[11];
    const float* n2_b   = (const float*)d_in[12];
    const float* conv_w = (const float*)d_in[13];
    const float* conv_b = (const float*)d_in[14];
    const float* cn_g   = (const float*)d_in[15];
    const float* cn_b   = (const float*)d_in[16];

    const size_t R = (size_t)NB * NN * NC;     // 2097152
    float* ws = (float*)d_ws;
    float* x1   = ws;                 // R : Kcat during rowstat; Opart
    float* reg2 = ws + R;             // R : xcat -> Vtb(2nd half) -> split-K P0
    float* QhR  = ws + 2 * R;         // R : Qbs + Kb (bf16, head-major)
    float* Kh   = ws + 3 * R;         // R : hb (FFN1 out)
    float* Vh   = ws + 4 * R;         // R : V fp32; split-K partial P1
    size_t o = 5 * R;
    float* pmax  = ws + o;  o += 65536;   // rowmax (scaled)
    float* psum  = ws + o;  o += 65536;   // (layout stability; unused)
    float* Marr  = ws + o;  o += 32768;
    float* pmean = ws + o;  o += 32768;
    float* meanv = ws + o;  o += 1024;
    int*   idx   = (int*)(ws + o);  o += 8192;
    float* ml    = ws + o;  o += 65536;
    u16*   ctxb  = (u16*)(ws + o);  o += R / 2;
    u16*   x1b   = (u16*)(ws + o);  o += R / 2;   // Qcat lower half
    u16*   x2b   = (u16*)(ws + o);  o += R / 2;   // Qcat upper half; LN2 out
    u16*   owT   = (u16*)(ws + o);  o += 131072;
    u16*   w1T   = (u16*)(ws + o);  o += 524288;  // wcatT(lo) early
    u16*   w2T   = (u16*)(ws + o);  o += 524288;  // wcatT(hi) early
    u16*   cwT   = (u16*)(ws + o);  o += 393216;
    u16*   Qbs   = (u16*)QhR;                       // [16][2048][64] bf16 pre-scaled
    u16*   Kb    = (u16*)(QhR + R / 2);             // [16][2048][64] bf16
    u16*   Vtb   = (u16*)(ws + R + R / 2);          // [16][64][2048] bf16
    float* Opart    = x1;
    u16*   hb       = (u16*)Kh;
    float* rowmax   = pmax;
    float* skP0 = reg2;
    float* skP1 = Vh;
    u16*   xcat  = (u16*)reg2;        // dead after mfma_qkv
    u16*   wcatT = w1T;               // [1536][1024] fp16 spans w1T+w2T
    u16*   Qcat  = x1b;               // (x1b+x2b)
    u16*   Kcat  = (u16*)x1;
    (void)psum;

    // all input casts in ONE launch (castx + castw_hl + castw_t(ow) + castconvw)
    megacast_k<<<3840, 256, 0, stream>>>(x, qkv_w, out_w, conv_w,
                                         xcat, wcatT, owT, cwT);

    // fused Q,K,V projection: emits Qbs/Kb bf16 + Qcat/Kcat fp16 + Vh fp32
    mfma_qkv<<<dim3(32, 12), 256, 0, stream>>>(xcat, wcatT, qkv_b,
                                               Qbs, Kb, Vh, Qcat, Kcat);

    // FFN weight transposes + V transpose/meanv partials in ONE launch
    castffnv_k<<<2560, 256, 0, stream>>>(ffn_w1, ffn_w2, w1T, w2T, Vh, Vtb, pmean);

    // row max/mean of scores; emits Marr + rowmax
    rowstat_mfma_k<<<dim3(NB * NH, NN / 64), 256, 0, stream>>>(Qcat, Kcat, Marr, rowmax);
    // top-512 select (+ fused meanv combine)
    topk_k<<<NB * NH, 256, 0, stream>>>(Marr, pmean, meanv, idx);
    fill_k<<<(int)(R / 8 / 256), 256, 0, stream>>>(meanv, ctxb);
    attn_mfma_k<<<dim3(NB * NH * KSPLIT, NTOP / 64), 256, 0, stream>>>(
        Qbs, Kb, Vtb, idx, rowmax, Opart, ml);
    attn_comb_k<<<NB * NH * NTOP / 4, 256, 0, stream>>>(Opart, ml, idx, ctxb);

    // proj: split-K x2; partials combined in LN1
    mfma_gemm_sk<0><<<dim3(32, 4, 2), 256, 0, stream>>>(
        ctxb, NC, owT, skP0, skP1, NC, NC);

    // x1 = LN(x + proj_p0 + proj_p1 + out_b)
    ln_k<<<NB * NN, 256, 0, stream>>>(x, skP0, skP1, out_b, n1_g, n1_b, x1, x1b);

    // FFN1 (full-K); FFN2 split-K x2
    mfma_gemm<0><<<dim3(32, 16), 256, 0, stream>>>(
        x1b, NC, w1T, ffn_b1, (float*)nullptr, hb, DFF, NC, 1);
    mfma_gemm_sk<0><<<dim3(32, 4, 2), 256, 0, stream>>>(
        hb, DFF, w2T, skP0, skP1, NC, DFF);

    // x2 = LN(x1 + ffn2_p0 + ffn2_p1 + ffn_b2) -> bf16
    ln_k<<<NB * NN, 256, 0, stream>>>(x1, skP0, skP1, ffn_b2,
                                      n2_g, n2_b, (float*)nullptr, x2b);

    // fused circular conv1d(k=3): split-K x2 MFMA GEMM, K=1536
    mfma_gemm_sk<1><<<dim3(32, 4, 2), 256, 0, stream>>>(
        x2b, NC, cwT, skP0, skP1, NC, 1536);

    pool_ln_k<<<NB * NPOOL, 256, 0, stream>>>(skP0, skP1, conv_b, cn_g, cn_b,
                                              (float*)d_out);
}

// Round 12
// 303.831 us; speedup vs baseline: 1.9692x; 1.0351x over previous
//
#include <hip/hip_runtime.h>
#include <math.h>

#define NB 2
#define NN 2048
#define NC 512
#define NH 8
#define DK 64
#define DFF 2048
#define NTOP 512
#define NPOOL 1024
#define KSPLIT 4

typedef unsigned short u16;
typedef __attribute__((ext_vector_type(8))) short frag8;
typedef __attribute__((ext_vector_type(8))) _Float16 h8;
typedef __attribute__((ext_vector_type(4))) float f32x4;

static __device__ __forceinline__ u16 f2b(float f) {
    union { float f; unsigned int u; } v; v.f = f;
    unsigned int r = (v.u + 0x7fffu + ((v.u >> 16) & 1u)) >> 16;
    return (u16)r;
}
static __device__ __forceinline__ float b2f(u16 v) {
    union { unsigned u; float f; } x; x.u = ((unsigned)v) << 16; return x.f;
}
static __device__ __forceinline__ u16 f2h_bits(float f) {
    union { _Float16 h; u16 u; } v; v.h = (_Float16)f; return v.u;
}
static __device__ __forceinline__ float h2f_bits(u16 u) {
    union { u16 u; _Float16 h; } v; v.u = u; return (float)v.h;
}

// =============== bf16 MFMA GEMM (full-K): used for FFN1 (+gelu) ===============
template<int MODE>
__global__ __launch_bounds__(256) void mfma_gemm(const u16* __restrict__ A, int lda,
    const u16* __restrict__ Bt, const float* __restrict__ bias,
    float* __restrict__ C, u16* __restrict__ Cb, int ldc, int K, int act)
{
    __shared__ u16 As[128][72];
    __shared__ u16 Bs[128][72];
    int tid = threadIdx.x;
    int m0 = blockIdx.x * 128, n0 = blockIdx.y * 128;
    int wave = tid >> 6, lane = tid & 63;
    int ln = lane & 15, quad = lane >> 4;
    int wm = (wave >> 1) * 64, wn = (wave & 1) * 64;
    f32x4 acc[4][4] = {};
    for (int k0 = 0; k0 < K; k0 += 64) {
        #pragma unroll
        for (int i = 0; i < 4; i++) {
            int t = tid + i * 256;
            int m = t >> 3, kq = t & 7;
            size_t aoff;
            if (MODE == 1) {
                int grow = m0 + m;
                int shift = (k0 >> 9) - 1;
                int arow = (grow & ~(NN - 1)) | ((grow + shift) & (NN - 1));
                aoff = (size_t)arow * NC + ((k0 & 511) + kq * 8);
            } else {
                aoff = (size_t)(m0 + m) * lda + k0 + kq * 8;
            }
            *(uint4*)&As[m][kq * 8] = *(const uint4*)&A[aoff];
            *(uint4*)&Bs[m][kq * 8] = *(const uint4*)&Bt[(size_t)(n0 + m) * K + k0 + kq * 8];
        }
        __syncthreads();
        #pragma unroll
        for (int kk = 0; kk < 2; kk++) {
            frag8 af[4], bf[4];
            #pragma unroll
            for (int i = 0; i < 4; i++) {
                af[i] = *(const frag8*)&As[wm + i * 16 + ln][kk * 32 + quad * 8];
                bf[i] = *(const frag8*)&Bs[wn + i * 16 + ln][kk * 32 + quad * 8];
            }
            #pragma unroll
            for (int i = 0; i < 4; i++)
                #pragma unroll
                for (int j = 0; j < 4; j++)
                    acc[i][j] = __builtin_amdgcn_mfma_f32_16x16x32_bf16(
                        af[i], bf[j], acc[i][j], 0, 0, 0);
        }
        __syncthreads();
    }
    #pragma unroll
    for (int i = 0; i < 4; i++) {
        #pragma unroll
        for (int j = 0; j < 4; j++) {
            int col = n0 + wn + j * 16 + ln;
            float bv = bias ? bias[col] : 0.f;
            #pragma unroll
            for (int r = 0; r < 4; r++) {
                int row = m0 + wm + i * 16 + quad * 4 + r;
                float v = acc[i][j][r] + bv;
                if (act == 1) v = 0.5f * v * (1.0f + erff(v * 0.70710678118654752f));
                if (Cb) Cb[(size_t)row * ldc + col] = f2b(v);
                else    C[(size_t)row * ldc + col] = v;
            }
        }
    }
}

// =============== split-K x2 MFMA GEMM: fp32 partials, no bias/act ===============
template<int MODE>
__global__ __launch_bounds__(256) void mfma_gemm_sk(const u16* __restrict__ A, int lda,
    const u16* __restrict__ Bt, float* __restrict__ P0, float* __restrict__ P1,
    int ldc, int K)
{
    __shared__ u16 As[128][72];
    __shared__ u16 Bs[128][72];
    int tid = threadIdx.x;
    int m0 = blockIdx.x * 128, n0 = blockIdx.y * 128;
    int split = blockIdx.z;
    int K2 = K >> 1, kbeg = split * K2;
    int wave = tid >> 6, lane = tid & 63;
    int ln = lane & 15, quad = lane >> 4;
    int wm = (wave >> 1) * 64, wn = (wave & 1) * 64;
    f32x4 acc[4][4] = {};
    for (int k0 = kbeg; k0 < kbeg + K2; k0 += 64) {
        #pragma unroll
        for (int i = 0; i < 4; i++) {
            int t = tid + i * 256;
            int m = t >> 3, kq = t & 7;
            size_t aoff;
            if (MODE == 1) {
                int grow = m0 + m;
                int shift = (k0 >> 9) - 1;
                int arow = (grow & ~(NN - 1)) | ((grow + shift) & (NN - 1));
                aoff = (size_t)arow * NC + ((k0 & 511) + kq * 8);
            } else {
                aoff = (size_t)(m0 + m) * lda + k0 + kq * 8;
            }
            *(uint4*)&As[m][kq * 8] = *(const uint4*)&A[aoff];
            *(uint4*)&Bs[m][kq * 8] = *(const uint4*)&Bt[(size_t)(n0 + m) * K + k0 + kq * 8];
        }
        __syncthreads();
        #pragma unroll
        for (int kk = 0; kk < 2; kk++) {
            frag8 af[4], bf[4];
            #pragma unroll
            for (int i = 0; i < 4; i++) {
                af[i] = *(const frag8*)&As[wm + i * 16 + ln][kk * 32 + quad * 8];
                bf[i] = *(const frag8*)&Bs[wn + i * 16 + ln][kk * 32 + quad * 8];
            }
            #pragma unroll
            for (int i = 0; i < 4; i++)
                #pragma unroll
                for (int j = 0; j < 4; j++)
                    acc[i][j] = __builtin_amdgcn_mfma_f32_16x16x32_bf16(
                        af[i], bf[j], acc[i][j], 0, 0, 0);
        }
        __syncthreads();
    }
    float* P = split ? P1 : P0;
    #pragma unroll
    for (int i = 0; i < 4; i++) {
        #pragma unroll
        for (int j = 0; j < 4; j++) {
            int col = n0 + wn + j * 16 + ln;
            #pragma unroll
            for (int r = 0; r < 4; r++) {
                int row = m0 + wm + i * 16 + quad * 4 + r;
                P[(size_t)row * ldc + col] = acc[i][j][r];
            }
        }
    }
}

// =============== QKV projection: f16 concat-hi/lo MFMA GEMM (fp32-grade) =========
__global__ __launch_bounds__(256) void mfma_qkv(const u16* __restrict__ A,
    const u16* __restrict__ Bt, const float* __restrict__ bias,
    u16* __restrict__ Qbs, u16* __restrict__ Kb, float* __restrict__ Vh,
    u16* __restrict__ Qcat, u16* __restrict__ Kcat)
{
    __shared__ u16 As[128][72];
    __shared__ u16 Bs[128][72];
    int tid = threadIdx.x;
    int m0 = blockIdx.x * 128, n0 = blockIdx.y * 128;
    int wave = tid >> 6, lane = tid & 63;
    int ln = lane & 15, quad = lane >> 4;
    int wm = (wave >> 1) * 64, wn = (wave & 1) * 64;
    f32x4 acc[4][4] = {};
    for (int k0 = 0; k0 < 1024; k0 += 64) {
        #pragma unroll
        for (int i = 0; i < 4; i++) {
            int t = tid + i * 256;
            int m = t >> 3, kq = t & 7;
            *(uint4*)&As[m][kq * 8] = *(const uint4*)&A[(size_t)(m0 + m) * 1024 + k0 + kq * 8];
            *(uint4*)&Bs[m][kq * 8] = *(const uint4*)&Bt[(size_t)(n0 + m) * 1024 + k0 + kq * 8];
        }
        __syncthreads();
        #pragma unroll
        for (int kk = 0; kk < 2; kk++) {
            h8 af[4], bf[4];
            #pragma unroll
            for (int i = 0; i < 4; i++) {
                af[i] = *(const h8*)&As[wm + i * 16 + ln][kk * 32 + quad * 8];
                bf[i] = *(const h8*)&Bs[wn + i * 16 + ln][kk * 32 + quad * 8];
            }
            #pragma unroll
            for (int i = 0; i < 4; i++)
                #pragma unroll
                for (int j = 0; j < 4; j++)
                    acc[i][j] = __builtin_amdgcn_mfma_f32_16x16x32_f16(
                        af[i], bf[j], acc[i][j], 0, 0, 0);
        }
        __syncthreads();
    }
    #pragma unroll
    for (int i = 0; i < 4; i++) {
        #pragma unroll
        for (int j = 0; j < 4; j++) {
            int col = n0 + wn + j * 16 + ln;   // 0..1535 : [Q | K | V]
            float bv = bias[col];
            int which = col >> 9;
            int h = (col >> 6) & 7, d = col & 63;
            #pragma unroll
            for (int r = 0; r < 4; r++) {
                int row = m0 + wm + i * 16 + quad * 4 + r;
                int b = row >> 11, n = row & (NN - 1);
                float v = acc[i][j][r] + bv;
                size_t off32 = ((size_t)((b << 3) + h) * NN + n) * DK + d;
                if (which == 2) {
                    Vh[off32] = v;
                } else {
                    size_t offc = ((size_t)((b << 3) + h) * NN + n) * 128 + d;
                    u16 hb_ = f2h_bits(v);
                    u16 lb_ = f2h_bits(v - h2f_bits(hb_));
                    if (which == 0) {
                        Qbs[off32] = f2b(v * 0.125f);
                        Qcat[offc] = hb_; Qcat[offc + 64] = lb_;
                    } else {
                        Kb[off32] = f2b(v);
                        Kcat[offc] = hb_; Kcat[offc + 64] = lb_;
                    }
                }
            }
        }
    }
}

// =============== megacast: castx + castw_hl + castw_t(out_w) + castconvw ==========
__global__ __launch_bounds__(256) void megacast_k(const float* __restrict__ x,
    const float* __restrict__ qkv_w, const float* __restrict__ out_w,
    const float* __restrict__ cw,
    u16* __restrict__ xcat, u16* __restrict__ wcatT, u16* __restrict__ owT,
    u16* __restrict__ cwT)
{
    __shared__ float t[32][33];
    int b = blockIdx.x;
    int tid = threadIdx.x;
    if (b < 2048) {
        int i = b * 256 + tid;
        int m = i >> 7, kq = i & 127;
        float4 v = ((const float4*)x)[i];
        ushort4 h, l;
        h.x = f2h_bits(v.x); h.y = f2h_bits(v.y);
        h.z = f2h_bits(v.z); h.w = f2h_bits(v.w);
        l.x = f2h_bits(v.x - h2f_bits(h.x));
        l.y = f2h_bits(v.y - h2f_bits(h.y));
        l.z = f2h_bits(v.z - h2f_bits(h.z));
        l.w = f2h_bits(v.w - h2f_bits(h.w));
        *(ushort4*)&xcat[(size_t)m * 1024 + kq * 4] = h;
        *(ushort4*)&xcat[(size_t)m * 1024 + 512 + kq * 4] = l;
    } else if (b < 2816) {
        int lb = b - 2048;
        int c0 = (lb % 48) * 32, r0 = (lb / 48) * 32;
        int lx = tid & 31, ly = tid >> 5;
        #pragma unroll
        for (int i = 0; i < 4; i++)
            t[ly + i * 8][lx] = qkv_w[(size_t)(r0 + ly + i * 8) * 1536 + c0 + lx];
        __syncthreads();
        #pragma unroll
        for (int i = 0; i < 4; i++) {
            float v = t[lx][ly + i * 8];
            u16 hb_ = f2h_bits(v);
            u16 lb_ = f2h_bits(v - h2f_bits(hb_));
            size_t ob = (size_t)(c0 + ly + i * 8) * 1024 + r0 + lx;
            wcatT[ob] = hb_;
            wcatT[ob + 512] = lb_;
        }
    } else if (b < 3072) {
        int lb = b - 2816;
        int c0 = (lb % 16) * 32, r0 = (lb / 16) * 32;
        int lx = tid & 31, ly = tid >> 5;
        #pragma unroll
        for (int i = 0; i < 4; i++)
            t[ly + i * 8][lx] = out_w[(size_t)(r0 + ly + i * 8) * 512 + c0 + lx];
        __syncthreads();
        #pragma unroll
        for (int i = 0; i < 4; i++)
            owT[(size_t)(c0 + ly + i * 8) * 512 + r0 + lx] = f2b(t[lx][ly + i * 8]);
    } else {
        int g = (b - 3072) * 256 + tid;
        int co = g / 384;
        int rem = g - co * 384;
        int tt = rem >> 7;
        int ci0 = (rem & 127) * 4;
        const float* src = cw + (size_t)co * 1536 + tt;
        ushort4 o;
        o.x = f2b(src[(ci0 + 0) * 3]);
        o.y = f2b(src[(ci0 + 1) * 3]);
        o.z = f2b(src[(ci0 + 2) * 3]);
        o.w = f2b(src[(ci0 + 3) * 3]);
        *(ushort4*)&cwT[(size_t)co * 1536 + tt * NC + ci0] = o;
    }
}

// ===== castrow: rowstat MFMA (first, long pole) + FFN weight casts + castv =======
// Shared-memory arena: max over roles (rowstat Ks = 34816 B), not the sum.
// Role bases are multiples of 8 and internal strides preserved -> XCD mapping
// and arithmetic of every role are bit-identical to the separate kernels.
__global__ __launch_bounds__(256) void castrow_k(
    const u16* __restrict__ Qcat, const u16* __restrict__ Kcat,
    float* __restrict__ Marr, float* __restrict__ rowmax,
    const float* __restrict__ w1, const float* __restrict__ w2,
    u16* __restrict__ w1T, u16* __restrict__ w2T,
    const float* __restrict__ Vh, u16* __restrict__ Vtb, float* __restrict__ pmean)
{
    __shared__ __align__(16) char smem[34816];
    int b = blockIdx.x;
    int tid = threadIdx.x;
    if (b < 512) {
        // ---- rowstat role: bh = b & 15 (stride-16 co-XCD per head) ----
        u16 (*Ks)[136] = (u16(*)[136])smem;
        int bh = b & 15;
        int m0 = (b >> 4) * 64;
        int wave = tid >> 6, lane = tid & 63;
        int ln = lane & 15, quad = lane >> 4;
        h8 qf[4];
        {
            const u16* qp = &Qcat[((size_t)bh * NN + m0 + wave * 16 + ln) * 128];
            #pragma unroll
            for (int ks = 0; ks < 4; ks++)
                qf[ks] = *(const h8*)&qp[ks * 32 + quad * 8];
        }
        f32x4 vmax, vsum;
        #pragma unroll
        for (int r = 0; r < 4; r++) { vmax[r] = -INFINITY; vsum[r] = 0.f; }
        const u16* kB = Kcat + (size_t)bh * NN * 128;
        for (int nc = 0; nc < NN; nc += 128) {
            __syncthreads();
            #pragma unroll
            for (int i = 0; i < 8; i++) {
                int e = tid + i * 256;
                int n = e >> 4, kq = e & 15;
                *(uint4*)&Ks[n][kq * 8] = *(const uint4*)&kB[(size_t)(nc + n) * 128 + kq * 8];
            }
            __syncthreads();
            f32x4 accS[8] = {};
            #pragma unroll
            for (int nt = 0; nt < 8; nt++) {
                #pragma unroll
                for (int ks = 0; ks < 4; ks++) {
                    h8 kf = *(const h8*)&Ks[nt * 16 + ln][ks * 32 + quad * 8];
                    accS[nt] = __builtin_amdgcn_mfma_f32_16x16x32_f16(
                        qf[ks], kf, accS[nt], 0, 0, 0);
                }
            }
            #pragma unroll
            for (int nt = 0; nt < 8; nt++)
                #pragma unroll
                for (int r = 0; r < 4; r++) {
                    vmax[r] = fmaxf(vmax[r], accS[nt][r]);
                    vsum[r] += accS[nt][r];
                }
        }
        #pragma unroll
        for (int r = 0; r < 4; r++) {
            float mx = vmax[r], sm = vsum[r];
            #pragma unroll
            for (int off = 1; off < 16; off <<= 1) {
                mx = fmaxf(mx, __shfl_xor(mx, off));
                sm += __shfl_xor(sm, off);
            }
            if (ln == 0) {
                int m = m0 + wave * 16 + quad * 4 + r;
                Marr[(size_t)bh * NN + m] = (mx - sm * (1.0f / (float)NN)) * 0.125f;
                rowmax[(size_t)bh * NN + m] = mx * 0.125f;
            }
        }
    } else if (b < 2560) {
        // ---- FFN weight transpose roles ----
        float (*t)[33] = (float(*)[33])smem;
        int lb = b - 512;
        const float* in; u16* out; int ldi, R, c0, r0;
        if (lb < 1024) {           // ffn_w1 [512][2048] -> w1T [2048][512]
            in = w1; out = w1T; ldi = 2048; R = 512;
            c0 = (lb & 63) * 32; r0 = (lb >> 6) * 32;
        } else {                   // ffn_w2 [2048][512] -> w2T [512][2048]
            int l2 = lb - 1024;
            in = w2; out = w2T; ldi = 512; R = 2048;
            c0 = (l2 & 15) * 32; r0 = (l2 >> 4) * 32;
        }
        int lx = tid & 31, ly = tid >> 5;
        #pragma unroll
        for (int i = 0; i < 4; i++)
            t[ly + i * 8][lx] = in[(size_t)(r0 + ly + i * 8) * ldi + c0 + lx];
        __syncthreads();
        #pragma unroll
        for (int i = 0; i < 4; i++)
            out[(size_t)(c0 + ly + i * 8) * R + r0 + lx] = f2b(t[lx][ly + i * 8]);
    } else {
        // ---- castv role: V transpose -> Vtb bf16 + meanv partials ----
        float (*vt)[68] = (float(*)[68])smem;
        float* red = (float*)(smem + 64 * 68 * 4);
        int lb = b - 2560;
        int n0 = (lb & 31) * 64;
        int bh = lb >> 5;
        const float* vin = Vh + ((size_t)bh * NN + n0) * DK;
        #pragma unroll
        for (int i = 0; i < 4; i++) {
            int e = tid + i * 256;
            int n = e >> 4, dq = e & 15;
            float4 w = *(const float4*)&vin[(size_t)n * DK + dq * 4];
            vt[dq * 4 + 0][n] = w.x; vt[dq * 4 + 1][n] = w.y;
            vt[dq * 4 + 2][n] = w.z; vt[dq * 4 + 3][n] = w.w;
        }
        __syncthreads();
        #pragma unroll
        for (int i = 0; i < 4; i++) {
            int e = tid + i * 256;
            int d = e >> 4, nq = e & 15;
            float4 v = *(const float4*)&vt[d][nq * 4];
            ushort4 o;
            o.x = f2b(v.x); o.y = f2b(v.y); o.z = f2b(v.z); o.w = f2b(v.w);
            *(ushort4*)&Vtb[((size_t)bh * DK + d) * NN + n0 + nq * 4] = o;
        }
        int d = tid & 63, sub = tid >> 6;
        float s = 0.f;
        #pragma unroll
        for (int r = 0; r < 16; r++) s += vt[d][sub * 16 + r];
        red[tid] = s;
        __syncthreads();
        if (sub == 0)
            pmean[((size_t)bh * 32 + (n0 >> 6)) * 64 + d] =
                red[d] + red[64 + d] + red[128 + d] + red[192 + d];
    }
}

// =============== top-512 per (b,h) + fused meanv combine (first 64 lanes) =========
__global__ __launch_bounds__(256) void topk_k(const float* __restrict__ Marr,
    const float* __restrict__ pmean, float* __restrict__ meanv,
    int* __restrict__ idx)
{
    int bh = blockIdx.x;
    int tid = threadIdx.x;
    if (tid < 64) {
        float s = 0.f;
        #pragma unroll
        for (int c = 0; c < 32; c++) s += pmean[((size_t)bh * 32 + c) * 64 + tid];
        meanv[bh * DK + tid] = s * (1.0f / (float)NN);
    }
    const float* Mr = Marr + (size_t)bh * NN;
    int* idxr = idx + (size_t)bh * NTOP;
    __shared__ int hist[256];
    __shared__ int suf[256];
    __shared__ int wred[4], wred2[4];
    __shared__ int bin_sh, rank_sh;
    int lane = tid & 63, w = tid >> 6;
    unsigned prefix = 0;
    int rank = NTOP;
    for (int pass = 0; pass < 4; pass++) {
        int shift = 24 - pass * 8;
        unsigned mask_hi = (pass == 0) ? 0u : (0xFFFFFFFFu << (shift + 8));
        hist[tid] = 0;
        __syncthreads();
        for (int i = tid; i < NN; i += 256) {
            union { float f; unsigned u; } v; v.f = Mr[i];
            unsigned k = (v.u & 0x80000000u) ? ~v.u : (v.u | 0x80000000u);
            if ((k & mask_hi) == prefix)
                atomicAdd(&hist[(k >> shift) & 255], 1);
        }
        __syncthreads();
        int v = hist[tid];
        #pragma unroll
        for (int off = 1; off < 64; off <<= 1) {
            int t = __shfl_down(v, off);
            if (lane + off < 64) v += t;
        }
        if (lane == 0) wred[w] = v;
        __syncthreads();
        int add = 0;
        #pragma unroll
        for (int w2 = 0; w2 < 4; w2++) if (w2 > w) add += wred[w2];
        suf[tid] = v + add;
        __syncthreads();
        int sv = suf[tid];
        int nxt = (tid < 255) ? suf[tid + 1] : 0;
        if (sv >= rank && nxt < rank) { bin_sh = tid; rank_sh = rank - nxt; }
        __syncthreads();
        prefix |= ((unsigned)bin_sh << shift);
        rank = rank_sh;
        __syncthreads();
    }
    union { unsigned u; float f; } tv;
    tv.u = (prefix & 0x80000000u) ? (prefix & 0x7FFFFFFFu) : ~prefix;
    float thr = tv.f;
    int lg = 0, le = 0;
    #pragma unroll
    for (int k = 0; k < 8; k++) {
        float v = Mr[tid * 8 + k];
        lg += (v > thr) ? 1 : 0;
        le += (v == thr) ? 1 : 0;
    }
    int vg = lg, ve = le;
    #pragma unroll
    for (int off = 1; off < 64; off <<= 1) {
        int tg = __shfl_up(vg, off);
        int te = __shfl_up(ve, off);
        if (lane >= off) { vg += tg; ve += te; }
    }
    if (lane == 63) { wred[w] = vg; wred2[w] = ve; }
    __syncthreads();
    int addg = 0, adde = 0, totg = 0;
    #pragma unroll
    for (int w2 = 0; w2 < 4; w2++) {
        totg += wred[w2];
        if (w2 < w) { addg += wred[w2]; adde += wred2[w2]; }
    }
    int cnt_gt = totg;
    int needed = NTOP - cnt_gt;
    int gpre = (vg + addg) - lg, epre = (ve + adde) - le;
    #pragma unroll
    for (int k = 0; k < 8; k++) {
        int p = tid * 8 + k;
        float v = Mr[p];
        bool isgt = v > thr, iseq = v == thr;
        bool selv = isgt || (iseq && epre < needed);
        if (selv) idxr[gpre + (epre < needed ? epre : needed)] = p;
        gpre += isgt ? 1 : 0;
        epre += iseq ? 1 : 0;
    }
}

// ====== attn+fill fused: MFMA flash attention (first) + uniform-ctx fill =========
// Both depend only on topk's outputs; disjoint writes (Opart/ml vs ctxb);
// attn_comb (which overwrites selected ctxb rows) still runs strictly after.
__global__ __launch_bounds__(256) void attnfill_k(const u16* __restrict__ Qbs,
    const u16* __restrict__ Kb, const u16* __restrict__ Vtb,
    const int* __restrict__ idx, const float* __restrict__ rowmax,
    const float* __restrict__ meanv,
    float* __restrict__ Opart, float* __restrict__ ml, u16* __restrict__ ctxb)
{
    __shared__ u16 Ks[128][72];
    __shared__ u16 Vt[64][136];
    __shared__ u16 Ps[4][16][136];
    __shared__ int rows[64];
    int blk = blockIdx.x;
    int tid = threadIdx.x;
    if (blk >= 512) {
        // ---- fill role: ushort8 uniform-attention ctx ----
        int i = (blk - 512) * 256 + tid;
        int c = (i * 8) & (NC - 1);
        int m = (i * 8) >> 9;
        int b = m >> 11;
        int h = c >> 6, d = c & 63;
        const float* mv = &meanv[(((b << 3) + h) << 6) + d];
        float4 v0 = *(const float4*)mv;
        float4 v1 = *(const float4*)(mv + 4);
        union { u16 s[8]; uint4 u; } r;
        r.s[0] = f2b(v0.x); r.s[1] = f2b(v0.y); r.s[2] = f2b(v0.z); r.s[3] = f2b(v0.w);
        r.s[4] = f2b(v1.x); r.s[5] = f2b(v1.y); r.s[6] = f2b(v1.z); r.s[7] = f2b(v1.w);
        *(uint4*)&ctxb[(size_t)i * 8] = r.u;
        return;
    }
    // ---- attn role: yy = blk & 63 (stride-64 co-XCD per (bh,split)) ----
    int yy = blk & 63;
    int bh = yy >> 2, split = yy & (KSPLIT - 1);
    int t0 = (blk >> 6) * 64;
    int wave = tid >> 6, lane = tid & 63;
    int ln = lane & 15, quad = lane >> 4;
    if (tid < 64) rows[tid] = idx[bh * NTOP + t0 + tid];
    __syncthreads();
    frag8 qf[2];
    {
        const u16* qp = &Qbs[((size_t)bh * NN + rows[wave * 16 + ln]) * DK];
        qf[0] = *(const frag8*)&qp[quad * 8];
        qf[1] = *(const frag8*)&qp[32 + quad * 8];
    }
    float rm[4];
    #pragma unroll
    for (int r = 0; r < 4; r++)
        rm[r] = rowmax[(size_t)bh * NN + rows[wave * 16 + quad * 4 + r]];
    f32x4 accO[4] = {};
    float lrun[4] = {};
    const u16* kbB = Kb + (size_t)bh * NN * DK;
    const u16* vtB = Vtb + (size_t)bh * DK * NN;
    int nc0 = split * (NN / KSPLIT);
    for (int nc = nc0; nc < nc0 + NN / KSPLIT; nc += 128) {
        __syncthreads();
        #pragma unroll
        for (int i = 0; i < 4; i++) {
            int e = tid + i * 256;
            int n = e >> 3, kq = e & 7;
            *(uint4*)&Ks[n][kq * 8] = *(const uint4*)&kbB[(size_t)(nc + n) * DK + kq * 8];
        }
        #pragma unroll
        for (int i = 0; i < 4; i++) {
            int e = tid + i * 256;
            int d = e >> 4, nq = e & 15;
            *(uint4*)&Vt[d][nq * 8] = *(const uint4*)&vtB[(size_t)d * NN + nc + nq * 8];
        }
        __syncthreads();
        f32x4 accS[8] = {};
        #pragma unroll
        for (int nt = 0; nt < 8; nt++) {
            frag8 b0 = *(const frag8*)&Ks[nt * 16 + ln][quad * 8];
            frag8 b1 = *(const frag8*)&Ks[nt * 16 + ln][32 + quad * 8];
            accS[nt] = __builtin_amdgcn_mfma_f32_16x16x32_bf16(qf[0], b0, accS[nt], 0, 0, 0);
            accS[nt] = __builtin_amdgcn_mfma_f32_16x16x32_bf16(qf[1], b1, accS[nt], 0, 0, 0);
        }
        #pragma unroll
        for (int nt = 0; nt < 8; nt++)
            #pragma unroll
            for (int r = 0; r < 4; r++) {
                float p = expf(accS[nt][r] - rm[r]);
                accS[nt][r] = p;
                lrun[r] += p;
            }
        #pragma unroll
        for (int nt = 0; nt < 8; nt++)
            #pragma unroll
            for (int r = 0; r < 4; r++)
                Ps[wave][quad * 4 + r][nt * 16 + ln] = f2b(accS[nt][r]);
        #pragma unroll
        for (int ks = 0; ks < 4; ks++) {
            frag8 pf = *(const frag8*)&Ps[wave][ln][ks * 32 + quad * 8];
            #pragma unroll
            for (int nt2 = 0; nt2 < 4; nt2++) {
                frag8 vf = *(const frag8*)&Vt[nt2 * 16 + ln][ks * 32 + quad * 8];
                accO[nt2] = __builtin_amdgcn_mfma_f32_16x16x32_bf16(pf, vf, accO[nt2], 0, 0, 0);
            }
        }
    }
    #pragma unroll
    for (int r = 0; r < 4; r++) {
        float ls = lrun[r];
        #pragma unroll
        for (int off = 1; off < 16; off <<= 1) ls += __shfl_xor(ls, off);
        int p = t0 + wave * 16 + quad * 4 + r;
        size_t pb = ((size_t)bh * NTOP + p) * KSPLIT + split;
        #pragma unroll
        for (int nt2 = 0; nt2 < 4; nt2++)
            Opart[pb * 64 + nt2 * 16 + ln] = accO[nt2][r];
        if (ln == 0) ml[pb] = ls;
    }
}

// =============== combine split-K partials -> ctxb (bf16) ===============
__global__ __launch_bounds__(256) void attn_comb_k(const float* __restrict__ Opart,
    const float* __restrict__ ml, const int* __restrict__ idx,
    u16* __restrict__ ctxb)
{
    int gid = blockIdx.x * 4 + (threadIdx.x >> 6);
    int lane = threadIdx.x & 63;
    int bh = gid >> 9;
    int h = bh & 7, b = bh >> 3;
    size_t base = (size_t)gid * KSPLIT;
    float L = 0.f, O = 0.f;
    #pragma unroll
    for (int s = 0; s < KSPLIT; s++) {
        L += ml[base + s];
        O += Opart[(base + s) * 64 + lane];
    }
    int n = idx[gid];
    ctxb[((size_t)(b * NN + n)) * NC + h * DK + lane] = f2b(O / L);
}

// =============== layernorm of A + P0 + P1 + cb (float2-vectorized) ===============
__global__ __launch_bounds__(256) void ln_k(const float* __restrict__ A,
    const float* __restrict__ P0, const float* __restrict__ P1,
    const float* __restrict__ cb,
    const float* __restrict__ g, const float* __restrict__ bb,
    float* __restrict__ out, u16* __restrict__ outb)
{
    int row = blockIdx.x;
    int tid = threadIdx.x;
    __shared__ float red[256];
    size_t base = (size_t)row * NC;
    float2 a  = *(const float2*)&A[base + tid * 2];
    float2 p0 = *(const float2*)&P0[base + tid * 2];
    float2 p1 = *(const float2*)&P1[base + tid * 2];
    float2 c2 = *(const float2*)&cb[tid * 2];
    float v0 = a.x + p0.x + p1.x + c2.x;
    float v1 = a.y + p0.y + p1.y + c2.y;
    red[tid] = v0 + v1;
    __syncthreads();
    for (int off = 128; off > 0; off >>= 1) {
        if (tid < off) red[tid] += red[tid + off];
        __syncthreads();
    }
    float mu = red[0] / (float)NC;
    __syncthreads();
    float d0 = v0 - mu, d1 = v1 - mu;
    red[tid] = d0 * d0 + d1 * d1;
    __syncthreads();
    for (int off = 128; off > 0; off >>= 1) {
        if (tid < off) red[tid] += red[tid + off];
        __syncthreads();
    }
    float rstd = rsqrtf(red[0] / (float)NC + 1e-5f);
    float2 g2 = *(const float2*)&g[tid * 2];
    float2 b2 = *(const float2*)&bb[tid * 2];
    float r0 = d0 * rstd * g2.x + b2.x;
    float r1 = d1 * rstd * g2.y + b2.y;
    if (out) { float2 o; o.x = r0; o.y = r1; *(float2*)&out[base + tid * 2] = o; }
    if (outb) {
        union { u16 s[2]; unsigned u; } w2;
        w2.s[0] = f2b(r0); w2.s[1] = f2b(r1);
        *(unsigned*)&outb[base + tid * 2] = w2.u;
    }
}

// =============== maxpool(3,2,1)+ELU+LN over conv partials (float2) ===============
__global__ __launch_bounds__(256) void pool_ln_k(const float* __restrict__ P0,
    const float* __restrict__ P1, const float* __restrict__ cb,
    const float* __restrict__ g, const float* __restrict__ bb,
    float* __restrict__ outp)
{
    int row = blockIdx.x;
    int j = row & (NPOOL - 1), b = row / NPOOL;
    int tid = threadIdx.x;
    __shared__ float red[256];
    size_t bbase = (size_t)b * NN * NC;
    float2 c2 = *(const float2*)&cb[tid * 2];
    float m0 = -INFINITY, m1 = -INFINITY;
    int p0r = 2 * j - 1;
    #pragma unroll
    for (int t = 0; t < 3; t++) {
        int p = p0r + t;
        if (p >= 0 && p < NN) {
            size_t off = bbase + (size_t)p * NC + tid * 2;
            float2 a = *(const float2*)&P0[off];
            float2 c = *(const float2*)&P1[off];
            m0 = fmaxf(m0, a.x + c.x + c2.x);
            m1 = fmaxf(m1, a.y + c.y + c2.y);
        }
    }
    float v0 = m0 > 0.f ? m0 : expm1f(m0);
    float v1 = m1 > 0.f ? m1 : expm1f(m1);
    red[tid] = v0 + v1;
    __syncthreads();
    for (int off = 128; off > 0; off >>= 1) {
        if (tid < off) red[tid] += red[tid + off];
        __syncthreads();
    }
    float mu = red[0] / (float)NC;
    __syncthreads();
    float d0 = v0 - mu, d1 = v1 - mu;
    red[tid] = d0 * d0 + d1 * d1;
    __syncthreads();
    for (int off = 128; off > 0; off >>= 1) {
        if (tid < off) red[tid] += red[tid + off];
        __syncthreads();
    }
    float rstd = rsqrtf(red[0] / (float)NC + 1e-5f);
    float2 g2 = *(const float2*)&g[tid * 2];
    float2 b2 = *(const float2*)&bb[tid * 2];
    float2 o;
    o.x = d0 * rstd * g2.x + b2.x;
    o.y = d1 * rstd * g2.y + b2.y;
    *(float2*)&outp[(size_t)row * NC + tid * 2] = o;
}

extern "C" void kernel_launch(void* const* d_in, const int* in_sizes, int n_in,
                              void* d_out, int out_size, void* d_ws, size_t ws_size,
                              hipStream_t stream)
{
    (void)in_sizes; (void)n_in; (void)out_size; (void)ws_size;
    const float* x      = (const float*)d_in[0];
    const float* qkv_w  = (const float*)d_in[1];
    const float* qkv_b  = (const float*)d_in[2];
    const float* out_w  = (const float*)d_in[3];
    const float* out_b  = (const float*)d_in[4];
    const float* ffn_w1 = (const float*)d_in[5];
    const float* ffn_b1 = (const float*)d_in[6];
    const float* ffn_w2 = (const float*)d_in[7];
    const float* ffn_b2 = (const float*)d_in[8];
    const float* n1_g   = (const float*)d_in[9];
    const float* n1_b   = (const float*)d_in[10];
    const float* n2_g   = (const float*)d_in[11];
    const float* n2_b   = (const float*)d_in[12];
    const float* conv_w = (const float*)d_in[13];
    const float* conv_b = (const float*)d_in[14];
    const float* cn_g   = (const float*)d_in[15];
    const float* cn_b   = (const float*)d_in[16];

    const size_t R = (size_t)NB * NN * NC;     // 2097152
    float* ws = (float*)d_ws;
    float* x1   = ws;                 // R : Kcat during rowstat; Opart
    float* reg2 = ws + R;             // R : xcat -> Vtb(2nd half) -> split-K P0
    float* QhR  = ws + 2 * R;         // R : Qbs + Kb (bf16, head-major)
    float* Kh   = ws + 3 * R;         // R : hb (FFN1 out)
    float* Vh   = ws + 4 * R;         // R : V fp32; split-K partial P1
    size_t o = 5 * R;
    float* pmax  = ws + o;  o += 65536;   // rowmax (scaled)
    float* psum  = ws + o;  o += 65536;   // (layout stability; unused)
    float* Marr  = ws + o;  o += 32768;
    float* pmean = ws + o;  o += 32768;
    float* meanv = ws + o;  o += 1024;
    int*   idx   = (int*)(ws + o);  o += 8192;
    float* ml    = ws + o;  o += 65536;
    u16*   ctxb  = (u16*)(ws + o);  o += R / 2;
    u16*   x1b   = (u16*)(ws + o);  o += R / 2;   // Qcat lower half
    u16*   x2b   = (u16*)(ws + o);  o += R / 2;   // Qcat upper half; LN2 out
    u16*   owT   = (u16*)(ws + o);  o += 131072;
    u16*   w1T   = (u16*)(ws + o);  o += 524288;  // wcatT(lo) early
    u16*   w2T   = (u16*)(ws + o);  o += 524288;  // wcatT(hi) early
    u16*   cwT   = (u16*)(ws + o);  o += 393216;
    u16*   Qbs   = (u16*)QhR;                       // [16][2048][64] bf16 pre-scaled
    u16*   Kb    = (u16*)(QhR + R / 2);             // [16][2048][64] bf16
    u16*   Vtb   = (u16*)(ws + R + R / 2);          // [16][64][2048] bf16
    float* Opart    = x1;
    u16*   hb       = (u16*)Kh;
    float* rowmax   = pmax;
    float* skP0 = reg2;
    float* skP1 = Vh;
    u16*   xcat  = (u16*)reg2;        // dead after mfma_qkv
    u16*   wcatT = w1T;               // [1536][1024] fp16 spans w1T+w2T
    u16*   Qcat  = x1b;               // (x1b+x2b)
    u16*   Kcat  = (u16*)x1;
    (void)psum;

    // all input casts in ONE launch
    megacast_k<<<3840, 256, 0, stream>>>(x, qkv_w, out_w, conv_w,
                                         xcat, wcatT, owT, cwT);

    // fused Q,K,V projection: emits Qbs/Kb bf16 + Qcat/Kcat fp16 + Vh fp32
    mfma_qkv<<<dim3(32, 12), 256, 0, stream>>>(xcat, wcatT, qkv_b,
                                               Qbs, Kb, Vh, Qcat, Kcat);

    // rowstat MFMA + FFN weight transposes + V transpose/meanv in ONE launch
    castrow_k<<<3072, 256, 0, stream>>>(Qcat, Kcat, Marr, rowmax,
                                        ffn_w1, ffn_w2, w1T, w2T, Vh, Vtb, pmean);

    // top-512 select (+ fused meanv combine)
    topk_k<<<NB * NH, 256, 0, stream>>>(Marr, pmean, meanv, idx);

    // attention + uniform-ctx fill in ONE launch
    attnfill_k<<<1536, 256, 0, stream>>>(Qbs, Kb, Vtb, idx, rowmax, meanv,
                                         Opart, ml, ctxb);
    attn_comb_k<<<NB * NH * NTOP / 4, 256, 0, stream>>>(Opart, ml, idx, ctxb);

    // proj: split-K x2; partials combined in LN1
    mfma_gemm_sk<0><<<dim3(32, 4, 2), 256, 0, stream>>>(
        ctxb, NC, owT, skP0, skP1, NC, NC);

    // x1 = LN(x + proj_p0 + proj_p1 + out_b)
    ln_k<<<NB * NN, 256, 0, stream>>>(x, skP0, skP1, out_b, n1_g, n1_b, x1, x1b);

    // FFN1 (full-K); FFN2 split-K x2
    mfma_gemm<0><<<dim3(32, 16), 256, 0, stream>>>(
        x1b, NC, w1T, ffn_b1, (float*)nullptr, hb, DFF, NC, 1);
    mfma_gemm_sk<0><<<dim3(32, 4, 2), 256, 0, stream>>>(
        hb, DFF, w2T, skP0, skP1, NC, DFF);

    // x2 = LN(x1 + ffn2_p0 + ffn2_p1 + ffn_b2) -> bf16
    ln_k<<<NB * NN, 256, 0, stream>>>(x1, skP0, skP1, ffn_b2,
                                      n2_g, n2_b, (float*)nullptr, x2b);

    // fused circular conv1d(k=3): split-K x2 MFMA GEMM, K=1536
    mfma_gemm_sk<1><<<dim3(32, 4, 2), 256, 0, stream>>>(
        x2b, NC, cwT, skP0, skP1, NC, 1536);

    pool_ln_k<<<NB * NPOOL, 256, 0, stream>>>(skP0, skP1, conv_b, cn_g, cn_b,
                                              (float*)d_out);
}

// Round 13
// 302.908 us; speedup vs baseline: 1.9752x; 1.0030x over previous
//
#include <hip/hip_runtime.h>
#include <math.h>

#define NB 2
#define NN 2048
#define NC 512
#define NH 8
#define DK 64
#define DFF 2048
#define NTOP 512
#define NPOOL 1024
#define KSPLIT 4

typedef unsigned short u16;
typedef __attribute__((ext_vector_type(8))) short frag8;
typedef __attribute__((ext_vector_type(8))) _Float16 h8;
typedef __attribute__((ext_vector_type(4))) float f32x4;

static __device__ __forceinline__ u16 f2b(float f) {
    union { float f; unsigned int u; } v; v.f = f;
    unsigned int r = (v.u + 0x7fffu + ((v.u >> 16) & 1u)) >> 16;
    return (u16)r;
}
static __device__ __forceinline__ float b2f(u16 v) {
    union { unsigned u; float f; } x; x.u = ((unsigned)v) << 16; return x.f;
}
static __device__ __forceinline__ u16 f2h_bits(float f) {
    union { _Float16 h; u16 u; } v; v.h = (_Float16)f; return v.u;
}
static __device__ __forceinline__ float h2f_bits(u16 u) {
    union { u16 u; _Float16 h; } v; v.u = u; return (float)v.h;
}

// =============== bf16 MFMA GEMM (full-K): used for FFN1 (+gelu) ===============
template<int MODE>
__global__ __launch_bounds__(256) void mfma_gemm(const u16* __restrict__ A, int lda,
    const u16* __restrict__ Bt, const float* __restrict__ bias,
    float* __restrict__ C, u16* __restrict__ Cb, int ldc, int K, int act)
{
    __shared__ u16 As[128][72];
    __shared__ u16 Bs[128][72];
    int tid = threadIdx.x;
    int m0 = blockIdx.x * 128, n0 = blockIdx.y * 128;
    int wave = tid >> 6, lane = tid & 63;
    int ln = lane & 15, quad = lane >> 4;
    int wm = (wave >> 1) * 64, wn = (wave & 1) * 64;
    f32x4 acc[4][4] = {};
    for (int k0 = 0; k0 < K; k0 += 64) {
        #pragma unroll
        for (int i = 0; i < 4; i++) {
            int t = tid + i * 256;
            int m = t >> 3, kq = t & 7;
            size_t aoff;
            if (MODE == 1) {
                int grow = m0 + m;
                int shift = (k0 >> 9) - 1;
                int arow = (grow & ~(NN - 1)) | ((grow + shift) & (NN - 1));
                aoff = (size_t)arow * NC + ((k0 & 511) + kq * 8);
            } else {
                aoff = (size_t)(m0 + m) * lda + k0 + kq * 8;
            }
            *(uint4*)&As[m][kq * 8] = *(const uint4*)&A[aoff];
            *(uint4*)&Bs[m][kq * 8] = *(const uint4*)&Bt[(size_t)(n0 + m) * K + k0 + kq * 8];
        }
        __syncthreads();
        #pragma unroll
        for (int kk = 0; kk < 2; kk++) {
            frag8 af[4], bf[4];
            #pragma unroll
            for (int i = 0; i < 4; i++) {
                af[i] = *(const frag8*)&As[wm + i * 16 + ln][kk * 32 + quad * 8];
                bf[i] = *(const frag8*)&Bs[wn + i * 16 + ln][kk * 32 + quad * 8];
            }
            #pragma unroll
            for (int i = 0; i < 4; i++)
                #pragma unroll
                for (int j = 0; j < 4; j++)
                    acc[i][j] = __builtin_amdgcn_mfma_f32_16x16x32_bf16(
                        af[i], bf[j], acc[i][j], 0, 0, 0);
        }
        __syncthreads();
    }
    #pragma unroll
    for (int i = 0; i < 4; i++) {
        #pragma unroll
        for (int j = 0; j < 4; j++) {
            int col = n0 + wn + j * 16 + ln;
            float bv = bias ? bias[col] : 0.f;
            #pragma unroll
            for (int r = 0; r < 4; r++) {
                int row = m0 + wm + i * 16 + quad * 4 + r;
                float v = acc[i][j][r] + bv;
                if (act == 1) v = 0.5f * v * (1.0f + erff(v * 0.70710678118654752f));
                if (Cb) Cb[(size_t)row * ldc + col] = f2b(v);
                else    C[(size_t)row * ldc + col] = v;
            }
        }
    }
}

// =============== split-K x2 MFMA GEMM: fp32 partials, no bias/act ===============
template<int MODE>
__global__ __launch_bounds__(256) void mfma_gemm_sk(const u16* __restrict__ A, int lda,
    const u16* __restrict__ Bt, float* __restrict__ P0, float* __restrict__ P1,
    int ldc, int K)
{
    __shared__ u16 As[128][72];
    __shared__ u16 Bs[128][72];
    int tid = threadIdx.x;
    int m0 = blockIdx.x * 128, n0 = blockIdx.y * 128;
    int split = blockIdx.z;
    int K2 = K >> 1, kbeg = split * K2;
    int wave = tid >> 6, lane = tid & 63;
    int ln = lane & 15, quad = lane >> 4;
    int wm = (wave >> 1) * 64, wn = (wave & 1) * 64;
    f32x4 acc[4][4] = {};
    for (int k0 = kbeg; k0 < kbeg + K2; k0 += 64) {
        #pragma unroll
        for (int i = 0; i < 4; i++) {
            int t = tid + i * 256;
            int m = t >> 3, kq = t & 7;
            size_t aoff;
            if (MODE == 1) {
                int grow = m0 + m;
                int shift = (k0 >> 9) - 1;
                int arow = (grow & ~(NN - 1)) | ((grow + shift) & (NN - 1));
                aoff = (size_t)arow * NC + ((k0 & 511) + kq * 8);
            } else {
                aoff = (size_t)(m0 + m) * lda + k0 + kq * 8;
            }
            *(uint4*)&As[m][kq * 8] = *(const uint4*)&A[aoff];
            *(uint4*)&Bs[m][kq * 8] = *(const uint4*)&Bt[(size_t)(n0 + m) * K + k0 + kq * 8];
        }
        __syncthreads();
        #pragma unroll
        for (int kk = 0; kk < 2; kk++) {
            frag8 af[4], bf[4];
            #pragma unroll
            for (int i = 0; i < 4; i++) {
                af[i] = *(const frag8*)&As[wm + i * 16 + ln][kk * 32 + quad * 8];
                bf[i] = *(const frag8*)&Bs[wn + i * 16 + ln][kk * 32 + quad * 8];
            }
            #pragma unroll
            for (int i = 0; i < 4; i++)
                #pragma unroll
                for (int j = 0; j < 4; j++)
                    acc[i][j] = __builtin_amdgcn_mfma_f32_16x16x32_bf16(
                        af[i], bf[j], acc[i][j], 0, 0, 0);
        }
        __syncthreads();
    }
    float* P = split ? P1 : P0;
    #pragma unroll
    for (int i = 0; i < 4; i++) {
        #pragma unroll
        for (int j = 0; j < 4; j++) {
            int col = n0 + wn + j * 16 + ln;
            #pragma unroll
            for (int r = 0; r < 4; r++) {
                int row = m0 + wm + i * 16 + quad * 4 + r;
                P[(size_t)row * ldc + col] = acc[i][j][r];
            }
        }
    }
}

// =============== QKV projection: f16 concat-hi/lo MFMA GEMM (fp32-grade) =========
__global__ __launch_bounds__(256) void mfma_qkv(const u16* __restrict__ A,
    const u16* __restrict__ Bt, const float* __restrict__ bias,
    u16* __restrict__ Qbs, u16* __restrict__ Kb, float* __restrict__ Vh,
    u16* __restrict__ Qcat, u16* __restrict__ Kcat)
{
    __shared__ u16 As[128][72];
    __shared__ u16 Bs[128][72];
    int tid = threadIdx.x;
    int m0 = blockIdx.x * 128, n0 = blockIdx.y * 128;
    int wave = tid >> 6, lane = tid & 63;
    int ln = lane & 15, quad = lane >> 4;
    int wm = (wave >> 1) * 64, wn = (wave & 1) * 64;
    f32x4 acc[4][4] = {};
    for (int k0 = 0; k0 < 1024; k0 += 64) {
        #pragma unroll
        for (int i = 0; i < 4; i++) {
            int t = tid + i * 256;
            int m = t >> 3, kq = t & 7;
            *(uint4*)&As[m][kq * 8] = *(const uint4*)&A[(size_t)(m0 + m) * 1024 + k0 + kq * 8];
            *(uint4*)&Bs[m][kq * 8] = *(const uint4*)&Bt[(size_t)(n0 + m) * 1024 + k0 + kq * 8];
        }
        __syncthreads();
        #pragma unroll
        for (int kk = 0; kk < 2; kk++) {
            h8 af[4], bf[4];
            #pragma unroll
            for (int i = 0; i < 4; i++) {
                af[i] = *(const h8*)&As[wm + i * 16 + ln][kk * 32 + quad * 8];
                bf[i] = *(const h8*)&Bs[wn + i * 16 + ln][kk * 32 + quad * 8];
            }
            #pragma unroll
            for (int i = 0; i < 4; i++)
                #pragma unroll
                for (int j = 0; j < 4; j++)
                    acc[i][j] = __builtin_amdgcn_mfma_f32_16x16x32_f16(
                        af[i], bf[j], acc[i][j], 0, 0, 0);
        }
        __syncthreads();
    }
    #pragma unroll
    for (int i = 0; i < 4; i++) {
        #pragma unroll
        for (int j = 0; j < 4; j++) {
            int col = n0 + wn + j * 16 + ln;   // 0..1535 : [Q | K | V]
            float bv = bias[col];
            int which = col >> 9;
            int h = (col >> 6) & 7, d = col & 63;
            #pragma unroll
            for (int r = 0; r < 4; r++) {
                int row = m0 + wm + i * 16 + quad * 4 + r;
                int b = row >> 11, n = row & (NN - 1);
                float v = acc[i][j][r] + bv;
                size_t off32 = ((size_t)((b << 3) + h) * NN + n) * DK + d;
                if (which == 2) {
                    Vh[off32] = v;
                } else {
                    size_t offc = ((size_t)((b << 3) + h) * NN + n) * 128 + d;
                    u16 hb_ = f2h_bits(v);
                    u16 lb_ = f2h_bits(v - h2f_bits(hb_));
                    if (which == 0) {
                        Qbs[off32] = f2b(v * 0.125f);
                        Qcat[offc] = hb_; Qcat[offc + 64] = lb_;
                    } else {
                        Kb[off32] = f2b(v);
                        Kcat[offc] = hb_; Kcat[offc + 64] = lb_;
                    }
                }
            }
        }
    }
}

// =============== megacast: castx + castw_hl + castw_t(out_w) + castconvw ==========
__global__ __launch_bounds__(256) void megacast_k(const float* __restrict__ x,
    const float* __restrict__ qkv_w, const float* __restrict__ out_w,
    const float* __restrict__ cw,
    u16* __restrict__ xcat, u16* __restrict__ wcatT, u16* __restrict__ owT,
    u16* __restrict__ cwT)
{
    __shared__ float t[32][33];
    int b = blockIdx.x;
    int tid = threadIdx.x;
    if (b < 2048) {
        int i = b * 256 + tid;
        int m = i >> 7, kq = i & 127;
        float4 v = ((const float4*)x)[i];
        ushort4 h, l;
        h.x = f2h_bits(v.x); h.y = f2h_bits(v.y);
        h.z = f2h_bits(v.z); h.w = f2h_bits(v.w);
        l.x = f2h_bits(v.x - h2f_bits(h.x));
        l.y = f2h_bits(v.y - h2f_bits(h.y));
        l.z = f2h_bits(v.z - h2f_bits(h.z));
        l.w = f2h_bits(v.w - h2f_bits(h.w));
        *(ushort4*)&xcat[(size_t)m * 1024 + kq * 4] = h;
        *(ushort4*)&xcat[(size_t)m * 1024 + 512 + kq * 4] = l;
    } else if (b < 2816) {
        int lb = b - 2048;
        int c0 = (lb % 48) * 32, r0 = (lb / 48) * 32;
        int lx = tid & 31, ly = tid >> 5;
        #pragma unroll
        for (int i = 0; i < 4; i++)
            t[ly + i * 8][lx] = qkv_w[(size_t)(r0 + ly + i * 8) * 1536 + c0 + lx];
        __syncthreads();
        #pragma unroll
        for (int i = 0; i < 4; i++) {
            float v = t[lx][ly + i * 8];
            u16 hb_ = f2h_bits(v);
            u16 lb_ = f2h_bits(v - h2f_bits(hb_));
            size_t ob = (size_t)(c0 + ly + i * 8) * 1024 + r0 + lx;
            wcatT[ob] = hb_;
            wcatT[ob + 512] = lb_;
        }
    } else if (b < 3072) {
        int lb = b - 2816;
        int c0 = (lb % 16) * 32, r0 = (lb / 16) * 32;
        int lx = tid & 31, ly = tid >> 5;
        #pragma unroll
        for (int i = 0; i < 4; i++)
            t[ly + i * 8][lx] = out_w[(size_t)(r0 + ly + i * 8) * 512 + c0 + lx];
        __syncthreads();
        #pragma unroll
        for (int i = 0; i < 4; i++)
            owT[(size_t)(c0 + ly + i * 8) * 512 + r0 + lx] = f2b(t[lx][ly + i * 8]);
    } else {
        int g = (b - 3072) * 256 + tid;
        int co = g / 384;
        int rem = g - co * 384;
        int tt = rem >> 7;
        int ci0 = (rem & 127) * 4;
        const float* src = cw + (size_t)co * 1536 + tt;
        ushort4 o;
        o.x = f2b(src[(ci0 + 0) * 3]);
        o.y = f2b(src[(ci0 + 1) * 3]);
        o.z = f2b(src[(ci0 + 2) * 3]);
        o.w = f2b(src[(ci0 + 3) * 3]);
        *(ushort4*)&cwT[(size_t)co * 1536 + tt * NC + ci0] = o;
    }
}

// ===== castrow: rowstat MFMA (first, long pole) + FFN weight casts + castv =======
__global__ __launch_bounds__(256) void castrow_k(
    const u16* __restrict__ Qcat, const u16* __restrict__ Kcat,
    float* __restrict__ Marr, float* __restrict__ rowmax,
    const float* __restrict__ w1, const float* __restrict__ w2,
    u16* __restrict__ w1T, u16* __restrict__ w2T,
    const float* __restrict__ Vh, u16* __restrict__ Vtb, float* __restrict__ pmean)
{
    __shared__ __align__(16) char smem[34816];
    int b = blockIdx.x;
    int tid = threadIdx.x;
    if (b < 512) {
        // ---- rowstat role: bh = b & 15 (stride-16 co-XCD per head) ----
        u16 (*Ks)[136] = (u16(*)[136])smem;
        int bh = b & 15;
        int m0 = (b >> 4) * 64;
        int wave = tid >> 6, lane = tid & 63;
        int ln = lane & 15, quad = lane >> 4;
        h8 qf[4];
        {
            const u16* qp = &Qcat[((size_t)bh * NN + m0 + wave * 16 + ln) * 128];
            #pragma unroll
            for (int ks = 0; ks < 4; ks++)
                qf[ks] = *(const h8*)&qp[ks * 32 + quad * 8];
        }
        f32x4 vmax, vsum;
        #pragma unroll
        for (int r = 0; r < 4; r++) { vmax[r] = -INFINITY; vsum[r] = 0.f; }
        const u16* kB = Kcat + (size_t)bh * NN * 128;
        for (int nc = 0; nc < NN; nc += 128) {
            __syncthreads();
            #pragma unroll
            for (int i = 0; i < 8; i++) {
                int e = tid + i * 256;
                int n = e >> 4, kq = e & 15;
                *(uint4*)&Ks[n][kq * 8] = *(const uint4*)&kB[(size_t)(nc + n) * 128 + kq * 8];
            }
            __syncthreads();
            f32x4 accS[8] = {};
            #pragma unroll
            for (int nt = 0; nt < 8; nt++) {
                #pragma unroll
                for (int ks = 0; ks < 4; ks++) {
                    h8 kf = *(const h8*)&Ks[nt * 16 + ln][ks * 32 + quad * 8];
                    accS[nt] = __builtin_amdgcn_mfma_f32_16x16x32_f16(
                        qf[ks], kf, accS[nt], 0, 0, 0);
                }
            }
            #pragma unroll
            for (int nt = 0; nt < 8; nt++)
                #pragma unroll
                for (int r = 0; r < 4; r++) {
                    vmax[r] = fmaxf(vmax[r], accS[nt][r]);
                    vsum[r] += accS[nt][r];
                }
        }
        #pragma unroll
        for (int r = 0; r < 4; r++) {
            float mx = vmax[r], sm = vsum[r];
            #pragma unroll
            for (int off = 1; off < 16; off <<= 1) {
                mx = fmaxf(mx, __shfl_xor(mx, off));
                sm += __shfl_xor(sm, off);
            }
            if (ln == 0) {
                int m = m0 + wave * 16 + quad * 4 + r;
                Marr[(size_t)bh * NN + m] = (mx - sm * (1.0f / (float)NN)) * 0.125f;
                rowmax[(size_t)bh * NN + m] = mx * 0.125f;
            }
        }
    } else if (b < 2560) {
        // ---- FFN weight transpose roles ----
        float (*t)[33] = (float(*)[33])smem;
        int lb = b - 512;
        const float* in; u16* out; int ldi, R, c0, r0;
        if (lb < 1024) {
            in = w1; out = w1T; ldi = 2048; R = 512;
            c0 = (lb & 63) * 32; r0 = (lb >> 6) * 32;
        } else {
            int l2 = lb - 1024;
            in = w2; out = w2T; ldi = 512; R = 2048;
            c0 = (l2 & 15) * 32; r0 = (l2 >> 4) * 32;
        }
        int lx = tid & 31, ly = tid >> 5;
        #pragma unroll
        for (int i = 0; i < 4; i++)
            t[ly + i * 8][lx] = in[(size_t)(r0 + ly + i * 8) * ldi + c0 + lx];
        __syncthreads();
        #pragma unroll
        for (int i = 0; i < 4; i++)
            out[(size_t)(c0 + ly + i * 8) * R + r0 + lx] = f2b(t[lx][ly + i * 8]);
    } else {
        // ---- castv role: V transpose -> Vtb bf16 + meanv partials ----
        float (*vt)[68] = (float(*)[68])smem;
        float* red = (float*)(smem + 64 * 68 * 4);
        int lb = b - 2560;
        int n0 = (lb & 31) * 64;
        int bh = lb >> 5;
        const float* vin = Vh + ((size_t)bh * NN + n0) * DK;
        #pragma unroll
        for (int i = 0; i < 4; i++) {
            int e = tid + i * 256;
            int n = e >> 4, dq = e & 15;
            float4 w = *(const float4*)&vin[(size_t)n * DK + dq * 4];
            vt[dq * 4 + 0][n] = w.x; vt[dq * 4 + 1][n] = w.y;
            vt[dq * 4 + 2][n] = w.z; vt[dq * 4 + 3][n] = w.w;
        }
        __syncthreads();
        #pragma unroll
        for (int i = 0; i < 4; i++) {
            int e = tid + i * 256;
            int d = e >> 4, nq = e & 15;
            float4 v = *(const float4*)&vt[d][nq * 4];
            ushort4 o;
            o.x = f2b(v.x); o.y = f2b(v.y); o.z = f2b(v.z); o.w = f2b(v.w);
            *(ushort4*)&Vtb[((size_t)bh * DK + d) * NN + n0 + nq * 4] = o;
        }
        int d = tid & 63, sub = tid >> 6;
        float s = 0.f;
        #pragma unroll
        for (int r = 0; r < 16; r++) s += vt[d][sub * 16 + r];
        red[tid] = s;
        __syncthreads();
        if (sub == 0)
            pmean[((size_t)bh * 32 + (n0 >> 6)) * 64 + d] =
                red[d] + red[64 + d] + red[128 + d] + red[192 + d];
    }
}

// =============== top-512 per (b,h) + fused meanv combine (first 64 lanes) =========
__global__ __launch_bounds__(256) void topk_k(const float* __restrict__ Marr,
    const float* __restrict__ pmean, float* __restrict__ meanv,
    int* __restrict__ idx)
{
    int bh = blockIdx.x;
    int tid = threadIdx.x;
    if (tid < 64) {
        float s = 0.f;
        #pragma unroll
        for (int c = 0; c < 32; c++) s += pmean[((size_t)bh * 32 + c) * 64 + tid];
        meanv[bh * DK + tid] = s * (1.0f / (float)NN);
    }
    const float* Mr = Marr + (size_t)bh * NN;
    int* idxr = idx + (size_t)bh * NTOP;
    __shared__ int hist[256];
    __shared__ int suf[256];
    __shared__ int wred[4], wred2[4];
    __shared__ int bin_sh, rank_sh;
    int lane = tid & 63, w = tid >> 6;
    unsigned prefix = 0;
    int rank = NTOP;
    for (int pass = 0; pass < 4; pass++) {
        int shift = 24 - pass * 8;
        unsigned mask_hi = (pass == 0) ? 0u : (0xFFFFFFFFu << (shift + 8));
        hist[tid] = 0;
        __syncthreads();
        for (int i = tid; i < NN; i += 256) {
            union { float f; unsigned u; } v; v.f = Mr[i];
            unsigned k = (v.u & 0x80000000u) ? ~v.u : (v.u | 0x80000000u);
            if ((k & mask_hi) == prefix)
                atomicAdd(&hist[(k >> shift) & 255], 1);
        }
        __syncthreads();
        int v = hist[tid];
        #pragma unroll
        for (int off = 1; off < 64; off <<= 1) {
            int t = __shfl_down(v, off);
            if (lane + off < 64) v += t;
        }
        if (lane == 0) wred[w] = v;
        __syncthreads();
        int add = 0;
        #pragma unroll
        for (int w2 = 0; w2 < 4; w2++) if (w2 > w) add += wred[w2];
        suf[tid] = v + add;
        __syncthreads();
        int sv = suf[tid];
        int nxt = (tid < 255) ? suf[tid + 1] : 0;
        if (sv >= rank && nxt < rank) { bin_sh = tid; rank_sh = rank - nxt; }
        __syncthreads();
        prefix |= ((unsigned)bin_sh << shift);
        rank = rank_sh;
        __syncthreads();
    }
    union { unsigned u; float f; } tv;
    tv.u = (prefix & 0x80000000u) ? (prefix & 0x7FFFFFFFu) : ~prefix;
    float thr = tv.f;
    int lg = 0, le = 0;
    #pragma unroll
    for (int k = 0; k < 8; k++) {
        float v = Mr[tid * 8 + k];
        lg += (v > thr) ? 1 : 0;
        le += (v == thr) ? 1 : 0;
    }
    int vg = lg, ve = le;
    #pragma unroll
    for (int off = 1; off < 64; off <<= 1) {
        int tg = __shfl_up(vg, off);
        int te = __shfl_up(ve, off);
        if (lane >= off) { vg += tg; ve += te; }
    }
    if (lane == 63) { wred[w] = vg; wred2[w] = ve; }
    __syncthreads();
    int addg = 0, adde = 0, totg = 0;
    #pragma unroll
    for (int w2 = 0; w2 < 4; w2++) {
        totg += wred[w2];
        if (w2 < w) { addg += wred[w2]; adde += wred2[w2]; }
    }
    int cnt_gt = totg;
    int needed = NTOP - cnt_gt;
    int gpre = (vg + addg) - lg, epre = (ve + adde) - le;
    #pragma unroll
    for (int k = 0; k < 8; k++) {
        int p = tid * 8 + k;
        float v = Mr[p];
        bool isgt = v > thr, iseq = v == thr;
        bool selv = isgt || (iseq && epre < needed);
        if (selv) idxr[gpre + (epre < needed ? epre : needed)] = p;
        gpre += isgt ? 1 : 0;
        epre += iseq ? 1 : 0;
    }
}

// ====== attn+fill fused: MFMA flash attention (first) + uniform-ctx fill =========
__global__ __launch_bounds__(256) void attnfill_k(const u16* __restrict__ Qbs,
    const u16* __restrict__ Kb, const u16* __restrict__ Vtb,
    const int* __restrict__ idx, const float* __restrict__ rowmax,
    const float* __restrict__ meanv,
    float* __restrict__ Opart, float* __restrict__ ml, u16* __restrict__ ctxb)
{
    __shared__ u16 Ks[128][72];
    __shared__ u16 Vt[64][136];
    __shared__ u16 Ps[4][16][136];
    __shared__ int rows[64];
    int blk = blockIdx.x;
    int tid = threadIdx.x;
    if (blk >= 512) {
        int i = (blk - 512) * 256 + tid;
        int c = (i * 8) & (NC - 1);
        int m = (i * 8) >> 9;
        int b = m >> 11;
        int h = c >> 6, d = c & 63;
        const float* mv = &meanv[(((b << 3) + h) << 6) + d];
        float4 v0 = *(const float4*)mv;
        float4 v1 = *(const float4*)(mv + 4);
        union { u16 s[8]; uint4 u; } r;
        r.s[0] = f2b(v0.x); r.s[1] = f2b(v0.y); r.s[2] = f2b(v0.z); r.s[3] = f2b(v0.w);
        r.s[4] = f2b(v1.x); r.s[5] = f2b(v1.y); r.s[6] = f2b(v1.z); r.s[7] = f2b(v1.w);
        *(uint4*)&ctxb[(size_t)i * 8] = r.u;
        return;
    }
    int yy = blk & 63;
    int bh = yy >> 2, split = yy & (KSPLIT - 1);
    int t0 = (blk >> 6) * 64;
    int wave = tid >> 6, lane = tid & 63;
    int ln = lane & 15, quad = lane >> 4;
    if (tid < 64) rows[tid] = idx[bh * NTOP + t0 + tid];
    __syncthreads();
    frag8 qf[2];
    {
        const u16* qp = &Qbs[((size_t)bh * NN + rows[wave * 16 + ln]) * DK];
        qf[0] = *(const frag8*)&qp[quad * 8];
        qf[1] = *(const frag8*)&qp[32 + quad * 8];
    }
    float rm[4];
    #pragma unroll
    for (int r = 0; r < 4; r++)
        rm[r] = rowmax[(size_t)bh * NN + rows[wave * 16 + quad * 4 + r]];
    f32x4 accO[4] = {};
    float lrun[4] = {};
    const u16* kbB = Kb + (size_t)bh * NN * DK;
    const u16* vtB = Vtb + (size_t)bh * DK * NN;
    int nc0 = split * (NN / KSPLIT);
    for (int nc = nc0; nc < nc0 + NN / KSPLIT; nc += 128) {
        __syncthreads();
        #pragma unroll
        for (int i = 0; i < 4; i++) {
            int e = tid + i * 256;
            int n = e >> 3, kq = e & 7;
            *(uint4*)&Ks[n][kq * 8] = *(const uint4*)&kbB[(size_t)(nc + n) * DK + kq * 8];
        }
        #pragma unroll
        for (int i = 0; i < 4; i++) {
            int e = tid + i * 256;
            int d = e >> 4, nq = e & 15;
            *(uint4*)&Vt[d][nq * 8] = *(const uint4*)&vtB[(size_t)d * NN + nc + nq * 8];
        }
        __syncthreads();
        f32x4 accS[8] = {};
        #pragma unroll
        for (int nt = 0; nt < 8; nt++) {
            frag8 b0 = *(const frag8*)&Ks[nt * 16 + ln][quad * 8];
            frag8 b1 = *(const frag8*)&Ks[nt * 16 + ln][32 + quad * 8];
            accS[nt] = __builtin_amdgcn_mfma_f32_16x16x32_bf16(qf[0], b0, accS[nt], 0, 0, 0);
            accS[nt] = __builtin_amdgcn_mfma_f32_16x16x32_bf16(qf[1], b1, accS[nt], 0, 0, 0);
        }
        #pragma unroll
        for (int nt = 0; nt < 8; nt++)
            #pragma unroll
            for (int r = 0; r < 4; r++) {
                float p = expf(accS[nt][r] - rm[r]);
                accS[nt][r] = p;
                lrun[r] += p;
            }
        #pragma unroll
        for (int nt = 0; nt < 8; nt++)
            #pragma unroll
            for (int r = 0; r < 4; r++)
                Ps[wave][quad * 4 + r][nt * 16 + ln] = f2b(accS[nt][r]);
        #pragma unroll
        for (int ks = 0; ks < 4; ks++) {
            frag8 pf = *(const frag8*)&Ps[wave][ln][ks * 32 + quad * 8];
            #pragma unroll
            for (int nt2 = 0; nt2 < 4; nt2++) {
                frag8 vf = *(const frag8*)&Vt[nt2 * 16 + ln][ks * 32 + quad * 8];
                accO[nt2] = __builtin_amdgcn_mfma_f32_16x16x32_bf16(pf, vf, accO[nt2], 0, 0, 0);
            }
        }
    }
    #pragma unroll
    for (int r = 0; r < 4; r++) {
        float ls = lrun[r];
        #pragma unroll
        for (int off = 1; off < 16; off <<= 1) ls += __shfl_xor(ls, off);
        int p = t0 + wave * 16 + quad * 4 + r;
        size_t pb = ((size_t)bh * NTOP + p) * KSPLIT + split;
        #pragma unroll
        for (int nt2 = 0; nt2 < 4; nt2++)
            Opart[pb * 64 + nt2 * 16 + ln] = accO[nt2][r];
        if (ln == 0) ml[pb] = ls;
    }
}

// =============== combine split-K partials -> ctxb (bf16) ===============
__global__ __launch_bounds__(256) void attn_comb_k(const float* __restrict__ Opart,
    const float* __restrict__ ml, const int* __restrict__ idx,
    u16* __restrict__ ctxb)
{
    int gid = blockIdx.x * 4 + (threadIdx.x >> 6);
    int lane = threadIdx.x & 63;
    int bh = gid >> 9;
    int h = bh & 7, b = bh >> 3;
    size_t base = (size_t)gid * KSPLIT;
    float L = 0.f, O = 0.f;
    #pragma unroll
    for (int s = 0; s < KSPLIT; s++) {
        L += ml[base + s];
        O += Opart[(base + s) * 64 + lane];
    }
    int n = idx[gid];
    ctxb[((size_t)(b * NN + n)) * NC + h * DK + lane] = f2b(O / L);
}

// ======= layernorm of A + P0 + P1 + cb: wave-shfl reduce (2 barriers) ===========
__global__ __launch_bounds__(256) void ln_k(const float* __restrict__ A,
    const float* __restrict__ P0, const float* __restrict__ P1,
    const float* __restrict__ cb,
    const float* __restrict__ g, const float* __restrict__ bb,
    float* __restrict__ out, u16* __restrict__ outb)
{
    int row = blockIdx.x;
    int tid = threadIdx.x;
    __shared__ float wsum[4], wvar[4];
    int lane = tid & 63, w = tid >> 6;
    size_t base = (size_t)row * NC;
    float2 a  = *(const float2*)&A[base + tid * 2];
    float2 p0 = *(const float2*)&P0[base + tid * 2];
    float2 p1 = *(const float2*)&P1[base + tid * 2];
    float2 c2 = *(const float2*)&cb[tid * 2];
    float v0 = a.x + p0.x + p1.x + c2.x;
    float v1 = a.y + p0.y + p1.y + c2.y;
    float s = v0 + v1;
    #pragma unroll
    for (int off = 1; off < 64; off <<= 1) s += __shfl_xor(s, off);
    if (lane == 0) wsum[w] = s;
    __syncthreads();
    float mu = (wsum[0] + wsum[1] + wsum[2] + wsum[3]) / (float)NC;
    float d0 = v0 - mu, d1 = v1 - mu;
    float q = d0 * d0 + d1 * d1;
    #pragma unroll
    for (int off = 1; off < 64; off <<= 1) q += __shfl_xor(q, off);
    if (lane == 0) wvar[w] = q;
    __syncthreads();
    float rstd = rsqrtf((wvar[0] + wvar[1] + wvar[2] + wvar[3]) / (float)NC + 1e-5f);
    float2 g2 = *(const float2*)&g[tid * 2];
    float2 b2 = *(const float2*)&bb[tid * 2];
    float r0 = d0 * rstd * g2.x + b2.x;
    float r1 = d1 * rstd * g2.y + b2.y;
    if (out) { float2 o; o.x = r0; o.y = r1; *(float2*)&out[base + tid * 2] = o; }
    if (outb) {
        union { u16 s[2]; unsigned u; } w2;
        w2.s[0] = f2b(r0); w2.s[1] = f2b(r1);
        *(unsigned*)&outb[base + tid * 2] = w2.u;
    }
}

// ===== maxpool(3,2,1)+ELU+LN over conv partials: wave-shfl reduce ===============
__global__ __launch_bounds__(256) void pool_ln_k(const float* __restrict__ P0,
    const float* __restrict__ P1, const float* __restrict__ cb,
    const float* __restrict__ g, const float* __restrict__ bb,
    float* __restrict__ outp)
{
    int row = blockIdx.x;
    int j = row & (NPOOL - 1), b = row / NPOOL;
    int tid = threadIdx.x;
    __shared__ float wsum[4], wvar[4];
    int lane = tid & 63, w = tid >> 6;
    size_t bbase = (size_t)b * NN * NC;
    float2 c2 = *(const float2*)&cb[tid * 2];
    float m0 = -INFINITY, m1 = -INFINITY;
    int p0r = 2 * j - 1;
    #pragma unroll
    for (int t = 0; t < 3; t++) {
        int p = p0r + t;
        if (p >= 0 && p < NN) {
            size_t off = bbase + (size_t)p * NC + tid * 2;
            float2 a = *(const float2*)&P0[off];
            float2 c = *(const float2*)&P1[off];
            m0 = fmaxf(m0, a.x + c.x + c2.x);
            m1 = fmaxf(m1, a.y + c.y + c2.y);
        }
    }
    float v0 = m0 > 0.f ? m0 : expm1f(m0);
    float v1 = m1 > 0.f ? m1 : expm1f(m1);
    float s = v0 + v1;
    #pragma unroll
    for (int off = 1; off < 64; off <<= 1) s += __shfl_xor(s, off);
    if (lane == 0) wsum[w] = s;
    __syncthreads();
    float mu = (wsum[0] + wsum[1] + wsum[2] + wsum[3]) / (float)NC;
    float d0 = v0 - mu, d1 = v1 - mu;
    float q = d0 * d0 + d1 * d1;
    #pragma unroll
    for (int off = 1; off < 64; off <<= 1) q += __shfl_xor(q, off);
    if (lane == 0) wvar[w] = q;
    __syncthreads();
    float rstd = rsqrtf((wvar[0] + wvar[1] + wvar[2] + wvar[3]) / (float)NC + 1e-5f);
    float2 g2 = *(const float2*)&g[tid * 2];
    float2 b2 = *(const float2*)&bb[tid * 2];
    float2 o;
    o.x = d0 * rstd * g2.x + b2.x;
    o.y = d1 * rstd * g2.y + b2.y;
    *(float2*)&outp[(size_t)row * NC + tid * 2] = o;
}

extern "C" void kernel_launch(void* const* d_in, const int* in_sizes, int n_in,
                              void* d_out, int out_size, void* d_ws, size_t ws_size,
                              hipStream_t stream)
{
    (void)in_sizes; (void)n_in; (void)out_size; (void)ws_size;
    const float* x      = (const float*)d_in[0];
    const float* qkv_w  = (const float*)d_in[1];
    const float* qkv_b  = (const float*)d_in[2];
    const float* out_w  = (const float*)d_in[3];
    const float* out_b  = (const float*)d_in[4];
    const float* ffn_w1 = (const float*)d_in[5];
    const float* ffn_b1 = (const float*)d_in[6];
    const float* ffn_w2 = (const float*)d_in[7];
    const float* ffn_b2 = (const float*)d_in[8];
    const float* n1_g   = (const float*)d_in[9];
    const float* n1_b   = (const float*)d_in[10];
    const float* n2_g   = (const float*)d_in[11];
    const float* n2_b   = (const float*)d_in[12];
    const float* conv_w = (const float*)d_in[13];
    const float* conv_b = (const float*)d_in[14];
    const float* cn_g   = (const float*)d_in[15];
    const float* cn_b   = (const float*)d_in[16];

    const size_t R = (size_t)NB * NN * NC;     // 2097152
    float* ws = (float*)d_ws;
    float* x1   = ws;                 // R : Kcat during rowstat; Opart
    float* reg2 = ws + R;             // R : xcat -> Vtb(2nd half) -> split-K P0
    float* QhR  = ws + 2 * R;         // R : Qbs + Kb (bf16, head-major)
    float* Kh   = ws + 3 * R;         // R : hb (FFN1 out)
    float* Vh   = ws + 4 * R;         // R : V fp32; split-K partial P1
    size_t o = 5 * R;
    float* pmax  = ws + o;  o += 65536;   // rowmax (scaled)
    float* psum  = ws + o;  o += 65536;   // (layout stability; unused)
    float* Marr  = ws + o;  o += 32768;
    float* pmean = ws + o;  o += 32768;
    float* meanv = ws + o;  o += 1024;
    int*   idx   = (int*)(ws + o);  o += 8192;
    float* ml    = ws + o;  o += 65536;
    u16*   ctxb  = (u16*)(ws + o);  o += R / 2;
    u16*   x1b   = (u16*)(ws + o);  o += R / 2;   // Qcat lower half
    u16*   x2b   = (u16*)(ws + o);  o += R / 2;   // Qcat upper half; LN2 out
    u16*   owT   = (u16*)(ws + o);  o += 131072;
    u16*   w1T   = (u16*)(ws + o);  o += 524288;  // wcatT(lo) early
    u16*   w2T   = (u16*)(ws + o);  o += 524288;  // wcatT(hi) early
    u16*   cwT   = (u16*)(ws + o);  o += 393216;
    u16*   Qbs   = (u16*)QhR;                       // [16][2048][64] bf16 pre-scaled
    u16*   Kb    = (u16*)(QhR + R / 2);             // [16][2048][64] bf16
    u16*   Vtb   = (u16*)(ws + R + R / 2);          // [16][64][2048] bf16
    float* Opart    = x1;
    u16*   hb       = (u16*)Kh;
    float* rowmax   = pmax;
    float* skP0 = reg2;
    float* skP1 = Vh;
    u16*   xcat  = (u16*)reg2;        // dead after mfma_qkv
    u16*   wcatT = w1T;               // [1536][1024] fp16 spans w1T+w2T
    u16*   Qcat  = x1b;               // (x1b+x2b)
    u16*   Kcat  = (u16*)x1;
    (void)psum;

    // all input casts in ONE launch
    megacast_k<<<3840, 256, 0, stream>>>(x, qkv_w, out_w, conv_w,
                                         xcat, wcatT, owT, cwT);

    // fused Q,K,V projection: emits Qbs/Kb bf16 + Qcat/Kcat fp16 + Vh fp32
    mfma_qkv<<<dim3(32, 12), 256, 0, stream>>>(xcat, wcatT, qkv_b,
                                               Qbs, Kb, Vh, Qcat, Kcat);

    // rowstat MFMA + FFN weight transposes + V transpose/meanv in ONE launch
    castrow_k<<<3072, 256, 0, stream>>>(Qcat, Kcat, Marr, rowmax,
                                        ffn_w1, ffn_w2, w1T, w2T, Vh, Vtb, pmean);

    // top-512 select (+ fused meanv combine)
    topk_k<<<NB * NH, 256, 0, stream>>>(Marr, pmean, meanv, idx);

    // attention + uniform-ctx fill in ONE launch
    attnfill_k<<<1536, 256, 0, stream>>>(Qbs, Kb, Vtb, idx, rowmax, meanv,
                                         Opart, ml, ctxb);
    attn_comb_k<<<NB * NH * NTOP / 4, 256, 0, stream>>>(Opart, ml, idx, ctxb);

    // proj: split-K x2; partials combined in LN1
    mfma_gemm_sk<0><<<dim3(32, 4, 2), 256, 0, stream>>>(
        ctxb, NC, owT, skP0, skP1, NC, NC);

    // x1 = LN(x + proj_p0 + proj_p1 + out_b)
    ln_k<<<NB * NN, 256, 0, stream>>>(x, skP0, skP1, out_b, n1_g, n1_b, x1, x1b);

    // FFN1 (full-K); FFN2 split-K x2
    mfma_gemm<0><<<dim3(32, 16), 256, 0, stream>>>(
        x1b, NC, w1T, ffn_b1, (float*)nullptr, hb, DFF, NC, 1);
    mfma_gemm_sk<0><<<dim3(32, 4, 2), 256, 0, stream>>>(
        hb, DFF, w2T, skP0, skP1, NC, DFF);

    // x2 = LN(x1 + ffn2_p0 + ffn2_p1 + ffn_b2) -> bf16
    ln_k<<<NB * NN, 256, 0, stream>>>(x1, skP0, skP1, ffn_b2,
                                      n2_g, n2_b, (float*)nullptr, x2b);

    // fused circular conv1d(k=3): split-K x2 MFMA GEMM, K=1536
    mfma_gemm_sk<1><<<dim3(32, 4, 2), 256, 0, stream>>>(
        x2b, NC, cwT, skP0, skP1, NC, 1536);

    pool_ln_k<<<NB * NPOOL, 256, 0, stream>>>(skP0, skP1, conv_b, cn_g, cn_b,
                                              (float*)d_out);
}